// Round 12
// baseline (439.444 us; speedup 1.0000x reference)
//
#include <hip/hip_runtime.h>
#include <hip/hip_bf16.h>

#define N_FEAT 64
#define NBW 9                      // log2(nodes per bucket) = 512
#define SRC_BITS 23                // key = (dstLocal << 23) | src ; src < 2^23

typedef unsigned short u16;

__device__ inline u16 f2bf(float f) {           // RNE f32 -> bf16
    unsigned u = __float_as_uint(f);
    u += 0x7fffu + ((u >> 16) & 1u);
    return (u16)(u >> 16);
}

// ---------------- CSR build: two-level bucket partition ----------------

__global__ __launch_bounds__(256) void coarse_hist(const int* __restrict__ ei, int* bcnt, int E, int NB) {
    __shared__ int h[256];
    int tid = threadIdx.x;
    h[tid] = 0;
    __syncthreads();
    for (int e = blockIdx.x * blockDim.x + tid; e < E; e += gridDim.x * blockDim.x)
        atomicAdd(&h[ei[E + e] >> NBW], 1);
    __syncthreads();
    if (tid < NB && h[tid]) atomicAdd(&bcnt[tid], h[tid]);
}

// block 0: exclusive scan of bucket counts; blocks 1..16: pad W3 to 64x64
__global__ __launch_bounds__(256) void scan_pad(const int* __restrict__ bcnt, int* boff, int* bcur, int NB,
                                                const float* __restrict__ W3, float* __restrict__ W3p) {
    if (blockIdx.x == 0) {
        __shared__ int wsum[4];
        int tid = threadIdx.x, lane = tid & 63, w = tid >> 6;
        int v = (tid < NB) ? bcnt[tid] : 0;
        int incl = v;
        #pragma unroll
        for (int o = 1; o < 64; o <<= 1) { int t = __shfl_up(incl, o); if (lane >= o) incl += t; }
        if (lane == 63) wsum[w] = incl;
        __syncthreads();
        int add = 0;
        #pragma unroll
        for (int i = 0; i < 4; ++i) if (i < w) add += wsum[i];
        int excl = add + incl - v;
        if (tid < NB) { boff[tid] = excl; bcur[tid] = excl; }
    } else {
        int i = (blockIdx.x - 1) * 256 + threadIdx.x;
        if (i < 64 * 64) {
            int k = i >> 6, c = i & 63;
            W3p[i] = (c < 16) ? W3[k * 16 + c] : 0.0f;
        }
    }
}

__global__ __launch_bounds__(256) void partition(const int* __restrict__ ei, const float* __restrict__ ew,
                                                 int* bcur, int2* __restrict__ ebuf, int E, int NB) {
    constexpr int EPT = 8;
    __shared__ int cnt[256];
    __shared__ int base[256];
    int tid = threadIdx.x;
    cnt[tid] = 0;
    __syncthreads();
    int start = blockIdx.x * (256 * EPT);

    int d[EPT], r[EPT], s[EPT]; float w[EPT];
    #pragma unroll
    for (int i = 0; i < EPT; ++i) {
        int e = start + i * 256 + tid;
        if (e < E) {
            d[i] = ei[E + e];
            s[i] = ei[e];
            w[i] = ew[e];
            r[i] = atomicAdd(&cnt[d[i] >> NBW], 1);
        } else d[i] = -1;
    }
    __syncthreads();
    if (tid < NB && cnt[tid]) base[tid] = atomicAdd(&bcur[tid], cnt[tid]);
    __syncthreads();
    #pragma unroll
    for (int i = 0; i < EPT; ++i) {
        if (d[i] >= 0) {
            int b = d[i] >> NBW;
            int dl = d[i] & ((1 << NBW) - 1);
            int key = (dl << SRC_BITS) | s[i];
            ebuf[base[b] + r[i]] = make_int2(key, __float_as_int(w[i]));
        }
    }
}

__global__ __launch_bounds__(256) void bucket_csr(const int2* __restrict__ ebuf, const int* __restrict__ boff,
                                                  const int* __restrict__ bcnt,
                                                  int2* __restrict__ csr, int* __restrict__ rowp,
                                                  int* __restrict__ cnt, float* __restrict__ dis, int N) {
    __shared__ int   h[512];
    __shared__ float ws[512];
    __shared__ int   off[512];
    __shared__ int   wsum[4];
    int b = blockIdx.x, tid = threadIdx.x;
    int nbase = b << NBW;
    int nn = min(512, N - nbase);
    int beg = boff[b], m = bcnt[b];

    h[tid] = 0; h[tid + 256] = 0;
    ws[tid] = 0.f; ws[tid + 256] = 0.f;
    __syncthreads();

    for (int i = tid; i < m; i += 256) {
        int2 en = ebuf[beg + i];
        int dl = ((unsigned)en.x) >> SRC_BITS;
        atomicAdd(&h[dl], 1);
        atomicAdd(&ws[dl], __int_as_float(en.y));
    }
    __syncthreads();

    int v0 = h[2 * tid], v1 = h[2 * tid + 1];
    int v = v0 + v1;
    int lane = tid & 63, wv = tid >> 6;
    int incl = v;
    #pragma unroll
    for (int o = 1; o < 64; o <<= 1) { int t = __shfl_up(incl, o); if (lane >= o) incl += t; }
    if (lane == 63) wsum[wv] = incl;
    __syncthreads();
    int add = 0;
    #pragma unroll
    for (int i = 0; i < 4; ++i) if (i < wv) add += wsum[i];
    int excl = add + incl - v;
    off[2 * tid] = excl;
    off[2 * tid + 1] = excl + v0;
    __syncthreads();

    for (int l = tid; l < nn; l += 256) {
        rowp[nbase + l] = beg + off[l];
        cnt[nbase + l]  = h[l];
        dis[nbase + l]  = rsqrtf(1.0f + ws[l]);
    }
    __syncthreads();
    h[tid] = 0; h[tid + 256] = 0;
    __syncthreads();

    for (int i = tid; i < m; i += 256) {
        int2 en = ebuf[beg + i];
        unsigned k = (unsigned)en.x;
        int dl  = k >> SRC_BITS;
        int src = k & ((1 << SRC_BITS) - 1);
        int pos = atomicAdd(&h[dl], 1);
        csr[beg + off[dl] + pos] = make_int2(src, en.y);
    }
}

// fold dis[src] into stored weight
__global__ __launch_bounds__(256) void fold_dis(int2* __restrict__ csr, const float* __restrict__ dis, int E) {
    int i = blockIdx.x * blockDim.x + threadIdx.x;
    if (i < E) {
        int2 en = csr[i];
        en.y = __float_as_int(__int_as_float(en.y) * dis[en.x]);
        csr[i] = en;
    }
}

// ---------------- GEMM: register-resident W, uniform VECTOR row loads --------
// C_bf16[N x OUTW] = A[N x 64] @ W[64 x 64]; A is f32 or bf16 (INBF).
// Row base r0 is wave-uniform -> all 64 lanes load the same A dwords (one
// broadcast L1 transaction each), pipelined on the VMEM path (NOT scalar
// cache — R11's s_load variant serialized on lgkmcnt). W column `lane` lives
// in 64 VGPRs per wave. #pragma unroll 4 bounds in-flight loads (~64 VGPR)
// to keep total VGPR < 256 (no spills).

template<int OUTW, bool INBF>
__global__ __launch_bounds__(256) void gemm_rv(const void* __restrict__ Av, const float* __restrict__ W,
                                               u16* __restrict__ C, int N) {
    int lane = threadIdx.x & 63;
    int wid  = (int)((blockIdx.x * blockDim.x + threadIdx.x) >> 6);
    int nw   = (int)((gridDim.x * blockDim.x) >> 6);

    float wcol[64];
    #pragma unroll
    for (int k = 0; k < 64; ++k) wcol[k] = W[k * 64 + lane];

    for (int r0 = wid * 4; r0 < N; r0 += nw * 4) {
        float acc0 = 0.f, acc1 = 0.f, acc2 = 0.f, acc3 = 0.f;
        if (INBF) {
            const uint4* a0 = (const uint4*)((const u16*)Av + (size_t)r0 * 64);  // 8 uint4/row
            #pragma unroll 4
            for (int q = 0; q < 8; ++q) {
                uint4 v0 = a0[q];
                uint4 v1 = a0[8 + q];
                uint4 v2 = a0[16 + q];
                uint4 v3 = a0[24 + q];
                int kk = q * 8;
                unsigned p0[4] = {v0.x, v0.y, v0.z, v0.w};
                unsigned p1[4] = {v1.x, v1.y, v1.z, v1.w};
                unsigned p2[4] = {v2.x, v2.y, v2.z, v2.w};
                unsigned p3[4] = {v3.x, v3.y, v3.z, v3.w};
                #pragma unroll
                for (int d = 0; d < 4; ++d) {
                    float wlo = wcol[kk + 2 * d];
                    float whi = wcol[kk + 2 * d + 1];
                    acc0 = fmaf(__uint_as_float(p0[d] << 16), wlo, acc0);
                    acc0 = fmaf(__uint_as_float(p0[d] & 0xffff0000u), whi, acc0);
                    acc1 = fmaf(__uint_as_float(p1[d] << 16), wlo, acc1);
                    acc1 = fmaf(__uint_as_float(p1[d] & 0xffff0000u), whi, acc1);
                    acc2 = fmaf(__uint_as_float(p2[d] << 16), wlo, acc2);
                    acc2 = fmaf(__uint_as_float(p2[d] & 0xffff0000u), whi, acc2);
                    acc3 = fmaf(__uint_as_float(p3[d] << 16), wlo, acc3);
                    acc3 = fmaf(__uint_as_float(p3[d] & 0xffff0000u), whi, acc3);
                }
            }
        } else {
            const float4* a0 = (const float4*)((const float*)Av + (size_t)r0 * 64); // 16 float4/row
            #pragma unroll 4
            for (int q = 0; q < 16; ++q) {
                float4 v0 = a0[q];
                float4 v1 = a0[16 + q];
                float4 v2 = a0[32 + q];
                float4 v3 = a0[48 + q];
                int kk = q * 4;
                float w0 = wcol[kk], w1 = wcol[kk + 1], w2 = wcol[kk + 2], w3 = wcol[kk + 3];
                acc0 = fmaf(v0.x, w0, acc0); acc0 = fmaf(v0.y, w1, acc0);
                acc0 = fmaf(v0.z, w2, acc0); acc0 = fmaf(v0.w, w3, acc0);
                acc1 = fmaf(v1.x, w0, acc1); acc1 = fmaf(v1.y, w1, acc1);
                acc1 = fmaf(v1.z, w2, acc1); acc1 = fmaf(v1.w, w3, acc1);
                acc2 = fmaf(v2.x, w0, acc2); acc2 = fmaf(v2.y, w1, acc2);
                acc2 = fmaf(v2.z, w2, acc2); acc2 = fmaf(v2.w, w3, acc2);
                acc3 = fmaf(v3.x, w0, acc3); acc3 = fmaf(v3.y, w1, acc3);
                acc3 = fmaf(v3.z, w2, acc3); acc3 = fmaf(v3.w, w3, acc3);
            }
        }
        bool cok = (OUTW == 64) || (lane < OUTW);
        if (cok) {
            if (r0 + 0 < N) C[(size_t)(r0 + 0) * OUTW + lane] = f2bf(acc0);
            if (r0 + 1 < N) C[(size_t)(r0 + 1) * OUTW + lane] = f2bf(acc1);
            if (r0 + 2 < N) C[(size_t)(r0 + 2) * OUTW + lane] = f2bf(acc2);
            if (r0 + 3 < N) C[(size_t)(r0 + 3) * OUTW + lane] = f2bf(acc3);
        }
    }
}

// ---------------- Aggregation: one node per 8-lane GROUP (shuffle-free) ------

template<int F, bool RELU, bool FINAL>
__global__ __launch_bounds__(256) void aggregate(const u16* __restrict__ hw, const int* __restrict__ rowp,
                                                 const int* __restrict__ cnt, const int2* __restrict__ csr,
                                                 const float* __restrict__ dis,
                                                 const float* __restrict__ bias, void* __restrict__ outv,
                                                 float* __restrict__ out2, float* __restrict__ out3, int N) {
    constexpr int GL   = F / 8;          // lanes per group/node (8 for F=64, 2 for F=16)
    constexpr int NPW  = 64 / GL;        // nodes per wave (8 or 32)
    constexpr unsigned ROWB = F * 2;     // row bytes (128 or 32)

    int wv   = (int)((blockIdx.x * blockDim.x + threadIdx.x) >> 6);
    int lane = threadIdx.x & 63;
    int g = lane / GL;
    int t = lane % GL;
    int n = wv * NPW + g;
    bool alive = (n < N);
    n = min(n, N - 1);

    float dd = dis[n];
    int beg = rowp[n];
    int c   = cnt[n];
    const char* hwb = (const char*)hw;
    unsigned toff = (unsigned)t * 16u;

    float acc[8];
    {   // self loop (weight 1)
        uint4 raw = *(const uint4*)(hwb + (unsigned)n * ROWB + toff);
        float w = dd * dd;
        unsigned uw[4] = {raw.x, raw.y, raw.z, raw.w};
        #pragma unroll
        for (int k = 0; k < 4; ++k) {
            acc[2 * k]     = w * __uint_as_float(uw[k] << 16);
            acc[2 * k + 1] = w * __uint_as_float(uw[k] & 0xffff0000u);
        }
    }

    int j = 0;
    for (; j + 4 <= c; j += 4) {         // 4 independent gathers in flight
        int2 e0 = csr[beg + j];
        int2 e1 = csr[beg + j + 1];
        int2 e2 = csr[beg + j + 2];
        int2 e3 = csr[beg + j + 3];
        uint4 r0 = *(const uint4*)(hwb + (unsigned)e0.x * ROWB + toff);
        uint4 r1 = *(const uint4*)(hwb + (unsigned)e1.x * ROWB + toff);
        uint4 r2 = *(const uint4*)(hwb + (unsigned)e2.x * ROWB + toff);
        uint4 r3 = *(const uint4*)(hwb + (unsigned)e3.x * ROWB + toff);
        float w0 = __int_as_float(e0.y) * dd;
        float w1 = __int_as_float(e1.y) * dd;
        float w2 = __int_as_float(e2.y) * dd;
        float w3 = __int_as_float(e3.y) * dd;
        unsigned ua[4] = {r0.x, r0.y, r0.z, r0.w};
        unsigned ub[4] = {r1.x, r1.y, r1.z, r1.w};
        unsigned uc[4] = {r2.x, r2.y, r2.z, r2.w};
        unsigned ud[4] = {r3.x, r3.y, r3.z, r3.w};
        #pragma unroll
        for (int k = 0; k < 4; ++k) {
            acc[2 * k]     = fmaf(w0, __uint_as_float(ua[k] << 16), acc[2 * k]);
            acc[2 * k + 1] = fmaf(w0, __uint_as_float(ua[k] & 0xffff0000u), acc[2 * k + 1]);
            acc[2 * k]     = fmaf(w1, __uint_as_float(ub[k] << 16), acc[2 * k]);
            acc[2 * k + 1] = fmaf(w1, __uint_as_float(ub[k] & 0xffff0000u), acc[2 * k + 1]);
            acc[2 * k]     = fmaf(w2, __uint_as_float(uc[k] << 16), acc[2 * k]);
            acc[2 * k + 1] = fmaf(w2, __uint_as_float(uc[k] & 0xffff0000u), acc[2 * k + 1]);
            acc[2 * k]     = fmaf(w3, __uint_as_float(ud[k] << 16), acc[2 * k]);
            acc[2 * k + 1] = fmaf(w3, __uint_as_float(ud[k] & 0xffff0000u), acc[2 * k + 1]);
        }
    }
    for (; j < c; ++j) {                 // tail (<=3)
        int2 e = csr[beg + j];
        uint4 r = *(const uint4*)(hwb + (unsigned)e.x * ROWB + toff);
        float w = __int_as_float(e.y) * dd;
        unsigned u[4] = {r.x, r.y, r.z, r.w};
        #pragma unroll
        for (int k = 0; k < 4; ++k) {
            acc[2 * k]     = fmaf(w, __uint_as_float(u[k] << 16), acc[2 * k]);
            acc[2 * k + 1] = fmaf(w, __uint_as_float(u[k] & 0xffff0000u), acc[2 * k + 1]);
        }
    }

    if (alive) {
        float4 b0 = *(const float4*)&bias[t * 8];
        float4 b1 = *(const float4*)&bias[t * 8 + 4];
        acc[0] += b0.x; acc[1] += b0.y; acc[2] += b0.z; acc[3] += b0.w;
        acc[4] += b1.x; acc[5] += b1.y; acc[6] += b1.z; acc[7] += b1.w;
        if (RELU) {
            #pragma unroll
            for (int k = 0; k < 8; ++k) acc[k] = fmaxf(acc[k], 0.0f);
        }
        if (!FINAL) {
            u16* o16 = (u16*)outv;
            uint4 pk;
            pk.x = (unsigned)f2bf(acc[0]) | ((unsigned)f2bf(acc[1]) << 16);
            pk.y = (unsigned)f2bf(acc[2]) | ((unsigned)f2bf(acc[3]) << 16);
            pk.z = (unsigned)f2bf(acc[4]) | ((unsigned)f2bf(acc[5]) << 16);
            pk.w = (unsigned)f2bf(acc[6]) | ((unsigned)f2bf(acc[7]) << 16);
            *(uint4*)&o16[(size_t)n * F + t * 8] = pk;
        } else {
            float4 r0 = make_float4(acc[0], acc[1], acc[2], acc[3]);
            float4 r1 = make_float4(acc[4], acc[5], acc[6], acc[7]);
            *(float4*)&out2[(size_t)n * F + t * 8] = r0;
            *(float4*)&out2[(size_t)n * F + t * 8 + 4] = r1;
            *(float4*)&out3[(size_t)n * F + t * 8] = r0;
            *(float4*)&out3[(size_t)n * F + t * 8 + 4] = r1;
            float mloc = acc[0];
            #pragma unroll
            for (int k = 1; k < 8; ++k) mloc = fmaxf(mloc, acc[k]);
            float m = fmaxf(mloc, __shfl_xor(mloc, 1));   // partner lane same group, same alive
            float sloc = 0.f;
            #pragma unroll
            for (int k = 0; k < 8; ++k) sloc += __expf(acc[k] - m);
            float ssum = sloc + __shfl_xor(sloc, 1);
            float ls = m + __logf(ssum);
            float* o = (float*)outv;
            float4 w0 = make_float4(acc[0] - ls, acc[1] - ls, acc[2] - ls, acc[3] - ls);
            float4 w1 = make_float4(acc[4] - ls, acc[5] - ls, acc[6] - ls, acc[7] - ls);
            *(float4*)&o[(size_t)n * F + t * 8] = w0;
            *(float4*)&o[(size_t)n * F + t * 8 + 4] = w1;
        }
    }
}

// ---------------- launch ----------------

extern "C" void kernel_launch(void* const* d_in, const int* in_sizes, int n_in,
                              void* d_out, int out_size, void* d_ws, size_t ws_size,
                              hipStream_t stream) {
    const float* x   = (const float*)d_in[0];
    const int*   ei  = (const int*)d_in[1];
    const float* ew  = (const float*)d_in[2];
    const float* W1  = (const float*)d_in[3];
    const float* b1  = (const float*)d_in[4];
    const float* W2  = (const float*)d_in[5];
    const float* b2  = (const float*)d_in[6];
    const float* W3  = (const float*)d_in[7];
    const float* b3  = (const float*)d_in[8];
    float* out = (float*)d_out;

    const int N = in_sizes[0] / N_FEAT;      // 100000
    const int E = in_sizes[2];               // 1600000
    const int NB = (N + (1 << NBW) - 1) >> NBW;

    size_t off = 0;
    auto alloc = [&](size_t bytes) {
        void* p = (char*)d_ws + off;
        off += (bytes + 255) & ~(size_t)255;
        return p;
    };
    float* dis     = (float*)alloc((size_t)N * 4);
    int*   cnt     = (int*)alloc((size_t)N * 4);
    int*   rowp    = (int*)alloc((size_t)N * 4);
    int*   bcnt    = (int*)alloc(256 * 4);
    int*   boff    = (int*)alloc(256 * 4);
    int*   bcur    = (int*)alloc(256 * 4);
    int2*  csr     = (int2*)alloc((size_t)E * 8);
    int2*  ebuf    = (int2*)alloc((size_t)E * 8);
    u16*   bufA16  = (u16*)alloc((size_t)N * 64 * 2);    // bf16 agg output (gemm input)
    u16*   hwB     = (u16*)alloc((size_t)N * 64 * 2);    // bf16 gemm output (gather side)
    u16*   hw16    = (u16*)alloc((size_t)N * 16 * 2);    // bf16 layer-3 gemm output
    float* W3p     = (float*)alloc(64 * 64 * 4);

    const int TB = 256;

    // CSR build
    hipMemsetAsync(bcnt, 0, 256 * 4, stream);
    coarse_hist<<<512, TB, 0, stream>>>(ei, bcnt, E, NB);
    scan_pad<<<17, TB, 0, stream>>>(bcnt, boff, bcur, NB, W3, W3p);
    partition<<<(E + 2047) / 2048, TB, 0, stream>>>(ei, ew, bcur, ebuf, E, NB);
    bucket_csr<<<NB, TB, 0, stream>>>(ebuf, boff, bcnt, csr, rowp, cnt, dis, N);
    fold_dis<<<(E + TB - 1) / TB, TB, 0, stream>>>(csr, dis, E);

    const int GB = 1024;                     // gemm blocks (4096 waves)
    int ablk64 = (N * 8 + TB - 1) / TB;      // 8 lanes/node
    int ablk16 = (N * 2 + TB - 1) / TB;      // 2 lanes/node

    float* logits = out + (size_t)N * 16;
    float* logits2 = out + (size_t)2 * N * 16;

    // layer 1
    gemm_rv<64, false><<<GB, TB, 0, stream>>>(x, W1, hwB, N);
    aggregate<64, true, false><<<ablk64, TB, 0, stream>>>(hwB, rowp, cnt, csr, dis, b1, bufA16, nullptr, nullptr, N);
    // layer 2
    gemm_rv<64, true><<<GB, TB, 0, stream>>>(bufA16, W2, hwB, N);
    aggregate<64, true, false><<<ablk64, TB, 0, stream>>>(hwB, rowp, cnt, csr, dis, b2, bufA16, nullptr, nullptr, N);
    // layer 3 + fused log-softmax
    gemm_rv<16, true><<<GB, TB, 0, stream>>>(bufA16, W3p, hw16, N);
    aggregate<16, false, true><<<ablk16, TB, 0, stream>>>(hw16, rowp, cnt, csr, dis, b3, out, logits, logits2, N);
}

// Round 13
// 249.796 us; speedup vs baseline: 1.7592x; 1.7592x over previous
//
#include <hip/hip_runtime.h>
#include <hip/hip_bf16.h>

#define N_FEAT 64
#define NBW 9                      // log2(nodes per bucket) = 512
#define SRC_BITS 23                // key = (dstLocal << 23) | src ; src < 2^23

typedef unsigned short u16;

__device__ inline u16 f2bf(float f) {           // RNE f32 -> bf16
    unsigned u = __float_as_uint(f);
    u += 0x7fffu + ((u >> 16) & 1u);
    return (u16)(u >> 16);
}

// ---------------- CSR build: two-level bucket partition ----------------

__global__ __launch_bounds__(256) void coarse_hist(const int* __restrict__ ei, int* bcnt, int E, int NB) {
    __shared__ int h[256];
    int tid = threadIdx.x;
    h[tid] = 0;
    __syncthreads();
    for (int e = blockIdx.x * blockDim.x + tid; e < E; e += gridDim.x * blockDim.x)
        atomicAdd(&h[ei[E + e] >> NBW], 1);
    __syncthreads();
    if (tid < NB && h[tid]) atomicAdd(&bcnt[tid], h[tid]);
}

// block 0: exclusive scan of bucket counts; blocks 1..16: pad W3 to 64x64
__global__ __launch_bounds__(256) void scan_pad(const int* __restrict__ bcnt, int* boff, int* bcur, int NB,
                                                const float* __restrict__ W3, float* __restrict__ W3p) {
    if (blockIdx.x == 0) {
        __shared__ int wsum[4];
        int tid = threadIdx.x, lane = tid & 63, w = tid >> 6;
        int v = (tid < NB) ? bcnt[tid] : 0;
        int incl = v;
        #pragma unroll
        for (int o = 1; o < 64; o <<= 1) { int t = __shfl_up(incl, o); if (lane >= o) incl += t; }
        if (lane == 63) wsum[w] = incl;
        __syncthreads();
        int add = 0;
        #pragma unroll
        for (int i = 0; i < 4; ++i) if (i < w) add += wsum[i];
        int excl = add + incl - v;
        if (tid < NB) { boff[tid] = excl; bcur[tid] = excl; }
    } else {
        int i = (blockIdx.x - 1) * 256 + threadIdx.x;
        if (i < 64 * 64) {
            int k = i >> 6, c = i & 63;
            W3p[i] = (c < 16) ? W3[k * 16 + c] : 0.0f;
        }
    }
}

__global__ __launch_bounds__(256) void partition(const int* __restrict__ ei, const float* __restrict__ ew,
                                                 int* bcur, int2* __restrict__ ebuf, int E, int NB) {
    constexpr int EPT = 8;
    __shared__ int cnt[256];
    __shared__ int base[256];
    int tid = threadIdx.x;
    cnt[tid] = 0;
    __syncthreads();
    int start = blockIdx.x * (256 * EPT);

    int d[EPT], r[EPT], s[EPT]; float w[EPT];
    #pragma unroll
    for (int i = 0; i < EPT; ++i) {
        int e = start + i * 256 + tid;
        if (e < E) {
            d[i] = ei[E + e];
            s[i] = ei[e];
            w[i] = ew[e];
            r[i] = atomicAdd(&cnt[d[i] >> NBW], 1);
        } else d[i] = -1;
    }
    __syncthreads();
    if (tid < NB && cnt[tid]) base[tid] = atomicAdd(&bcur[tid], cnt[tid]);
    __syncthreads();
    #pragma unroll
    for (int i = 0; i < EPT; ++i) {
        if (d[i] >= 0) {
            int b = d[i] >> NBW;
            int dl = d[i] & ((1 << NBW) - 1);
            int key = (dl << SRC_BITS) | s[i];
            ebuf[base[b] + r[i]] = make_int2(key, __float_as_int(w[i]));
        }
    }
}

__global__ __launch_bounds__(256) void bucket_csr(const int2* __restrict__ ebuf, const int* __restrict__ boff,
                                                  const int* __restrict__ bcnt,
                                                  int2* __restrict__ csr, int* __restrict__ rowp,
                                                  int* __restrict__ cnt, float* __restrict__ dis, int N) {
    __shared__ int   h[512];
    __shared__ float ws[512];
    __shared__ int   off[512];
    __shared__ int   wsum[4];
    int b = blockIdx.x, tid = threadIdx.x;
    int nbase = b << NBW;
    int nn = min(512, N - nbase);
    int beg = boff[b], m = bcnt[b];

    h[tid] = 0; h[tid + 256] = 0;
    ws[tid] = 0.f; ws[tid + 256] = 0.f;
    __syncthreads();

    for (int i = tid; i < m; i += 256) {
        int2 en = ebuf[beg + i];
        int dl = ((unsigned)en.x) >> SRC_BITS;
        atomicAdd(&h[dl], 1);
        atomicAdd(&ws[dl], __int_as_float(en.y));
    }
    __syncthreads();

    int v0 = h[2 * tid], v1 = h[2 * tid + 1];
    int v = v0 + v1;
    int lane = tid & 63, wv = tid >> 6;
    int incl = v;
    #pragma unroll
    for (int o = 1; o < 64; o <<= 1) { int t = __shfl_up(incl, o); if (lane >= o) incl += t; }
    if (lane == 63) wsum[wv] = incl;
    __syncthreads();
    int add = 0;
    #pragma unroll
    for (int i = 0; i < 4; ++i) if (i < wv) add += wsum[i];
    int excl = add + incl - v;
    off[2 * tid] = excl;
    off[2 * tid + 1] = excl + v0;
    __syncthreads();

    for (int l = tid; l < nn; l += 256) {
        rowp[nbase + l] = beg + off[l];
        cnt[nbase + l]  = h[l];
        dis[nbase + l]  = rsqrtf(1.0f + ws[l]);
    }
    __syncthreads();
    h[tid] = 0; h[tid + 256] = 0;
    __syncthreads();

    for (int i = tid; i < m; i += 256) {
        int2 en = ebuf[beg + i];
        unsigned k = (unsigned)en.x;
        int dl  = k >> SRC_BITS;
        int src = k & ((1 << SRC_BITS) - 1);
        int pos = atomicAdd(&h[dl], 1);
        csr[beg + off[dl] + pos] = make_int2(src, en.y);
    }
}

// fold dis[src] into stored weight
__global__ __launch_bounds__(256) void fold_dis(int2* __restrict__ csr, const float* __restrict__ dis, int E) {
    int i = blockIdx.x * blockDim.x + threadIdx.x;
    if (i < E) {
        int2 en = csr[i];
        en.y = __float_as_int(__int_as_float(en.y) * dis[en.x]);
        csr[i] = en;
    }
}

// ---------------- GEMM: one ROW per LANE, W via scalar cache ----------------
// C_bf16[N x OUTW] = A[N x 64] @ W[64 x 64]; A f32 or bf16 (INBF).
// Wave = 64 rows (one per lane) x COLS output columns (CS-way column split).
// A row chunks: per-lane vector loads (streams 25.6MB on the VMEM path, L1
// line reuse 4-16x). W[k][c]: wave-uniform index (readfirstlane'd wave id)
// -> s_load through the 16KB-resident scalar cache, v_fmac(sgpr, vgpr).
// This is the transpose of R6 (W was in VGPRs, A through scalar cache: 41us)
// and avoids R12's per-wave 16KB W re-read from VMEM (64MB/launch: 127us).

template<int OUTW, bool INBF, int CS>
__global__ __launch_bounds__(256) void gemm_rs(const void* __restrict__ Av, const float* __restrict__ W,
                                               u16* __restrict__ C, int N) {
    constexpr int COLS = OUTW / CS;        // 32 (OUTW=64,CS=2) or 16 (OUTW=16,CS=1)
    int lane = threadIdx.x & 63;
    int wv   = (int)((blockIdx.x * blockDim.x + threadIdx.x) >> 6);
    int wvu  = __builtin_amdgcn_readfirstlane(wv);   // wave-uniform wave id
    int tile = wvu / CS;
    int cbase = (wvu % CS) * COLS;                   // uniform -> W via s_load

    int row = tile * 64 + lane;
    bool alive = (row < N);
    int r = min(row, N - 1);

    float acc[COLS] = {};

    if (INBF) {
        const uint4* arow = (const uint4*)((const u16*)Av + (size_t)r * 64);  // 8 uint4
        #pragma unroll 2
        for (int kq = 0; kq < 8; ++kq) {
            uint4 v = arow[kq];
            unsigned p[4] = {v.x, v.y, v.z, v.w};
            #pragma unroll
            for (int d = 0; d < 4; ++d) {
                float alo = __uint_as_float(p[d] << 16);
                float ahi = __uint_as_float(p[d] & 0xffff0000u);
                int k = kq * 8 + 2 * d;
                #pragma unroll
                for (int c = 0; c < COLS; ++c)
                    acc[c] = fmaf(alo, W[k * 64 + cbase + c], acc[c]);
                #pragma unroll
                for (int c = 0; c < COLS; ++c)
                    acc[c] = fmaf(ahi, W[(k + 1) * 64 + cbase + c], acc[c]);
            }
        }
    } else {
        const float4* arow = (const float4*)((const float*)Av + (size_t)r * 64); // 16 float4
        #pragma unroll 4
        for (int kq = 0; kq < 16; ++kq) {
            float4 v = arow[kq];
            float a[4] = {v.x, v.y, v.z, v.w};
            #pragma unroll
            for (int d = 0; d < 4; ++d) {
                int k = kq * 4 + d;
                #pragma unroll
                for (int c = 0; c < COLS; ++c)
                    acc[c] = fmaf(a[d], W[k * 64 + cbase + c], acc[c]);
            }
        }
    }

    if (alive) {
        u16* dst = C + (size_t)row * OUTW + cbase;
        unsigned pk[COLS / 2];
        #pragma unroll
        for (int i = 0; i < COLS / 2; ++i)
            pk[i] = (unsigned)f2bf(acc[2 * i]) | ((unsigned)f2bf(acc[2 * i + 1]) << 16);
        #pragma unroll
        for (int q = 0; q < COLS / 8; ++q)
            ((uint4*)dst)[q] = make_uint4(pk[4 * q], pk[4 * q + 1], pk[4 * q + 2], pk[4 * q + 3]);
    }
}

// ---------------- Aggregation: one node per 8-lane GROUP (shuffle-free) ------

template<int F, bool RELU, bool FINAL>
__global__ __launch_bounds__(256) void aggregate(const u16* __restrict__ hw, const int* __restrict__ rowp,
                                                 const int* __restrict__ cnt, const int2* __restrict__ csr,
                                                 const float* __restrict__ dis,
                                                 const float* __restrict__ bias, void* __restrict__ outv,
                                                 float* __restrict__ out2, float* __restrict__ out3, int N) {
    constexpr int GL   = F / 8;          // lanes per group/node (8 for F=64, 2 for F=16)
    constexpr int NPW  = 64 / GL;        // nodes per wave (8 or 32)
    constexpr unsigned ROWB = F * 2;     // row bytes (128 or 32)

    int wv   = (int)((blockIdx.x * blockDim.x + threadIdx.x) >> 6);
    int lane = threadIdx.x & 63;
    int g = lane / GL;
    int t = lane % GL;
    int n = wv * NPW + g;
    bool alive = (n < N);
    n = min(n, N - 1);

    float dd = dis[n];
    int beg = rowp[n];
    int c   = cnt[n];
    const char* hwb = (const char*)hw;
    unsigned toff = (unsigned)t * 16u;

    float acc[8];
    {   // self loop (weight 1)
        uint4 raw = *(const uint4*)(hwb + (unsigned)n * ROWB + toff);
        float w = dd * dd;
        unsigned uw[4] = {raw.x, raw.y, raw.z, raw.w};
        #pragma unroll
        for (int k = 0; k < 4; ++k) {
            acc[2 * k]     = w * __uint_as_float(uw[k] << 16);
            acc[2 * k + 1] = w * __uint_as_float(uw[k] & 0xffff0000u);
        }
    }

    int j = 0;
    for (; j + 4 <= c; j += 4) {         // 4 independent gathers in flight
        int2 e0 = csr[beg + j];
        int2 e1 = csr[beg + j + 1];
        int2 e2 = csr[beg + j + 2];
        int2 e3 = csr[beg + j + 3];
        uint4 r0 = *(const uint4*)(hwb + (unsigned)e0.x * ROWB + toff);
        uint4 r1 = *(const uint4*)(hwb + (unsigned)e1.x * ROWB + toff);
        uint4 r2 = *(const uint4*)(hwb + (unsigned)e2.x * ROWB + toff);
        uint4 r3 = *(const uint4*)(hwb + (unsigned)e3.x * ROWB + toff);
        float w0 = __int_as_float(e0.y) * dd;
        float w1 = __int_as_float(e1.y) * dd;
        float w2 = __int_as_float(e2.y) * dd;
        float w3 = __int_as_float(e3.y) * dd;
        unsigned ua[4] = {r0.x, r0.y, r0.z, r0.w};
        unsigned ub[4] = {r1.x, r1.y, r1.z, r1.w};
        unsigned uc[4] = {r2.x, r2.y, r2.z, r2.w};
        unsigned ud[4] = {r3.x, r3.y, r3.z, r3.w};
        #pragma unroll
        for (int k = 0; k < 4; ++k) {
            acc[2 * k]     = fmaf(w0, __uint_as_float(ua[k] << 16), acc[2 * k]);
            acc[2 * k + 1] = fmaf(w0, __uint_as_float(ua[k] & 0xffff0000u), acc[2 * k + 1]);
            acc[2 * k]     = fmaf(w1, __uint_as_float(ub[k] << 16), acc[2 * k]);
            acc[2 * k + 1] = fmaf(w1, __uint_as_float(ub[k] & 0xffff0000u), acc[2 * k + 1]);
            acc[2 * k]     = fmaf(w2, __uint_as_float(uc[k] << 16), acc[2 * k]);
            acc[2 * k + 1] = fmaf(w2, __uint_as_float(uc[k] & 0xffff0000u), acc[2 * k + 1]);
            acc[2 * k]     = fmaf(w3, __uint_as_float(ud[k] << 16), acc[2 * k]);
            acc[2 * k + 1] = fmaf(w3, __uint_as_float(ud[k] & 0xffff0000u), acc[2 * k + 1]);
        }
    }
    for (; j < c; ++j) {                 // tail (<=3)
        int2 e = csr[beg + j];
        uint4 r = *(const uint4*)(hwb + (unsigned)e.x * ROWB + toff);
        float w = __int_as_float(e.y) * dd;
        unsigned u[4] = {r.x, r.y, r.z, r.w};
        #pragma unroll
        for (int k = 0; k < 4; ++k) {
            acc[2 * k]     = fmaf(w, __uint_as_float(u[k] << 16), acc[2 * k]);
            acc[2 * k + 1] = fmaf(w, __uint_as_float(u[k] & 0xffff0000u), acc[2 * k + 1]);
        }
    }

    if (alive) {
        float4 b0 = *(const float4*)&bias[t * 8];
        float4 b1 = *(const float4*)&bias[t * 8 + 4];
        acc[0] += b0.x; acc[1] += b0.y; acc[2] += b0.z; acc[3] += b0.w;
        acc[4] += b1.x; acc[5] += b1.y; acc[6] += b1.z; acc[7] += b1.w;
        if (RELU) {
            #pragma unroll
            for (int k = 0; k < 8; ++k) acc[k] = fmaxf(acc[k], 0.0f);
        }
        if (!FINAL) {
            u16* o16 = (u16*)outv;
            uint4 pk;
            pk.x = (unsigned)f2bf(acc[0]) | ((unsigned)f2bf(acc[1]) << 16);
            pk.y = (unsigned)f2bf(acc[2]) | ((unsigned)f2bf(acc[3]) << 16);
            pk.z = (unsigned)f2bf(acc[4]) | ((unsigned)f2bf(acc[5]) << 16);
            pk.w = (unsigned)f2bf(acc[6]) | ((unsigned)f2bf(acc[7]) << 16);
            *(uint4*)&o16[(size_t)n * F + t * 8] = pk;
        } else {
            float4 r0 = make_float4(acc[0], acc[1], acc[2], acc[3]);
            float4 r1 = make_float4(acc[4], acc[5], acc[6], acc[7]);
            *(float4*)&out2[(size_t)n * F + t * 8] = r0;
            *(float4*)&out2[(size_t)n * F + t * 8 + 4] = r1;
            *(float4*)&out3[(size_t)n * F + t * 8] = r0;
            *(float4*)&out3[(size_t)n * F + t * 8 + 4] = r1;
            float mloc = acc[0];
            #pragma unroll
            for (int k = 1; k < 8; ++k) mloc = fmaxf(mloc, acc[k]);
            float m = fmaxf(mloc, __shfl_xor(mloc, 1));   // partner lane same group, same alive
            float sloc = 0.f;
            #pragma unroll
            for (int k = 0; k < 8; ++k) sloc += __expf(acc[k] - m);
            float ssum = sloc + __shfl_xor(sloc, 1);
            float ls = m + __logf(ssum);
            float* o = (float*)outv;
            float4 w0 = make_float4(acc[0] - ls, acc[1] - ls, acc[2] - ls, acc[3] - ls);
            float4 w1 = make_float4(acc[4] - ls, acc[5] - ls, acc[6] - ls, acc[7] - ls);
            *(float4*)&o[(size_t)n * F + t * 8] = w0;
            *(float4*)&o[(size_t)n * F + t * 8 + 4] = w1;
        }
    }
}

// ---------------- launch ----------------

extern "C" void kernel_launch(void* const* d_in, const int* in_sizes, int n_in,
                              void* d_out, int out_size, void* d_ws, size_t ws_size,
                              hipStream_t stream) {
    const float* x   = (const float*)d_in[0];
    const int*   ei  = (const int*)d_in[1];
    const float* ew  = (const float*)d_in[2];
    const float* W1  = (const float*)d_in[3];
    const float* b1  = (const float*)d_in[4];
    const float* W2  = (const float*)d_in[5];
    const float* b2  = (const float*)d_in[6];
    const float* W3  = (const float*)d_in[7];
    const float* b3  = (const float*)d_in[8];
    float* out = (float*)d_out;

    const int N = in_sizes[0] / N_FEAT;      // 100000
    const int E = in_sizes[2];               // 1600000
    const int NB = (N + (1 << NBW) - 1) >> NBW;

    size_t off = 0;
    auto alloc = [&](size_t bytes) {
        void* p = (char*)d_ws + off;
        off += (bytes + 255) & ~(size_t)255;
        return p;
    };
    float* dis     = (float*)alloc((size_t)N * 4);
    int*   cnt     = (int*)alloc((size_t)N * 4);
    int*   rowp    = (int*)alloc((size_t)N * 4);
    int*   bcnt    = (int*)alloc(256 * 4);
    int*   boff    = (int*)alloc(256 * 4);
    int*   bcur    = (int*)alloc(256 * 4);
    int2*  csr     = (int2*)alloc((size_t)E * 8);
    int2*  ebuf    = (int2*)alloc((size_t)E * 8);
    u16*   bufA16  = (u16*)alloc((size_t)N * 64 * 2);    // bf16 agg output (gemm input)
    u16*   hwB     = (u16*)alloc((size_t)N * 64 * 2);    // bf16 gemm output (gather side)
    u16*   hw16    = (u16*)alloc((size_t)N * 16 * 2);    // bf16 layer-3 gemm output
    float* W3p     = (float*)alloc(64 * 64 * 4);

    const int TB = 256;

    // CSR build
    hipMemsetAsync(bcnt, 0, 256 * 4, stream);
    coarse_hist<<<512, TB, 0, stream>>>(ei, bcnt, E, NB);
    scan_pad<<<17, TB, 0, stream>>>(bcnt, boff, bcur, NB, W3, W3p);
    partition<<<(E + 2047) / 2048, TB, 0, stream>>>(ei, ew, bcur, ebuf, E, NB);
    bucket_csr<<<NB, TB, 0, stream>>>(ebuf, boff, bcnt, csr, rowp, cnt, dis, N);
    fold_dis<<<(E + TB - 1) / TB, TB, 0, stream>>>(csr, dis, E);

    int tiles = (N + 63) / 64;
    int gb64  = (tiles * 2 + 3) / 4;         // CS=2: 2 waves per 64-row tile
    int gb16  = (tiles + 3) / 4;             // CS=1
    int ablk64 = (N * 8 + TB - 1) / TB;      // 8 lanes/node
    int ablk16 = (N * 2 + TB - 1) / TB;      // 2 lanes/node

    float* logits = out + (size_t)N * 16;
    float* logits2 = out + (size_t)2 * N * 16;

    // layer 1
    gemm_rs<64, false, 2><<<gb64, TB, 0, stream>>>(x, W1, hwB, N);
    aggregate<64, true, false><<<ablk64, TB, 0, stream>>>(hwB, rowp, cnt, csr, dis, b1, bufA16, nullptr, nullptr, N);
    // layer 2
    gemm_rs<64, true, 2><<<gb64, TB, 0, stream>>>(bufA16, W2, hwB, N);
    aggregate<64, true, false><<<ablk64, TB, 0, stream>>>(hwB, rowp, cnt, csr, dis, b2, bufA16, nullptr, nullptr, N);
    // layer 3 + fused log-softmax
    gemm_rs<16, true, 1><<<gb16, TB, 0, stream>>>(bufA16, W3p, hw16, N);
    aggregate<16, false, true><<<ablk16, TB, 0, stream>>>(hw16, rowp, cnt, csr, dis, b3, out, logits, logits2, N);
}

// Round 14
// 205.177 us; speedup vs baseline: 2.1418x; 1.2175x over previous
//
#include <hip/hip_runtime.h>
#include <hip/hip_bf16.h>

#define N_FEAT 64
#define NBW 9                      // log2(nodes per bucket) = 512
#define SRC_BITS 23                // key = (dstLocal << 23) | src ; src < 2^23

typedef unsigned short u16;
typedef __attribute__((ext_vector_type(8))) short short8;   // 8 bf16 (4 VGPRs)
typedef __attribute__((ext_vector_type(4))) float f32x4;    // MFMA C/D

__device__ inline u16 f2bf(float f) {           // RNE f32 -> bf16
    unsigned u = __float_as_uint(f);
    u += 0x7fffu + ((u >> 16) & 1u);
    return (u16)(u >> 16);
}

// ---------------- CSR build: two-level bucket partition ----------------

__global__ __launch_bounds__(256) void coarse_hist(const int* __restrict__ ei, int* bcnt, int E, int NB) {
    __shared__ int h[256];
    int tid = threadIdx.x;
    h[tid] = 0;
    __syncthreads();
    for (int e = blockIdx.x * blockDim.x + tid; e < E; e += gridDim.x * blockDim.x)
        atomicAdd(&h[ei[E + e] >> NBW], 1);
    __syncthreads();
    if (tid < NB && h[tid]) atomicAdd(&bcnt[tid], h[tid]);
}

// pack W[64 x wcols] into MFMA B-fragment order:
// frag f = (cb*2+s)*64+lane ; elem i -> W[(s*32+(lane>>4)*8+i)*wcols + cb*16+(lane&15)]
__device__ inline void packW(const float* __restrict__ W, uint4* __restrict__ Wpk,
                             int ncb, int wcols, int tid) {
    int nf = ncb * 2 * 64;
    for (int f = tid; f < nf; f += 256) {
        int cb = f >> 7;
        int s  = (f >> 6) & 1;
        int lane = f & 63;
        int kb = lane >> 4, c16 = lane & 15;
        union { uint4 q; u16 u[8]; } pk;
        #pragma unroll
        for (int i = 0; i < 8; ++i) {
            int k = s * 32 + kb * 8 + i;
            pk.u[i] = f2bf(W[k * wcols + cb * 16 + c16]);
        }
        Wpk[f] = pk.q;
    }
}

// block 0: exclusive scan of bucket counts; blocks 1-3: pack W1/W2/W3
__global__ __launch_bounds__(256) void scan_pad(const int* __restrict__ bcnt, int* boff, int* bcur, int NB,
                                                const float* __restrict__ W1, const float* __restrict__ W2,
                                                const float* __restrict__ W3,
                                                uint4* Wp1, uint4* Wp2, uint4* Wp3) {
    if (blockIdx.x == 0) {
        __shared__ int wsum[4];
        int tid = threadIdx.x, lane = tid & 63, w = tid >> 6;
        int v = (tid < NB) ? bcnt[tid] : 0;
        int incl = v;
        #pragma unroll
        for (int o = 1; o < 64; o <<= 1) { int t = __shfl_up(incl, o); if (lane >= o) incl += t; }
        if (lane == 63) wsum[w] = incl;
        __syncthreads();
        int add = 0;
        #pragma unroll
        for (int i = 0; i < 4; ++i) if (i < w) add += wsum[i];
        int excl = add + incl - v;
        if (tid < NB) { boff[tid] = excl; bcur[tid] = excl; }
    } else if (blockIdx.x == 1) {
        packW(W1, Wp1, 4, 64, threadIdx.x);
    } else if (blockIdx.x == 2) {
        packW(W2, Wp2, 4, 64, threadIdx.x);
    } else {
        packW(W3, Wp3, 1, 16, threadIdx.x);
    }
}

__global__ __launch_bounds__(256) void partition(const int* __restrict__ ei, const float* __restrict__ ew,
                                                 int* bcur, int2* __restrict__ ebuf, int E, int NB) {
    constexpr int EPT = 8;
    __shared__ int cnt[256];
    __shared__ int base[256];
    int tid = threadIdx.x;
    cnt[tid] = 0;
    __syncthreads();
    int start = blockIdx.x * (256 * EPT);

    int d[EPT], r[EPT], s[EPT]; float w[EPT];
    #pragma unroll
    for (int i = 0; i < EPT; ++i) {
        int e = start + i * 256 + tid;
        if (e < E) {
            d[i] = ei[E + e];
            s[i] = ei[e];
            w[i] = ew[e];
            r[i] = atomicAdd(&cnt[d[i] >> NBW], 1);
        } else d[i] = -1;
    }
    __syncthreads();
    if (tid < NB && cnt[tid]) base[tid] = atomicAdd(&bcur[tid], cnt[tid]);
    __syncthreads();
    #pragma unroll
    for (int i = 0; i < EPT; ++i) {
        if (d[i] >= 0) {
            int b = d[i] >> NBW;
            int dl = d[i] & ((1 << NBW) - 1);
            int key = (dl << SRC_BITS) | s[i];
            ebuf[base[b] + r[i]] = make_int2(key, __float_as_int(w[i]));
        }
    }
}

__global__ __launch_bounds__(256) void bucket_csr(const int2* __restrict__ ebuf, const int* __restrict__ boff,
                                                  const int* __restrict__ bcnt,
                                                  int2* __restrict__ csr, int* __restrict__ rowp,
                                                  int* __restrict__ cnt, float* __restrict__ dis, int N) {
    __shared__ int   h[512];
    __shared__ float ws[512];
    __shared__ int   off[512];
    __shared__ int   wsum[4];
    int b = blockIdx.x, tid = threadIdx.x;
    int nbase = b << NBW;
    int nn = min(512, N - nbase);
    int beg = boff[b], m = bcnt[b];

    h[tid] = 0; h[tid + 256] = 0;
    ws[tid] = 0.f; ws[tid + 256] = 0.f;
    __syncthreads();

    for (int i = tid; i < m; i += 256) {
        int2 en = ebuf[beg + i];
        int dl = ((unsigned)en.x) >> SRC_BITS;
        atomicAdd(&h[dl], 1);
        atomicAdd(&ws[dl], __int_as_float(en.y));
    }
    __syncthreads();

    int v0 = h[2 * tid], v1 = h[2 * tid + 1];
    int v = v0 + v1;
    int lane = tid & 63, wv = tid >> 6;
    int incl = v;
    #pragma unroll
    for (int o = 1; o < 64; o <<= 1) { int t = __shfl_up(incl, o); if (lane >= o) incl += t; }
    if (lane == 63) wsum[wv] = incl;
    __syncthreads();
    int add = 0;
    #pragma unroll
    for (int i = 0; i < 4; ++i) if (i < wv) add += wsum[i];
    int excl = add + incl - v;
    off[2 * tid] = excl;
    off[2 * tid + 1] = excl + v0;
    __syncthreads();

    for (int l = tid; l < nn; l += 256) {
        rowp[nbase + l] = beg + off[l];
        cnt[nbase + l]  = h[l];
        dis[nbase + l]  = rsqrtf(1.0f + ws[l]);
    }
    __syncthreads();
    h[tid] = 0; h[tid + 256] = 0;
    __syncthreads();

    for (int i = tid; i < m; i += 256) {
        int2 en = ebuf[beg + i];
        unsigned k = (unsigned)en.x;
        int dl  = k >> SRC_BITS;
        int src = k & ((1 << SRC_BITS) - 1);
        int pos = atomicAdd(&h[dl], 1);
        csr[beg + off[dl] + pos] = make_int2(src, en.y);
    }
}

// fold dis[src] into stored weight
__global__ __launch_bounds__(256) void fold_dis(int2* __restrict__ csr, const float* __restrict__ dis, int E) {
    int i = blockIdx.x * blockDim.x + threadIdx.x;
    if (i < E) {
        int2 en = csr[i];
        en.y = __float_as_int(__int_as_float(en.y) * dis[en.x]);
        csr[i] = en;
    }
}

// ---------------- GEMM via MFMA 16x16x32 bf16 ----------------
// C_bf16[N x OUTW] = A[N x 64] @ W[64 x OUTW]; A f32 (converted in-register)
// or bf16 (INBF). One 16-row tile per wave; K=64 -> 2 MFMAs per 16x16 block.
// Fragment layouts (m89/m91-verified): A/B lane = (idx&15) + 16*kblk, 8
// k-elems/lane; C/D col = lane&15, row = (lane>>4)*4 + reg. W pre-packed into
// B-fragment order by scan_pad (Wpk[(cb*2+s)*64+lane] = uint4 of 8 bf16).

template<int OUTW, bool INBF>
__global__ __launch_bounds__(256) void gemm_mf(const void* __restrict__ Av, const uint4* __restrict__ Wpk,
                                               u16* __restrict__ C, int N) {
    constexpr int NCB = OUTW / 16;
    int lane = threadIdx.x & 63;
    int wid  = (int)((blockIdx.x * blockDim.x + threadIdx.x) >> 6);
    int r0 = wid * 16;
    if (r0 >= N) return;
    int row16 = lane & 15, kb = lane >> 4;
    int r = min(r0 + row16, N - 1);

    short8 a0, a1;
    if (INBF) {
        const u16* arow = (const u16*)Av + (size_t)r * 64 + kb * 8;
        a0 = __builtin_bit_cast(short8, *(const uint4*)arow);
        a1 = __builtin_bit_cast(short8, *(const uint4*)(arow + 32));
    } else {
        const float* arow = (const float*)Av + (size_t)r * 64 + kb * 8;
        float4 f0 = *(const float4*)arow;
        float4 f1 = *(const float4*)(arow + 4);
        float4 f2 = *(const float4*)(arow + 32);
        float4 f3 = *(const float4*)(arow + 36);
        union { short8 v; u16 u[8]; } pa, pb;
        pa.u[0] = f2bf(f0.x); pa.u[1] = f2bf(f0.y); pa.u[2] = f2bf(f0.z); pa.u[3] = f2bf(f0.w);
        pa.u[4] = f2bf(f1.x); pa.u[5] = f2bf(f1.y); pa.u[6] = f2bf(f1.z); pa.u[7] = f2bf(f1.w);
        pb.u[0] = f2bf(f2.x); pb.u[1] = f2bf(f2.y); pb.u[2] = f2bf(f2.z); pb.u[3] = f2bf(f2.w);
        pb.u[4] = f2bf(f3.x); pb.u[5] = f2bf(f3.y); pb.u[6] = f2bf(f3.z); pb.u[7] = f2bf(f3.w);
        a0 = pa.v; a1 = pb.v;
    }

    f32x4 acc[NCB];
    #pragma unroll
    for (int cb = 0; cb < NCB; ++cb) {
        short8 b0 = __builtin_bit_cast(short8, Wpk[(cb * 2 + 0) * 64 + lane]);
        short8 b1 = __builtin_bit_cast(short8, Wpk[(cb * 2 + 1) * 64 + lane]);
        f32x4 z = {0.f, 0.f, 0.f, 0.f};
        z = __builtin_amdgcn_mfma_f32_16x16x32_bf16(a0, b0, z, 0, 0, 0);
        z = __builtin_amdgcn_mfma_f32_16x16x32_bf16(a1, b1, z, 0, 0, 0);
        acc[cb] = z;
    }

    int rbase = r0 + kb * 4;
    #pragma unroll
    for (int cb = 0; cb < NCB; ++cb) {
        int col = cb * 16 + row16;
        #pragma unroll
        for (int j = 0; j < 4; ++j) {
            int rr = rbase + j;
            if (rr < N) C[(size_t)rr * OUTW + col] = f2bf(acc[cb][j]);
        }
    }
}

// ---------------- Aggregation: one node per 8-lane GROUP (shuffle-free) ------

template<int F, bool RELU, bool FINAL>
__global__ __launch_bounds__(256) void aggregate(const u16* __restrict__ hw, const int* __restrict__ rowp,
                                                 const int* __restrict__ cnt, const int2* __restrict__ csr,
                                                 const float* __restrict__ dis,
                                                 const float* __restrict__ bias, void* __restrict__ outv,
                                                 float* __restrict__ out2, float* __restrict__ out3, int N) {
    constexpr int GL   = F / 8;          // lanes per group/node (8 for F=64, 2 for F=16)
    constexpr int NPW  = 64 / GL;        // nodes per wave (8 or 32)
    constexpr unsigned ROWB = F * 2;     // row bytes (128 or 32)

    int wv   = (int)((blockIdx.x * blockDim.x + threadIdx.x) >> 6);
    int lane = threadIdx.x & 63;
    int g = lane / GL;
    int t = lane % GL;
    int n = wv * NPW + g;
    bool alive = (n < N);
    n = min(n, N - 1);

    float dd = dis[n];
    int beg = rowp[n];
    int c   = cnt[n];
    const char* hwb = (const char*)hw;
    unsigned toff = (unsigned)t * 16u;

    float acc[8];
    {   // self loop (weight 1)
        uint4 raw = *(const uint4*)(hwb + (unsigned)n * ROWB + toff);
        float w = dd * dd;
        unsigned uw[4] = {raw.x, raw.y, raw.z, raw.w};
        #pragma unroll
        for (int k = 0; k < 4; ++k) {
            acc[2 * k]     = w * __uint_as_float(uw[k] << 16);
            acc[2 * k + 1] = w * __uint_as_float(uw[k] & 0xffff0000u);
        }
    }

    int j = 0;
    for (; j + 4 <= c; j += 4) {         // 4 independent gathers in flight
        int2 e0 = csr[beg + j];
        int2 e1 = csr[beg + j + 1];
        int2 e2 = csr[beg + j + 2];
        int2 e3 = csr[beg + j + 3];
        uint4 r0 = *(const uint4*)(hwb + (unsigned)e0.x * ROWB + toff);
        uint4 r1 = *(const uint4*)(hwb + (unsigned)e1.x * ROWB + toff);
        uint4 r2 = *(const uint4*)(hwb + (unsigned)e2.x * ROWB + toff);
        uint4 r3 = *(const uint4*)(hwb + (unsigned)e3.x * ROWB + toff);
        float w0 = __int_as_float(e0.y) * dd;
        float w1 = __int_as_float(e1.y) * dd;
        float w2 = __int_as_float(e2.y) * dd;
        float w3 = __int_as_float(e3.y) * dd;
        unsigned ua[4] = {r0.x, r0.y, r0.z, r0.w};
        unsigned ub[4] = {r1.x, r1.y, r1.z, r1.w};
        unsigned uc[4] = {r2.x, r2.y, r2.z, r2.w};
        unsigned ud[4] = {r3.x, r3.y, r3.z, r3.w};
        #pragma unroll
        for (int k = 0; k < 4; ++k) {
            acc[2 * k]     = fmaf(w0, __uint_as_float(ua[k] << 16), acc[2 * k]);
            acc[2 * k + 1] = fmaf(w0, __uint_as_float(ua[k] & 0xffff0000u), acc[2 * k + 1]);
            acc[2 * k]     = fmaf(w1, __uint_as_float(ub[k] << 16), acc[2 * k]);
            acc[2 * k + 1] = fmaf(w1, __uint_as_float(ub[k] & 0xffff0000u), acc[2 * k + 1]);
            acc[2 * k]     = fmaf(w2, __uint_as_float(uc[k] << 16), acc[2 * k]);
            acc[2 * k + 1] = fmaf(w2, __uint_as_float(uc[k] & 0xffff0000u), acc[2 * k + 1]);
            acc[2 * k]     = fmaf(w3, __uint_as_float(ud[k] << 16), acc[2 * k]);
            acc[2 * k + 1] = fmaf(w3, __uint_as_float(ud[k] & 0xffff0000u), acc[2 * k + 1]);
        }
    }
    for (; j < c; ++j) {                 // tail (<=3)
        int2 e = csr[beg + j];
        uint4 r = *(const uint4*)(hwb + (unsigned)e.x * ROWB + toff);
        float w = __int_as_float(e.y) * dd;
        unsigned u[4] = {r.x, r.y, r.z, r.w};
        #pragma unroll
        for (int k = 0; k < 4; ++k) {
            acc[2 * k]     = fmaf(w, __uint_as_float(u[k] << 16), acc[2 * k]);
            acc[2 * k + 1] = fmaf(w, __uint_as_float(u[k] & 0xffff0000u), acc[2 * k + 1]);
        }
    }

    if (alive) {
        float4 b0 = *(const float4*)&bias[t * 8];
        float4 b1 = *(const float4*)&bias[t * 8 + 4];
        acc[0] += b0.x; acc[1] += b0.y; acc[2] += b0.z; acc[3] += b0.w;
        acc[4] += b1.x; acc[5] += b1.y; acc[6] += b1.z; acc[7] += b1.w;
        if (RELU) {
            #pragma unroll
            for (int k = 0; k < 8; ++k) acc[k] = fmaxf(acc[k], 0.0f);
        }
        if (!FINAL) {
            u16* o16 = (u16*)outv;
            uint4 pk;
            pk.x = (unsigned)f2bf(acc[0]) | ((unsigned)f2bf(acc[1]) << 16);
            pk.y = (unsigned)f2bf(acc[2]) | ((unsigned)f2bf(acc[3]) << 16);
            pk.z = (unsigned)f2bf(acc[4]) | ((unsigned)f2bf(acc[5]) << 16);
            pk.w = (unsigned)f2bf(acc[6]) | ((unsigned)f2bf(acc[7]) << 16);
            *(uint4*)&o16[(size_t)n * F + t * 8] = pk;
        } else {
            float4 r0 = make_float4(acc[0], acc[1], acc[2], acc[3]);
            float4 r1 = make_float4(acc[4], acc[5], acc[6], acc[7]);
            *(float4*)&out2[(size_t)n * F + t * 8] = r0;
            *(float4*)&out2[(size_t)n * F + t * 8 + 4] = r1;
            *(float4*)&out3[(size_t)n * F + t * 8] = r0;
            *(float4*)&out3[(size_t)n * F + t * 8 + 4] = r1;
            float mloc = acc[0];
            #pragma unroll
            for (int k = 1; k < 8; ++k) mloc = fmaxf(mloc, acc[k]);
            float m = fmaxf(mloc, __shfl_xor(mloc, 1));   // partner lane same group, same alive
            float sloc = 0.f;
            #pragma unroll
            for (int k = 0; k < 8; ++k) sloc += __expf(acc[k] - m);
            float ssum = sloc + __shfl_xor(sloc, 1);
            float ls = m + __logf(ssum);
            float* o = (float*)outv;
            float4 w0 = make_float4(acc[0] - ls, acc[1] - ls, acc[2] - ls, acc[3] - ls);
            float4 w1 = make_float4(acc[4] - ls, acc[5] - ls, acc[6] - ls, acc[7] - ls);
            *(float4*)&o[(size_t)n * F + t * 8] = w0;
            *(float4*)&o[(size_t)n * F + t * 8 + 4] = w1;
        }
    }
}

// ---------------- launch ----------------

extern "C" void kernel_launch(void* const* d_in, const int* in_sizes, int n_in,
                              void* d_out, int out_size, void* d_ws, size_t ws_size,
                              hipStream_t stream) {
    const float* x   = (const float*)d_in[0];
    const int*   ei  = (const int*)d_in[1];
    const float* ew  = (const float*)d_in[2];
    const float* W1  = (const float*)d_in[3];
    const float* b1  = (const float*)d_in[4];
    const float* W2  = (const float*)d_in[5];
    const float* b2  = (const float*)d_in[6];
    const float* W3  = (const float*)d_in[7];
    const float* b3  = (const float*)d_in[8];
    float* out = (float*)d_out;

    const int N = in_sizes[0] / N_FEAT;      // 100000
    const int E = in_sizes[2];               // 1600000
    const int NB = (N + (1 << NBW) - 1) >> NBW;

    size_t off = 0;
    auto alloc = [&](size_t bytes) {
        void* p = (char*)d_ws + off;
        off += (bytes + 255) & ~(size_t)255;
        return p;
    };
    float* dis     = (float*)alloc((size_t)N * 4);
    int*   cnt     = (int*)alloc((size_t)N * 4);
    int*   rowp    = (int*)alloc((size_t)N * 4);
    int*   bcnt    = (int*)alloc(256 * 4);
    int*   boff    = (int*)alloc(256 * 4);
    int*   bcur    = (int*)alloc(256 * 4);
    int2*  csr     = (int2*)alloc((size_t)E * 8);
    int2*  ebuf    = (int2*)alloc((size_t)E * 8);
    u16*   bufA16  = (u16*)alloc((size_t)N * 64 * 2);    // bf16 agg output (gemm input)
    u16*   hwB     = (u16*)alloc((size_t)N * 64 * 2);    // bf16 gemm output (gather side)
    u16*   hw16    = (u16*)alloc((size_t)N * 16 * 2);    // bf16 layer-3 gemm output
    uint4* Wp1     = (uint4*)alloc(512 * 16);            // B-fragment-packed weights
    uint4* Wp2     = (uint4*)alloc(512 * 16);
    uint4* Wp3     = (uint4*)alloc(128 * 16);

    const int TB = 256;

    // CSR build + weight packing
    hipMemsetAsync(bcnt, 0, 256 * 4, stream);
    coarse_hist<<<512, TB, 0, stream>>>(ei, bcnt, E, NB);
    scan_pad<<<4, TB, 0, stream>>>(bcnt, boff, bcur, NB, W1, W2, W3, Wp1, Wp2, Wp3);
    partition<<<(E + 2047) / 2048, TB, 0, stream>>>(ei, ew, bcur, ebuf, E, NB);
    bucket_csr<<<NB, TB, 0, stream>>>(ebuf, boff, bcnt, csr, rowp, cnt, dis, N);
    fold_dis<<<(E + TB - 1) / TB, TB, 0, stream>>>(csr, dis, E);

    int gblk   = ((N + 15) / 16 + 3) / 4;    // one 16-row tile per wave
    int ablk64 = (N * 8 + TB - 1) / TB;      // 8 lanes/node
    int ablk16 = (N * 2 + TB - 1) / TB;      // 2 lanes/node

    float* logits = out + (size_t)N * 16;
    float* logits2 = out + (size_t)2 * N * 16;

    // layer 1
    gemm_mf<64, false><<<gblk, TB, 0, stream>>>(x, Wp1, hwB, N);
    aggregate<64, true, false><<<ablk64, TB, 0, stream>>>(hwB, rowp, cnt, csr, dis, b1, bufA16, nullptr, nullptr, N);
    // layer 2
    gemm_mf<64, true><<<gblk, TB, 0, stream>>>(bufA16, Wp2, hwB, N);
    aggregate<64, true, false><<<ablk64, TB, 0, stream>>>(hwB, rowp, cnt, csr, dis, b2, bufA16, nullptr, nullptr, N);
    // layer 3 + fused log-softmax
    gemm_mf<16, true><<<gblk, TB, 0, stream>>>(bufA16, Wp3, hw16, N);
    aggregate<16, false, true><<<ablk16, TB, 0, stream>>>(hw16, rowp, cnt, csr, dis, b3, out, logits, logits2, N);
}

// Round 15
// 193.163 us; speedup vs baseline: 2.2750x; 1.0622x over previous
//
#include <hip/hip_runtime.h>
#include <hip/hip_bf16.h>

#define N_FEAT 64
#define NBW 9                      // log2(nodes per bucket) = 512
#define SRC_BITS 23                // key = (dstLocal << 23) | src ; src < 2^23

typedef unsigned short u16;
typedef __attribute__((ext_vector_type(8))) short short8;   // 8 bf16 (4 VGPRs)
typedef __attribute__((ext_vector_type(4))) float f32x4;    // MFMA C/D

__device__ inline u16 f2bf(float f) {           // RNE f32 -> bf16
    unsigned u = __float_as_uint(f);
    u += 0x7fffu + ((u >> 16) & 1u);
    return (u16)(u >> 16);
}

// ---------------- CSR build: two-level bucket partition ----------------

__global__ __launch_bounds__(256) void coarse_hist(const int* __restrict__ ei, int* bcnt, int E, int NB) {
    __shared__ int h[256];
    int tid = threadIdx.x;
    h[tid] = 0;
    __syncthreads();
    for (int e = blockIdx.x * blockDim.x + tid; e < E; e += gridDim.x * blockDim.x)
        atomicAdd(&h[ei[E + e] >> NBW], 1);
    __syncthreads();
    if (tid < NB && h[tid]) atomicAdd(&bcnt[tid], h[tid]);
}

// pack W[64 x wcols] into MFMA B-fragment order:
// frag f = (cb*2+s)*64+lane ; elem i -> W[(s*32+(lane>>4)*8+i)*wcols + cb*16+(lane&15)]
__device__ inline void packW(const float* __restrict__ W, uint4* __restrict__ Wpk,
                             int ncb, int wcols, int tid) {
    int nf = ncb * 2 * 64;
    for (int f = tid; f < nf; f += 256) {
        int cb = f >> 7;
        int s  = (f >> 6) & 1;
        int lane = f & 63;
        int kb = lane >> 4, c16 = lane & 15;
        union { uint4 q; u16 u[8]; } pk;
        #pragma unroll
        for (int i = 0; i < 8; ++i) {
            int k = s * 32 + kb * 8 + i;
            pk.u[i] = f2bf(W[k * wcols + cb * 16 + c16]);
        }
        Wpk[f] = pk.q;
    }
}

// block 0: exclusive scan of bucket counts; blocks 1-3: pack W1/W2/W3
__global__ __launch_bounds__(256) void scan_pad(const int* __restrict__ bcnt, int* boff, int* bcur, int NB,
                                                const float* __restrict__ W1, const float* __restrict__ W2,
                                                const float* __restrict__ W3,
                                                uint4* Wp1, uint4* Wp2, uint4* Wp3) {
    if (blockIdx.x == 0) {
        __shared__ int wsum[4];
        int tid = threadIdx.x, lane = tid & 63, w = tid >> 6;
        int v = (tid < NB) ? bcnt[tid] : 0;
        int incl = v;
        #pragma unroll
        for (int o = 1; o < 64; o <<= 1) { int t = __shfl_up(incl, o); if (lane >= o) incl += t; }
        if (lane == 63) wsum[w] = incl;
        __syncthreads();
        int add = 0;
        #pragma unroll
        for (int i = 0; i < 4; ++i) if (i < w) add += wsum[i];
        int excl = add + incl - v;
        if (tid < NB) { boff[tid] = excl; bcur[tid] = excl; }
    } else if (blockIdx.x == 1) {
        packW(W1, Wp1, 4, 64, threadIdx.x);
    } else if (blockIdx.x == 2) {
        packW(W2, Wp2, 4, 64, threadIdx.x);
    } else {
        packW(W3, Wp3, 1, 16, threadIdx.x);
    }
}

__global__ __launch_bounds__(256) void partition(const int* __restrict__ ei, const float* __restrict__ ew,
                                                 int* bcur, int2* __restrict__ ebuf, int E, int NB) {
    constexpr int EPT = 8;
    __shared__ int cnt[256];
    __shared__ int base[256];
    int tid = threadIdx.x;
    cnt[tid] = 0;
    __syncthreads();
    int start = blockIdx.x * (256 * EPT);

    int d[EPT], r[EPT], s[EPT]; float w[EPT];
    #pragma unroll
    for (int i = 0; i < EPT; ++i) {
        int e = start + i * 256 + tid;
        if (e < E) {
            d[i] = ei[E + e];
            s[i] = ei[e];
            w[i] = ew[e];
            r[i] = atomicAdd(&cnt[d[i] >> NBW], 1);
        } else d[i] = -1;
    }
    __syncthreads();
    if (tid < NB && cnt[tid]) base[tid] = atomicAdd(&bcur[tid], cnt[tid]);
    __syncthreads();
    #pragma unroll
    for (int i = 0; i < EPT; ++i) {
        if (d[i] >= 0) {
            int b = d[i] >> NBW;
            int dl = d[i] & ((1 << NBW) - 1);
            int key = (dl << SRC_BITS) | s[i];
            ebuf[base[b] + r[i]] = make_int2(key, __float_as_int(w[i]));
        }
    }
}

__global__ __launch_bounds__(256) void bucket_csr(const int2* __restrict__ ebuf, const int* __restrict__ boff,
                                                  const int* __restrict__ bcnt,
                                                  int2* __restrict__ csr, int* __restrict__ rowp,
                                                  int* __restrict__ cnt, float* __restrict__ dis, int N) {
    __shared__ int   h[512];
    __shared__ float ws[512];
    __shared__ int   off[512];
    __shared__ int   wsum[4];
    int b = blockIdx.x, tid = threadIdx.x;
    int nbase = b << NBW;
    int nn = min(512, N - nbase);
    int beg = boff[b], m = bcnt[b];

    h[tid] = 0; h[tid + 256] = 0;
    ws[tid] = 0.f; ws[tid + 256] = 0.f;
    __syncthreads();

    for (int i = tid; i < m; i += 256) {
        int2 en = ebuf[beg + i];
        int dl = ((unsigned)en.x) >> SRC_BITS;
        atomicAdd(&h[dl], 1);
        atomicAdd(&ws[dl], __int_as_float(en.y));
    }
    __syncthreads();

    int v0 = h[2 * tid], v1 = h[2 * tid + 1];
    int v = v0 + v1;
    int lane = tid & 63, wv = tid >> 6;
    int incl = v;
    #pragma unroll
    for (int o = 1; o < 64; o <<= 1) { int t = __shfl_up(incl, o); if (lane >= o) incl += t; }
    if (lane == 63) wsum[wv] = incl;
    __syncthreads();
    int add = 0;
    #pragma unroll
    for (int i = 0; i < 4; ++i) if (i < wv) add += wsum[i];
    int excl = add + incl - v;
    off[2 * tid] = excl;
    off[2 * tid + 1] = excl + v0;
    __syncthreads();

    for (int l = tid; l < nn; l += 256) {
        rowp[nbase + l] = beg + off[l];
        cnt[nbase + l]  = h[l];
        dis[nbase + l]  = rsqrtf(1.0f + ws[l]);
    }
    __syncthreads();
    h[tid] = 0; h[tid + 256] = 0;
    __syncthreads();

    for (int i = tid; i < m; i += 256) {
        int2 en = ebuf[beg + i];
        unsigned k = (unsigned)en.x;
        int dl  = k >> SRC_BITS;
        int src = k & ((1 << SRC_BITS) - 1);
        int pos = atomicAdd(&h[dl], 1);
        csr[beg + off[dl] + pos] = make_int2(src, en.y);   // raw ew (dis folded in GEMM epilogue)
    }
}

// ---------------- GEMM via MFMA 16x16x32 bf16, epilogue row-scale by dis -----
// C_bf16[r] = dis[r] * (A[r] @ W)  ("hw-prime" rows; aggregation then uses raw
// edge weights and factors dis[dst] out to one final fma).

template<int OUTW, bool INBF>
__global__ __launch_bounds__(256) void gemm_mf(const void* __restrict__ Av, const uint4* __restrict__ Wpk,
                                               const float* __restrict__ dis,
                                               u16* __restrict__ C, int N) {
    constexpr int NCB = OUTW / 16;
    int lane = threadIdx.x & 63;
    int wid  = (int)((blockIdx.x * blockDim.x + threadIdx.x) >> 6);
    int r0 = wid * 16;
    if (r0 >= N) return;
    int row16 = lane & 15, kb = lane >> 4;
    int r = min(r0 + row16, N - 1);

    short8 a0, a1;
    if (INBF) {
        const u16* arow = (const u16*)Av + (size_t)r * 64 + kb * 8;
        a0 = __builtin_bit_cast(short8, *(const uint4*)arow);
        a1 = __builtin_bit_cast(short8, *(const uint4*)(arow + 32));
    } else {
        const float* arow = (const float*)Av + (size_t)r * 64 + kb * 8;
        float4 f0 = *(const float4*)arow;
        float4 f1 = *(const float4*)(arow + 4);
        float4 f2 = *(const float4*)(arow + 32);
        float4 f3 = *(const float4*)(arow + 36);
        union { short8 v; u16 u[8]; } pa, pb;
        pa.u[0] = f2bf(f0.x); pa.u[1] = f2bf(f0.y); pa.u[2] = f2bf(f0.z); pa.u[3] = f2bf(f0.w);
        pa.u[4] = f2bf(f1.x); pa.u[5] = f2bf(f1.y); pa.u[6] = f2bf(f1.z); pa.u[7] = f2bf(f1.w);
        pb.u[0] = f2bf(f2.x); pb.u[1] = f2bf(f2.y); pb.u[2] = f2bf(f2.z); pb.u[3] = f2bf(f2.w);
        pb.u[4] = f2bf(f3.x); pb.u[5] = f2bf(f3.y); pb.u[6] = f2bf(f3.z); pb.u[7] = f2bf(f3.w);
        a0 = pa.v; a1 = pb.v;
    }

    f32x4 acc[NCB];
    #pragma unroll
    for (int cb = 0; cb < NCB; ++cb) {
        short8 b0 = __builtin_bit_cast(short8, Wpk[(cb * 2 + 0) * 64 + lane]);
        short8 b1 = __builtin_bit_cast(short8, Wpk[(cb * 2 + 1) * 64 + lane]);
        f32x4 z = {0.f, 0.f, 0.f, 0.f};
        z = __builtin_amdgcn_mfma_f32_16x16x32_bf16(a0, b0, z, 0, 0, 0);
        z = __builtin_amdgcn_mfma_f32_16x16x32_bf16(a1, b1, z, 0, 0, 0);
        acc[cb] = z;
    }

    int rbase = r0 + kb * 4;
    float dsc[4];
    #pragma unroll
    for (int j = 0; j < 4; ++j) dsc[j] = dis[min(rbase + j, N - 1)];

    #pragma unroll
    for (int cb = 0; cb < NCB; ++cb) {
        int col = cb * 16 + row16;
        #pragma unroll
        for (int j = 0; j < 4; ++j) {
            int rr = rbase + j;
            if (rr < N) C[(size_t)rr * OUTW + col] = f2bf(acc[cb][j] * dsc[j]);
        }
    }
}

// ---------------- Aggregation: one node per GROUP, masked 8-deep pipeline ----
// hw' rows are pre-scaled by dis[src]; out = dd*(sum ew*hw'_s + hw'_n) + b.

template<int F, bool RELU, bool FINAL>
__global__ __launch_bounds__(256) void aggregate(const u16* __restrict__ hw, const int* __restrict__ rowp,
                                                 const int* __restrict__ cnt, const int2* __restrict__ csr,
                                                 const float* __restrict__ dis,
                                                 const float* __restrict__ bias, void* __restrict__ outv,
                                                 float* __restrict__ out2, float* __restrict__ out3, int N) {
    constexpr int GL   = F / 8;          // lanes per group/node (8 for F=64, 2 for F=16)
    constexpr int NPW  = 64 / GL;        // nodes per wave (8 or 32)
    constexpr unsigned ROWB = F * 2;     // row bytes (128 or 32)
    constexpr int UN   = 8;              // gathers in flight

    int wv   = (int)((blockIdx.x * blockDim.x + threadIdx.x) >> 6);
    int lane = threadIdx.x & 63;
    int g = lane / GL;
    int t = lane % GL;
    int n = wv * NPW + g;
    bool alive = (n < N);
    n = min(n, N - 1);

    float dd = dis[n];
    int beg = rowp[n];
    int c   = cnt[n];
    const char* hwb = (const char*)hw;
    unsigned toff = (unsigned)t * 16u;

    float acc[8];
    {   // self term: hw'_n with weight 1
        uint4 raw = *(const uint4*)(hwb + (unsigned)n * ROWB + toff);
        unsigned uw[4] = {raw.x, raw.y, raw.z, raw.w};
        #pragma unroll
        for (int k = 0; k < 4; ++k) {
            acc[2 * k]     = __uint_as_float(uw[k] << 16);
            acc[2 * k + 1] = __uint_as_float(uw[k] & 0xffff0000u);
        }
    }

    // masked 8-deep pipeline: all loads unconditional (clamped), weights masked
    for (int j0 = 0; j0 < c; j0 += UN) {
        int2 e[UN];
        #pragma unroll
        for (int i = 0; i < UN; ++i) e[i] = csr[beg + min(j0 + i, c - 1)];
        uint4 r[UN]; float w[UN];
        #pragma unroll
        for (int i = 0; i < UN; ++i) {
            r[i] = *(const uint4*)(hwb + (unsigned)e[i].x * ROWB + toff);
            w[i] = (j0 + i < c) ? __int_as_float(e[i].y) : 0.0f;
        }
        #pragma unroll
        for (int i = 0; i < UN; ++i) {
            unsigned u[4] = {r[i].x, r[i].y, r[i].z, r[i].w};
            #pragma unroll
            for (int k = 0; k < 4; ++k) {
                acc[2 * k]     = fmaf(w[i], __uint_as_float(u[k] << 16), acc[2 * k]);
                acc[2 * k + 1] = fmaf(w[i], __uint_as_float(u[k] & 0xffff0000u), acc[2 * k + 1]);
            }
        }
    }

    if (alive) {
        float4 b0 = *(const float4*)&bias[t * 8];
        float4 b1 = *(const float4*)&bias[t * 8 + 4];
        float bb[8] = {b0.x, b0.y, b0.z, b0.w, b1.x, b1.y, b1.z, b1.w};
        #pragma unroll
        for (int k = 0; k < 8; ++k) acc[k] = fmaf(dd, acc[k], bb[k]);   // dd factored out
        if (RELU) {
            #pragma unroll
            for (int k = 0; k < 8; ++k) acc[k] = fmaxf(acc[k], 0.0f);
        }
        if (!FINAL) {
            u16* o16 = (u16*)outv;
            uint4 pk;
            pk.x = (unsigned)f2bf(acc[0]) | ((unsigned)f2bf(acc[1]) << 16);
            pk.y = (unsigned)f2bf(acc[2]) | ((unsigned)f2bf(acc[3]) << 16);
            pk.z = (unsigned)f2bf(acc[4]) | ((unsigned)f2bf(acc[5]) << 16);
            pk.w = (unsigned)f2bf(acc[6]) | ((unsigned)f2bf(acc[7]) << 16);
            *(uint4*)&o16[(size_t)n * F + t * 8] = pk;
        } else {
            float4 r0 = make_float4(acc[0], acc[1], acc[2], acc[3]);
            float4 r1 = make_float4(acc[4], acc[5], acc[6], acc[7]);
            *(float4*)&out2[(size_t)n * F + t * 8] = r0;
            *(float4*)&out2[(size_t)n * F + t * 8 + 4] = r1;
            *(float4*)&out3[(size_t)n * F + t * 8] = r0;
            *(float4*)&out3[(size_t)n * F + t * 8 + 4] = r1;
            float mloc = acc[0];
            #pragma unroll
            for (int k = 1; k < 8; ++k) mloc = fmaxf(mloc, acc[k]);
            float m = fmaxf(mloc, __shfl_xor(mloc, 1));   // partner lane same group, same alive
            float sloc = 0.f;
            #pragma unroll
            for (int k = 0; k < 8; ++k) sloc += __expf(acc[k] - m);
            float ssum = sloc + __shfl_xor(sloc, 1);
            float ls = m + __logf(ssum);
            float* o = (float*)outv;
            float4 w0 = make_float4(acc[0] - ls, acc[1] - ls, acc[2] - ls, acc[3] - ls);
            float4 w1 = make_float4(acc[4] - ls, acc[5] - ls, acc[6] - ls, acc[7] - ls);
            *(float4*)&o[(size_t)n * F + t * 8] = w0;
            *(float4*)&o[(size_t)n * F + t * 8 + 4] = w1;
        }
    }
}

// ---------------- launch ----------------

extern "C" void kernel_launch(void* const* d_in, const int* in_sizes, int n_in,
                              void* d_out, int out_size, void* d_ws, size_t ws_size,
                              hipStream_t stream) {
    const float* x   = (const float*)d_in[0];
    const int*   ei  = (const int*)d_in[1];
    const float* ew  = (const float*)d_in[2];
    const float* W1  = (const float*)d_in[3];
    const float* b1  = (const float*)d_in[4];
    const float* W2  = (const float*)d_in[5];
    const float* b2  = (const float*)d_in[6];
    const float* W3  = (const float*)d_in[7];
    const float* b3  = (const float*)d_in[8];
    float* out = (float*)d_out;

    const int N = in_sizes[0] / N_FEAT;      // 100000
    const int E = in_sizes[2];               // 1600000
    const int NB = (N + (1 << NBW) - 1) >> NBW;

    size_t off = 0;
    auto alloc = [&](size_t bytes) {
        void* p = (char*)d_ws + off;
        off += (bytes + 255) & ~(size_t)255;
        return p;
    };
    float* dis     = (float*)alloc((size_t)N * 4);
    int*   cnt     = (int*)alloc((size_t)N * 4);
    int*   rowp    = (int*)alloc((size_t)N * 4);
    int*   bcnt    = (int*)alloc(256 * 4);
    int*   boff    = (int*)alloc(256 * 4);
    int*   bcur    = (int*)alloc(256 * 4);
    int2*  csr     = (int2*)alloc((size_t)E * 8);
    int2*  ebuf    = (int2*)alloc((size_t)E * 8);
    u16*   bufA16  = (u16*)alloc((size_t)N * 64 * 2);    // bf16 agg output (gemm input)
    u16*   hwB     = (u16*)alloc((size_t)N * 64 * 2);    // bf16 gemm output (gather side)
    u16*   hw16    = (u16*)alloc((size_t)N * 16 * 2);    // bf16 layer-3 gemm output
    uint4* Wp1     = (uint4*)alloc(512 * 16);            // B-fragment-packed weights
    uint4* Wp2     = (uint4*)alloc(512 * 16);
    uint4* Wp3     = (uint4*)alloc(128 * 16);

    const int TB = 256;

    // CSR build + weight packing
    hipMemsetAsync(bcnt, 0, 256 * 4, stream);
    coarse_hist<<<512, TB, 0, stream>>>(ei, bcnt, E, NB);
    scan_pad<<<4, TB, 0, stream>>>(bcnt, boff, bcur, NB, W1, W2, W3, Wp1, Wp2, Wp3);
    partition<<<(E + 2047) / 2048, TB, 0, stream>>>(ei, ew, bcur, ebuf, E, NB);
    bucket_csr<<<NB, TB, 0, stream>>>(ebuf, boff, bcnt, csr, rowp, cnt, dis, N);

    int gblk   = ((N + 15) / 16 + 3) / 4;    // one 16-row tile per wave
    int ablk64 = (N * 8 + TB - 1) / TB;      // 8 lanes/node
    int ablk16 = (N * 2 + TB - 1) / TB;      // 2 lanes/node

    float* logits = out + (size_t)N * 16;
    float* logits2 = out + (size_t)2 * N * 16;

    // layer 1
    gemm_mf<64, false><<<gblk, TB, 0, stream>>>(x, Wp1, dis, hwB, N);
    aggregate<64, true, false><<<ablk64, TB, 0, stream>>>(hwB, rowp, cnt, csr, dis, b1, bufA16, nullptr, nullptr, N);
    // layer 2
    gemm_mf<64, true><<<gblk, TB, 0, stream>>>(bufA16, Wp2, dis, hwB, N);
    aggregate<64, true, false><<<ablk64, TB, 0, stream>>>(hwB, rowp, cnt, csr, dis, b2, bufA16, nullptr, nullptr, N);
    // layer 3 + fused log-softmax
    gemm_mf<16, true><<<gblk, TB, 0, stream>>>(bufA16, Wp3, dis, hw16, N);
    aggregate<16, false, true><<<ablk16, TB, 0, stream>>>(hw16, rowp, cnt, csr, dis, b3, out, logits, logits2, N);
}

// Round 16
// 192.140 us; speedup vs baseline: 2.2871x; 1.0053x over previous
//
#include <hip/hip_runtime.h>
#include <hip/hip_bf16.h>

#define N_FEAT 64
#define NBW 9                      // log2(nodes per bucket) = 512
#define SRC_BITS 23                // key = (dstLocal << 23) | src ; src < 2^23

typedef unsigned short u16;
typedef __attribute__((ext_vector_type(8))) short short8;   // 8 bf16 (4 VGPRs)
typedef __attribute__((ext_vector_type(4))) float f32x4;    // MFMA C/D

__device__ inline u16 f2bf(float f) {           // RNE f32 -> bf16
    unsigned u = __float_as_uint(f);
    u += 0x7fffu + ((u >> 16) & 1u);
    return (u16)(u >> 16);
}

// ---------------- CSR build: two-level bucket partition ----------------

__global__ __launch_bounds__(256) void coarse_hist(const int* __restrict__ ei, int* bcnt, int E, int NB) {
    __shared__ int h[256];
    int tid = threadIdx.x;
    h[tid] = 0;
    __syncthreads();
    for (int e = blockIdx.x * blockDim.x + tid; e < E; e += gridDim.x * blockDim.x)
        atomicAdd(&h[ei[E + e] >> NBW], 1);
    __syncthreads();
    if (tid < NB && h[tid]) atomicAdd(&bcnt[tid], h[tid]);
}

// pack W[64 x wcols] into MFMA B-fragment order
__device__ inline void packW(const float* __restrict__ W, uint4* __restrict__ Wpk,
                             int ncb, int wcols, int tid) {
    int nf = ncb * 2 * 64;
    for (int f = tid; f < nf; f += 256) {
        int cb = f >> 7;
        int s  = (f >> 6) & 1;
        int lane = f & 63;
        int kb = lane >> 4, c16 = lane & 15;
        union { uint4 q; u16 u[8]; } pk;
        #pragma unroll
        for (int i = 0; i < 8; ++i) {
            int k = s * 32 + kb * 8 + i;
            pk.u[i] = f2bf(W[k * wcols + cb * 16 + c16]);
        }
        Wpk[f] = pk.q;
    }
}

__global__ __launch_bounds__(256) void scan_pad(const int* __restrict__ bcnt, int* boff, int* bcur, int NB,
                                                const float* __restrict__ W1, const float* __restrict__ W2,
                                                const float* __restrict__ W3,
                                                uint4* Wp1, uint4* Wp2, uint4* Wp3) {
    if (blockIdx.x == 0) {
        __shared__ int wsum[4];
        int tid = threadIdx.x, lane = tid & 63, w = tid >> 6;
        int v = (tid < NB) ? bcnt[tid] : 0;
        int incl = v;
        #pragma unroll
        for (int o = 1; o < 64; o <<= 1) { int t = __shfl_up(incl, o); if (lane >= o) incl += t; }
        if (lane == 63) wsum[w] = incl;
        __syncthreads();
        int add = 0;
        #pragma unroll
        for (int i = 0; i < 4; ++i) if (i < w) add += wsum[i];
        int excl = add + incl - v;
        if (tid < NB) { boff[tid] = excl; bcur[tid] = excl; }
    } else if (blockIdx.x == 1) {
        packW(W1, Wp1, 4, 64, threadIdx.x);
    } else if (blockIdx.x == 2) {
        packW(W2, Wp2, 4, 64, threadIdx.x);
    } else {
        packW(W3, Wp3, 1, 16, threadIdx.x);
    }
}

// ---------------- GEMM body via MFMA 16x16x32 bf16 ----------------
// C_bf16[r] = (SCALE ? dis[r] : 1) * (A[r] @ W). One 16-row tile per wave.

template<int OUTW, bool INBF, bool SCALE>
__device__ inline void gemm_body(const void* __restrict__ Av, const uint4* __restrict__ Wpk,
                                 const float* __restrict__ dis, u16* __restrict__ C, int N,
                                 int wid, int lane) {
    constexpr int NCB = OUTW / 16;
    int r0 = wid * 16;
    if (r0 >= N) return;
    int row16 = lane & 15, kb = lane >> 4;
    int r = min(r0 + row16, N - 1);

    short8 a0, a1;
    if (INBF) {
        const u16* arow = (const u16*)Av + (size_t)r * 64 + kb * 8;
        a0 = __builtin_bit_cast(short8, *(const uint4*)arow);
        a1 = __builtin_bit_cast(short8, *(const uint4*)(arow + 32));
    } else {
        const float* arow = (const float*)Av + (size_t)r * 64 + kb * 8;
        float4 f0 = *(const float4*)arow;
        float4 f1 = *(const float4*)(arow + 4);
        float4 f2 = *(const float4*)(arow + 32);
        float4 f3 = *(const float4*)(arow + 36);
        union { short8 v; u16 u[8]; } pa, pb;
        pa.u[0] = f2bf(f0.x); pa.u[1] = f2bf(f0.y); pa.u[2] = f2bf(f0.z); pa.u[3] = f2bf(f0.w);
        pa.u[4] = f2bf(f1.x); pa.u[5] = f2bf(f1.y); pa.u[6] = f2bf(f1.z); pa.u[7] = f2bf(f1.w);
        pb.u[0] = f2bf(f2.x); pb.u[1] = f2bf(f2.y); pb.u[2] = f2bf(f2.z); pb.u[3] = f2bf(f2.w);
        pb.u[4] = f2bf(f3.x); pb.u[5] = f2bf(f3.y); pb.u[6] = f2bf(f3.z); pb.u[7] = f2bf(f3.w);
        a0 = pa.v; a1 = pb.v;
    }

    f32x4 acc[NCB];
    #pragma unroll
    for (int cb = 0; cb < NCB; ++cb) {
        short8 b0 = __builtin_bit_cast(short8, Wpk[(cb * 2 + 0) * 64 + lane]);
        short8 b1 = __builtin_bit_cast(short8, Wpk[(cb * 2 + 1) * 64 + lane]);
        f32x4 z = {0.f, 0.f, 0.f, 0.f};
        z = __builtin_amdgcn_mfma_f32_16x16x32_bf16(a0, b0, z, 0, 0, 0);
        z = __builtin_amdgcn_mfma_f32_16x16x32_bf16(a1, b1, z, 0, 0, 0);
        acc[cb] = z;
    }

    int rbase = r0 + kb * 4;
    float dsc[4];
    #pragma unroll
    for (int j = 0; j < 4; ++j) dsc[j] = SCALE ? dis[min(rbase + j, N - 1)] : 1.0f;

    #pragma unroll
    for (int cb = 0; cb < NCB; ++cb) {
        int col = cb * 16 + row16;
        #pragma unroll
        for (int j = 0; j < 4; ++j) {
            int rr = rbase + j;
            if (rr < N) C[(size_t)rr * OUTW + col] = f2bf(SCALE ? acc[cb][j] * dsc[j] : acc[cb][j]);
        }
    }
}

template<int OUTW, bool INBF, bool SCALE>
__global__ __launch_bounds__(256) void gemm_mf(const void* __restrict__ Av, const uint4* __restrict__ Wpk,
                                               const float* __restrict__ dis,
                                               u16* __restrict__ C, int N) {
    int lane = threadIdx.x & 63;
    int wid  = (int)((blockIdx.x * blockDim.x + threadIdx.x) >> 6);
    gemm_body<OUTW, INBF, SCALE>(Av, Wpk, dis, C, N, wid, lane);
}

// ---------------- partition + fused layer-1 GEMM (independent work overlap) --
// blocks [0,PB): scatter edges into bucket-contiguous ebuf
// blocks [PB,..): gemm1 = bf16(x @ W1), unscaled (dis not yet available)

__global__ __launch_bounds__(256) void part_gemm(const int* __restrict__ ei, const float* __restrict__ ew,
                                                 int* bcur, int2* __restrict__ ebuf, int E, int NB, int PB,
                                                 const float* __restrict__ x, const uint4* __restrict__ Wp1,
                                                 u16* __restrict__ hwB, int N) {
    constexpr int EPT = 8;
    __shared__ int cnt[256];
    __shared__ int base[256];
    int tid = threadIdx.x;

    if ((int)blockIdx.x >= PB) {                 // ---- gemm1 path ----
        int wid = (int)(((blockIdx.x - PB) * blockDim.x + tid) >> 6);
        gemm_body<64, false, false>(x, Wp1, nullptr, hwB, N, wid, tid & 63);
        return;
    }

    cnt[tid] = 0;
    __syncthreads();
    int start = blockIdx.x * (256 * EPT);

    int d[EPT], r[EPT], s[EPT]; float w[EPT];
    #pragma unroll
    for (int i = 0; i < EPT; ++i) {
        int e = start + i * 256 + tid;
        if (e < E) {
            d[i] = ei[E + e];
            s[i] = ei[e];
            w[i] = ew[e];
            r[i] = atomicAdd(&cnt[d[i] >> NBW], 1);
        } else d[i] = -1;
    }
    __syncthreads();
    if (tid < NB && cnt[tid]) base[tid] = atomicAdd(&bcur[tid], cnt[tid]);
    __syncthreads();
    #pragma unroll
    for (int i = 0; i < EPT; ++i) {
        if (d[i] >= 0) {
            int b = d[i] >> NBW;
            int dl = d[i] & ((1 << NBW) - 1);
            int key = (dl << SRC_BITS) | s[i];
            ebuf[base[b] + r[i]] = make_int2(key, __float_as_int(w[i]));
        }
    }
}

__global__ __launch_bounds__(256) void bucket_csr(const int2* __restrict__ ebuf, const int* __restrict__ boff,
                                                  const int* __restrict__ bcnt,
                                                  int2* __restrict__ csr, int* __restrict__ rowp,
                                                  int* __restrict__ cnt, float* __restrict__ dis, int N) {
    __shared__ int   h[512];
    __shared__ float ws[512];
    __shared__ int   off[512];
    __shared__ int   wsum[4];
    int b = blockIdx.x, tid = threadIdx.x;
    int nbase = b << NBW;
    int nn = min(512, N - nbase);
    int beg = boff[b], m = bcnt[b];

    h[tid] = 0; h[tid + 256] = 0;
    ws[tid] = 0.f; ws[tid + 256] = 0.f;
    __syncthreads();

    for (int i = tid; i < m; i += 256) {
        int2 en = ebuf[beg + i];
        int dl = ((unsigned)en.x) >> SRC_BITS;
        atomicAdd(&h[dl], 1);
        atomicAdd(&ws[dl], __int_as_float(en.y));
    }
    __syncthreads();

    int v0 = h[2 * tid], v1 = h[2 * tid + 1];
    int v = v0 + v1;
    int lane = tid & 63, wv = tid >> 6;
    int incl = v;
    #pragma unroll
    for (int o = 1; o < 64; o <<= 1) { int t = __shfl_up(incl, o); if (lane >= o) incl += t; }
    if (lane == 63) wsum[wv] = incl;
    __syncthreads();
    int add = 0;
    #pragma unroll
    for (int i = 0; i < 4; ++i) if (i < wv) add += wsum[i];
    int excl = add + incl - v;
    off[2 * tid] = excl;
    off[2 * tid + 1] = excl + v0;
    __syncthreads();

    for (int l = tid; l < nn; l += 256) {
        rowp[nbase + l] = beg + off[l];
        cnt[nbase + l]  = h[l];
        dis[nbase + l]  = rsqrtf(1.0f + ws[l]);
    }
    __syncthreads();
    h[tid] = 0; h[tid + 256] = 0;
    __syncthreads();

    for (int i = tid; i < m; i += 256) {
        int2 en = ebuf[beg + i];
        unsigned k = (unsigned)en.x;
        int dl  = k >> SRC_BITS;
        int src = k & ((1 << SRC_BITS) - 1);
        int pos = atomicAdd(&h[dl], 1);
        csr[beg + off[dl] + pos] = make_int2(src, en.y);   // raw ew
    }
}

// ---------------- Aggregation: split-half, one node per 2x(F/8)-lane set ----
// Half s in {0,1} handles edges [s*8 + 16k, s*8+8 + 16k); merge = shfl_xor 32.
// LOADDIS: hw table unscaled (layer 1) -> w_e = ew * dis[src], self term dd*hw_n.
// else: hw pre-scaled by dis[row] in gemm epilogue -> w_e = ew, self term hw'_n.
// out = dd * (gather_sum + self) + b.

template<int F, bool RELU, bool FINAL, bool LOADDIS>
__global__ __launch_bounds__(256) void aggregate(const u16* __restrict__ hw, const int* __restrict__ rowp,
                                                 const int* __restrict__ cnt, const int2* __restrict__ csr,
                                                 const float* __restrict__ dis,
                                                 const float* __restrict__ bias, void* __restrict__ outv,
                                                 float* __restrict__ out2, float* __restrict__ out3, int N) {
    constexpr int GL   = F / 8;          // lanes per half-slice (8 for F=64, 2 for F=16)
    constexpr int NPW  = 32 / GL;        // nodes per wave (4 or 16)
    constexpr unsigned ROWB = F * 2;     // row bytes (128 or 32)
    constexpr int UN   = 8;              // gathers in flight per half

    int wv   = (int)((blockIdx.x * blockDim.x + threadIdx.x) >> 6);
    int lane = threadIdx.x & 63;
    int s = lane >> 5;                   // half
    int wl = lane & 31;
    int q = wl / GL;                     // node slot in wave
    int t = wl % GL;                     // 16B chunk in row
    int n = wv * NPW + q;
    bool alive = (n < N);
    n = min(n, N - 1);

    float dd = dis[n];
    int beg = rowp[n];
    int c   = cnt[n];
    const char* hwb = (const char*)hw;
    unsigned toff = (unsigned)t * 16u;

    float acc[8];
    {   // self term only in half 0 (avoid double count after merge)
        uint4 raw = *(const uint4*)(hwb + (unsigned)n * ROWB + toff);
        float sw = (s == 0) ? (LOADDIS ? dd : 1.0f) : 0.0f;
        unsigned uw[4] = {raw.x, raw.y, raw.z, raw.w};
        #pragma unroll
        for (int k = 0; k < 4; ++k) {
            acc[2 * k]     = sw * __uint_as_float(uw[k] << 16);
            acc[2 * k + 1] = sw * __uint_as_float(uw[k] & 0xffff0000u);
        }
    }

    // masked 8-deep pipeline over this half's edge slices
    for (int j0 = s * UN; j0 < c; j0 += 2 * UN) {
        int2 e[UN];
        #pragma unroll
        for (int i = 0; i < UN; ++i) e[i] = csr[beg + min(j0 + i, c - 1)];
        uint4 r[UN]; float w[UN];
        #pragma unroll
        for (int i = 0; i < UN; ++i) {
            r[i] = *(const uint4*)(hwb + (unsigned)e[i].x * ROWB + toff);
            float wr = __int_as_float(e[i].y);
            if (LOADDIS) wr *= dis[e[i].x];
            w[i] = (j0 + i < c) ? wr : 0.0f;
        }
        #pragma unroll
        for (int i = 0; i < UN; ++i) {
            unsigned u[4] = {r[i].x, r[i].y, r[i].z, r[i].w};
            #pragma unroll
            for (int k = 0; k < 4; ++k) {
                acc[2 * k]     = fmaf(w[i], __uint_as_float(u[k] << 16), acc[2 * k]);
                acc[2 * k + 1] = fmaf(w[i], __uint_as_float(u[k] & 0xffff0000u), acc[2 * k + 1]);
            }
        }
    }

    // merge halves (partners are 32 lanes apart; both sides alive-identical)
    #pragma unroll
    for (int k = 0; k < 8; ++k) acc[k] += __shfl_xor(acc[k], 32);

    if (alive && s == 0) {
        float4 b0 = *(const float4*)&bias[t * 8];
        float4 b1 = *(const float4*)&bias[t * 8 + 4];
        float bb[8] = {b0.x, b0.y, b0.z, b0.w, b1.x, b1.y, b1.z, b1.w};
        #pragma unroll
        for (int k = 0; k < 8; ++k) acc[k] = fmaf(dd, acc[k], bb[k]);
        if (RELU) {
            #pragma unroll
            for (int k = 0; k < 8; ++k) acc[k] = fmaxf(acc[k], 0.0f);
        }
        if (!FINAL) {
            u16* o16 = (u16*)outv;
            uint4 pk;
            pk.x = (unsigned)f2bf(acc[0]) | ((unsigned)f2bf(acc[1]) << 16);
            pk.y = (unsigned)f2bf(acc[2]) | ((unsigned)f2bf(acc[3]) << 16);
            pk.z = (unsigned)f2bf(acc[4]) | ((unsigned)f2bf(acc[5]) << 16);
            pk.w = (unsigned)f2bf(acc[6]) | ((unsigned)f2bf(acc[7]) << 16);
            *(uint4*)&o16[(size_t)n * F + t * 8] = pk;
        } else {
            float4 r0 = make_float4(acc[0], acc[1], acc[2], acc[3]);
            float4 r1 = make_float4(acc[4], acc[5], acc[6], acc[7]);
            *(float4*)&out2[(size_t)n * F + t * 8] = r0;
            *(float4*)&out2[(size_t)n * F + t * 8 + 4] = r1;
            *(float4*)&out3[(size_t)n * F + t * 8] = r0;
            *(float4*)&out3[(size_t)n * F + t * 8 + 4] = r1;
            float mloc = acc[0];
            #pragma unroll
            for (int k = 1; k < 8; ++k) mloc = fmaxf(mloc, acc[k]);
            float m = fmaxf(mloc, __shfl_xor(mloc, 1));   // t0<->t1 same node, both alive
            float sloc = 0.f;
            #pragma unroll
            for (int k = 0; k < 8; ++k) sloc += __expf(acc[k] - m);
            float ssum = sloc + __shfl_xor(sloc, 1);
            float ls = m + __logf(ssum);
            float* o = (float*)outv;
            float4 w0 = make_float4(acc[0] - ls, acc[1] - ls, acc[2] - ls, acc[3] - ls);
            float4 w1 = make_float4(acc[4] - ls, acc[5] - ls, acc[6] - ls, acc[7] - ls);
            *(float4*)&o[(size_t)n * F + t * 8] = w0;
            *(float4*)&o[(size_t)n * F + t * 8 + 4] = w1;
        }
    }
}

// ---------------- launch ----------------

extern "C" void kernel_launch(void* const* d_in, const int* in_sizes, int n_in,
                              void* d_out, int out_size, void* d_ws, size_t ws_size,
                              hipStream_t stream) {
    const float* x   = (const float*)d_in[0];
    const int*   ei  = (const int*)d_in[1];
    const float* ew  = (const float*)d_in[2];
    const float* W1  = (const float*)d_in[3];
    const float* b1  = (const float*)d_in[4];
    const float* W2  = (const float*)d_in[5];
    const float* b2  = (const float*)d_in[6];
    const float* W3  = (const float*)d_in[7];
    const float* b3  = (const float*)d_in[8];
    float* out = (float*)d_out;

    const int N = in_sizes[0] / N_FEAT;      // 100000
    const int E = in_sizes[2];               // 1600000
    const int NB = (N + (1 << NBW) - 1) >> NBW;

    size_t off = 0;
    auto alloc = [&](size_t bytes) {
        void* p = (char*)d_ws + off;
        off += (bytes + 255) & ~(size_t)255;
        return p;
    };
    float* dis     = (float*)alloc((size_t)N * 4);
    int*   cnt     = (int*)alloc((size_t)N * 4);
    int*   rowp    = (int*)alloc((size_t)N * 4);
    int*   bcnt    = (int*)alloc(256 * 4);
    int*   boff    = (int*)alloc(256 * 4);
    int*   bcur    = (int*)alloc(256 * 4);
    int2*  csr     = (int2*)alloc((size_t)E * 8);
    int2*  ebuf    = (int2*)alloc((size_t)E * 8);
    u16*   bufA16  = (u16*)alloc((size_t)N * 64 * 2);    // bf16 agg output (gemm input)
    u16*   hwB     = (u16*)alloc((size_t)N * 64 * 2);    // bf16 gemm output (gather side)
    u16*   hw16    = (u16*)alloc((size_t)N * 16 * 2);    // bf16 layer-3 gemm output
    uint4* Wp1     = (uint4*)alloc(512 * 16);            // B-fragment-packed weights
    uint4* Wp2     = (uint4*)alloc(512 * 16);
    uint4* Wp3     = (uint4*)alloc(128 * 16);

    const int TB = 256;

    int gblk = ((N + 15) / 16 + 3) / 4;      // gemm: one 16-row tile per wave
    int PB   = (E + 2047) / 2048;            // partition blocks

    // CSR build + weight packing + fused gemm1
    hipMemsetAsync(bcnt, 0, 256 * 4, stream);
    coarse_hist<<<512, TB, 0, stream>>>(ei, bcnt, E, NB);
    scan_pad<<<4, TB, 0, stream>>>(bcnt, boff, bcur, NB, W1, W2, W3, Wp1, Wp2, Wp3);
    part_gemm<<<PB + gblk, TB, 0, stream>>>(ei, ew, bcur, ebuf, E, NB, PB, x, Wp1, hwB, N);
    bucket_csr<<<NB, TB, 0, stream>>>(ebuf, boff, bcnt, csr, rowp, cnt, dis, N);

    int ablk64 = (N * 16 + TB - 1) / TB;     // 16 lanes/node (2 halves x 8)
    int ablk16 = (N * 4 + TB - 1) / TB;      // 4 lanes/node (2 halves x 2)

    float* logits = out + (size_t)N * 16;
    float* logits2 = out + (size_t)2 * N * 16;

    // layer 1 (hw unscaled; aggregate loads dis[src] per edge)
    aggregate<64, true, false, true><<<ablk64, TB, 0, stream>>>(hwB, rowp, cnt, csr, dis, b1, bufA16, nullptr, nullptr, N);
    // layer 2
    gemm_mf<64, true, true><<<gblk, TB, 0, stream>>>(bufA16, Wp2, dis, hwB, N);
    aggregate<64, true, false, false><<<ablk64, TB, 0, stream>>>(hwB, rowp, cnt, csr, dis, b2, bufA16, nullptr, nullptr, N);
    // layer 3 + fused log-softmax
    gemm_mf<16, true, true><<<gblk, TB, 0, stream>>>(bufA16, Wp3, dis, hw16, N);
    aggregate<16, false, true, false><<<ablk16, TB, 0, stream>>>(hw16, rowp, cnt, csr, dis, b3, out, logits, logits2, N);
}

// Round 17
// 175.405 us; speedup vs baseline: 2.5053x; 1.0954x over previous
//
#include <hip/hip_runtime.h>
#include <hip/hip_bf16.h>

#define N_FEAT 64
#define NBW 9                      // log2(nodes per bucket) = 512
#define SRC_BITS 23                // key = (dstLocal << 23) | src ; src < 2^23
#define CAP 9216                   // static bucket capacity (mean 8192 + >10 sigma)

typedef unsigned short u16;
typedef __attribute__((ext_vector_type(8))) short short8;   // 8 bf16 (4 VGPRs)
typedef __attribute__((ext_vector_type(4))) float f32x4;    // MFMA C/D

__device__ inline u16 f2bf(float f) {           // RNE f32 -> bf16
    unsigned u = __float_as_uint(f);
    u += 0x7fffu + ((u >> 16) & 1u);
    return (u16)(u >> 16);
}

// ---------------- pack W into MFMA B-fragment order + init cursors ----------

__device__ inline void packW(const float* __restrict__ W, uint4* __restrict__ Wpk,
                             int ncb, int wcols, int tid) {
    int nf = ncb * 2 * 64;
    for (int f = tid; f < nf; f += 256) {
        int cb = f >> 7;
        int s  = (f >> 6) & 1;
        int lane = f & 63;
        int kb = lane >> 4, c16 = lane & 15;
        union { uint4 q; u16 u[8]; } pk;
        #pragma unroll
        for (int i = 0; i < 8; ++i) {
            int k = s * 32 + kb * 8 + i;
            pk.u[i] = f2bf(W[k * wcols + cb * 16 + c16]);
        }
        Wpk[f] = pk.q;
    }
}

__global__ __launch_bounds__(256) void pack_init(const float* __restrict__ W1, const float* __restrict__ W2,
                                                 const float* __restrict__ W3,
                                                 uint4* Wp1, uint4* Wp2, uint4* Wp3, int* bcur) {
    if (blockIdx.x == 0)      packW(W1, Wp1, 4, 64, threadIdx.x);
    else if (blockIdx.x == 1) packW(W2, Wp2, 4, 64, threadIdx.x);
    else if (blockIdx.x == 2) packW(W3, Wp3, 1, 16, threadIdx.x);
    else                      bcur[threadIdx.x] = 0;
}

// ---------------- GEMM body via MFMA 16x16x32 bf16 ----------------
// C_bf16[r] = (SCALE ? dis[r] : 1) * (A[r] @ W). One 16-row tile per wave.

template<int OUTW, bool INBF, bool SCALE>
__device__ inline void gemm_body(const void* __restrict__ Av, const uint4* __restrict__ Wpk,
                                 const float* __restrict__ dis, u16* __restrict__ C, int N,
                                 int wid, int lane) {
    constexpr int NCB = OUTW / 16;
    int r0 = wid * 16;
    if (r0 >= N) return;
    int row16 = lane & 15, kb = lane >> 4;
    int r = min(r0 + row16, N - 1);

    short8 a0, a1;
    if (INBF) {
        const u16* arow = (const u16*)Av + (size_t)r * 64 + kb * 8;
        a0 = __builtin_bit_cast(short8, *(const uint4*)arow);
        a1 = __builtin_bit_cast(short8, *(const uint4*)(arow + 32));
    } else {
        const float* arow = (const float*)Av + (size_t)r * 64 + kb * 8;
        float4 f0 = *(const float4*)arow;
        float4 f1 = *(const float4*)(arow + 4);
        float4 f2 = *(const float4*)(arow + 32);
        float4 f3 = *(const float4*)(arow + 36);
        union { short8 v; u16 u[8]; } pa, pb;
        pa.u[0] = f2bf(f0.x); pa.u[1] = f2bf(f0.y); pa.u[2] = f2bf(f0.z); pa.u[3] = f2bf(f0.w);
        pa.u[4] = f2bf(f1.x); pa.u[5] = f2bf(f1.y); pa.u[6] = f2bf(f1.z); pa.u[7] = f2bf(f1.w);
        pb.u[0] = f2bf(f2.x); pb.u[1] = f2bf(f2.y); pb.u[2] = f2bf(f2.z); pb.u[3] = f2bf(f2.w);
        pb.u[4] = f2bf(f3.x); pb.u[5] = f2bf(f3.y); pb.u[6] = f2bf(f3.z); pb.u[7] = f2bf(f3.w);
        a0 = pa.v; a1 = pb.v;
    }

    f32x4 acc[NCB];
    #pragma unroll
    for (int cb = 0; cb < NCB; ++cb) {
        short8 b0 = __builtin_bit_cast(short8, Wpk[(cb * 2 + 0) * 64 + lane]);
        short8 b1 = __builtin_bit_cast(short8, Wpk[(cb * 2 + 1) * 64 + lane]);
        f32x4 z = {0.f, 0.f, 0.f, 0.f};
        z = __builtin_amdgcn_mfma_f32_16x16x32_bf16(a0, b0, z, 0, 0, 0);
        z = __builtin_amdgcn_mfma_f32_16x16x32_bf16(a1, b1, z, 0, 0, 0);
        acc[cb] = z;
    }

    int rbase = r0 + kb * 4;
    float dsc[4];
    #pragma unroll
    for (int j = 0; j < 4; ++j) dsc[j] = SCALE ? dis[min(rbase + j, N - 1)] : 1.0f;

    #pragma unroll
    for (int cb = 0; cb < NCB; ++cb) {
        int col = cb * 16 + row16;
        #pragma unroll
        for (int j = 0; j < 4; ++j) {
            int rr = rbase + j;
            if (rr < N) C[(size_t)rr * OUTW + col] = f2bf(SCALE ? acc[cb][j] * dsc[j] : acc[cb][j]);
        }
    }
}

template<int OUTW, bool INBF, bool SCALE>
__global__ __launch_bounds__(256) void gemm_mf(const void* __restrict__ Av, const uint4* __restrict__ Wpk,
                                               const float* __restrict__ dis,
                                               u16* __restrict__ C, int N) {
    int lane = threadIdx.x & 63;
    int wid  = (int)((blockIdx.x * blockDim.x + threadIdx.x) >> 6);
    gemm_body<OUTW, INBF, SCALE>(Av, Wpk, dis, C, N, wid, lane);
}

// ---------------- partition (static buckets) + fused layer-1 GEMM ------------
// blocks [0,PB): scatter edges into ebuf[b*CAP + pos], pos via atomic bump
// blocks [PB,..): gemm1 = bf16(x @ W1), unscaled (dis not yet available)

__global__ __launch_bounds__(256) void part_gemm(const int* __restrict__ ei, const float* __restrict__ ew,
                                                 int* bcur, int2* __restrict__ ebuf, int E, int NB, int PB,
                                                 const float* __restrict__ x, const uint4* __restrict__ Wp1,
                                                 u16* __restrict__ hwB, int N) {
    constexpr int EPT = 8;
    __shared__ int cnt[256];
    __shared__ int base[256];
    int tid = threadIdx.x;

    if ((int)blockIdx.x >= PB) {                 // ---- gemm1 path ----
        int wid = (int)(((blockIdx.x - PB) * blockDim.x + tid) >> 6);
        gemm_body<64, false, false>(x, Wp1, nullptr, hwB, N, wid, tid & 63);
        return;
    }

    cnt[tid] = 0;
    __syncthreads();
    int start = blockIdx.x * (256 * EPT);

    int d[EPT], r[EPT], s[EPT]; float w[EPT];
    #pragma unroll
    for (int i = 0; i < EPT; ++i) {
        int e = start + i * 256 + tid;
        if (e < E) {
            d[i] = ei[E + e];
            s[i] = ei[e];
            w[i] = ew[e];
            r[i] = atomicAdd(&cnt[d[i] >> NBW], 1);
        } else d[i] = -1;
    }
    __syncthreads();
    if (tid < NB && cnt[tid]) base[tid] = atomicAdd(&bcur[tid], cnt[tid]);
    __syncthreads();
    #pragma unroll
    for (int i = 0; i < EPT; ++i) {
        if (d[i] >= 0) {
            int b = d[i] >> NBW;
            int dl = d[i] & ((1 << NBW) - 1);
            int gpos = base[b] + r[i];
            if (gpos < CAP) {                    // safety guard (never triggers: CAP >> max bucket)
                int key = (dl << SRC_BITS) | s[i];
                ebuf[(size_t)b * CAP + gpos] = make_int2(key, __float_as_int(w[i]));
            }
        }
    }
}

// one block per bucket: per-node hist + weight-sum, scan, emit rowp/cnt/dis,
// scatter bucket edges into its csr slice (bucketed layout, rowp absolute)

__global__ __launch_bounds__(256) void bucket_csr(const int2* __restrict__ ebuf, const int* __restrict__ bcur,
                                                  int2* __restrict__ csr, int* __restrict__ rowp,
                                                  int* __restrict__ cnt, float* __restrict__ dis, int N) {
    __shared__ int   h[512];
    __shared__ float ws[512];
    __shared__ int   off[512];
    __shared__ int   wsum[4];
    int b = blockIdx.x, tid = threadIdx.x;
    int nbase = b << NBW;
    int nn = min(512, N - nbase);
    int beg = b * CAP;
    int m = min(bcur[b], CAP);

    h[tid] = 0; h[tid + 256] = 0;
    ws[tid] = 0.f; ws[tid + 256] = 0.f;
    __syncthreads();

    for (int i = tid; i < m; i += 256) {
        int2 en = ebuf[beg + i];
        int dl = ((unsigned)en.x) >> SRC_BITS;
        atomicAdd(&h[dl], 1);
        atomicAdd(&ws[dl], __int_as_float(en.y));
    }
    __syncthreads();

    int v0 = h[2 * tid], v1 = h[2 * tid + 1];
    int v = v0 + v1;
    int lane = tid & 63, wv = tid >> 6;
    int incl = v;
    #pragma unroll
    for (int o = 1; o < 64; o <<= 1) { int t = __shfl_up(incl, o); if (lane >= o) incl += t; }
    if (lane == 63) wsum[wv] = incl;
    __syncthreads();
    int add = 0;
    #pragma unroll
    for (int i = 0; i < 4; ++i) if (i < wv) add += wsum[i];
    int excl = add + incl - v;
    off[2 * tid] = excl;
    off[2 * tid + 1] = excl + v0;
    __syncthreads();

    for (int l = tid; l < nn; l += 256) {
        rowp[nbase + l] = beg + off[l];
        cnt[nbase + l]  = h[l];
        dis[nbase + l]  = rsqrtf(1.0f + ws[l]);
    }
    __syncthreads();
    h[tid] = 0; h[tid + 256] = 0;
    __syncthreads();

    for (int i = tid; i < m; i += 256) {
        int2 en = ebuf[beg + i];
        unsigned k = (unsigned)en.x;
        int dl  = k >> SRC_BITS;
        int src = k & ((1 << SRC_BITS) - 1);
        int pos = atomicAdd(&h[dl], 1);
        csr[beg + off[dl] + pos] = make_int2(src, en.y);   // raw ew
    }
}

// ---------------- Aggregation: one node per GROUP, masked 8-deep pipeline ----
// LOADDIS: hw unscaled (layer 1) -> w_e = ew*dis[src], self = dd*hw_n.
// else: hw pre-scaled by dis[row] -> w_e = ew, self = hw'_n.
// out = dd * (gather_sum + self) + b.

template<int F, bool RELU, bool FINAL, bool LOADDIS>
__global__ __launch_bounds__(256) void aggregate(const u16* __restrict__ hw, const int* __restrict__ rowp,
                                                 const int* __restrict__ cnt, const int2* __restrict__ csr,
                                                 const float* __restrict__ dis,
                                                 const float* __restrict__ bias, void* __restrict__ outv,
                                                 float* __restrict__ out2, float* __restrict__ out3, int N) {
    constexpr int GL   = F / 8;          // lanes per group/node (8 for F=64, 2 for F=16)
    constexpr int NPW  = 64 / GL;        // nodes per wave (8 or 32)
    constexpr unsigned ROWB = F * 2;     // row bytes (128 or 32)
    constexpr int UN   = 8;              // gathers in flight

    int wv   = (int)((blockIdx.x * blockDim.x + threadIdx.x) >> 6);
    int lane = threadIdx.x & 63;
    int g = lane / GL;
    int t = lane % GL;
    int n = wv * NPW + g;
    bool alive = (n < N);
    n = min(n, N - 1);

    float dd = dis[n];
    int beg = rowp[n];
    int c   = cnt[n];
    const char* hwb = (const char*)hw;
    unsigned toff = (unsigned)t * 16u;

    float acc[8];
    {   // self term
        uint4 raw = *(const uint4*)(hwb + (unsigned)n * ROWB + toff);
        float sw = LOADDIS ? dd : 1.0f;
        unsigned uw[4] = {raw.x, raw.y, raw.z, raw.w};
        #pragma unroll
        for (int k = 0; k < 4; ++k) {
            acc[2 * k]     = sw * __uint_as_float(uw[k] << 16);
            acc[2 * k + 1] = sw * __uint_as_float(uw[k] & 0xffff0000u);
        }
    }

    // masked 8-deep pipeline: all loads unconditional (clamped), weights masked
    for (int j0 = 0; j0 < c; j0 += UN) {
        int2 e[UN];
        #pragma unroll
        for (int i = 0; i < UN; ++i) e[i] = csr[beg + min(j0 + i, c - 1)];
        uint4 r[UN]; float w[UN];
        #pragma unroll
        for (int i = 0; i < UN; ++i) {
            r[i] = *(const uint4*)(hwb + (unsigned)e[i].x * ROWB + toff);
            float wr = __int_as_float(e[i].y);
            if (LOADDIS) wr *= dis[e[i].x];
            w[i] = (j0 + i < c) ? wr : 0.0f;
        }
        #pragma unroll
        for (int i = 0; i < UN; ++i) {
            unsigned u[4] = {r[i].x, r[i].y, r[i].z, r[i].w};
            #pragma unroll
            for (int k = 0; k < 4; ++k) {
                acc[2 * k]     = fmaf(w[i], __uint_as_float(u[k] << 16), acc[2 * k]);
                acc[2 * k + 1] = fmaf(w[i], __uint_as_float(u[k] & 0xffff0000u), acc[2 * k + 1]);
            }
        }
    }

    if (alive) {
        float4 b0 = *(const float4*)&bias[t * 8];
        float4 b1 = *(const float4*)&bias[t * 8 + 4];
        float bb[8] = {b0.x, b0.y, b0.z, b0.w, b1.x, b1.y, b1.z, b1.w};
        #pragma unroll
        for (int k = 0; k < 8; ++k) acc[k] = fmaf(dd, acc[k], bb[k]);   // dd factored out
        if (RELU) {
            #pragma unroll
            for (int k = 0; k < 8; ++k) acc[k] = fmaxf(acc[k], 0.0f);
        }
        if (!FINAL) {
            u16* o16 = (u16*)outv;
            uint4 pk;
            pk.x = (unsigned)f2bf(acc[0]) | ((unsigned)f2bf(acc[1]) << 16);
            pk.y = (unsigned)f2bf(acc[2]) | ((unsigned)f2bf(acc[3]) << 16);
            pk.z = (unsigned)f2bf(acc[4]) | ((unsigned)f2bf(acc[5]) << 16);
            pk.w = (unsigned)f2bf(acc[6]) | ((unsigned)f2bf(acc[7]) << 16);
            *(uint4*)&o16[(size_t)n * F + t * 8] = pk;
        } else {
            float4 r0 = make_float4(acc[0], acc[1], acc[2], acc[3]);
            float4 r1 = make_float4(acc[4], acc[5], acc[6], acc[7]);
            *(float4*)&out2[(size_t)n * F + t * 8] = r0;
            *(float4*)&out2[(size_t)n * F + t * 8 + 4] = r1;
            *(float4*)&out3[(size_t)n * F + t * 8] = r0;
            *(float4*)&out3[(size_t)n * F + t * 8 + 4] = r1;
            float mloc = acc[0];
            #pragma unroll
            for (int k = 1; k < 8; ++k) mloc = fmaxf(mloc, acc[k]);
            float m = fmaxf(mloc, __shfl_xor(mloc, 1));   // partner lane same group, same alive
            float sloc = 0.f;
            #pragma unroll
            for (int k = 0; k < 8; ++k) sloc += __expf(acc[k] - m);
            float ssum = sloc + __shfl_xor(sloc, 1);
            float ls = m + __logf(ssum);
            float* o = (float*)outv;
            float4 w0 = make_float4(acc[0] - ls, acc[1] - ls, acc[2] - ls, acc[3] - ls);
            float4 w1 = make_float4(acc[4] - ls, acc[5] - ls, acc[6] - ls, acc[7] - ls);
            *(float4*)&o[(size_t)n * F + t * 8] = w0;
            *(float4*)&o[(size_t)n * F + t * 8 + 4] = w1;
        }
    }
}

// ---------------- launch ----------------

extern "C" void kernel_launch(void* const* d_in, const int* in_sizes, int n_in,
                              void* d_out, int out_size, void* d_ws, size_t ws_size,
                              hipStream_t stream) {
    const float* x   = (const float*)d_in[0];
    const int*   ei  = (const int*)d_in[1];
    const float* ew  = (const float*)d_in[2];
    const float* W1  = (const float*)d_in[3];
    const float* b1  = (const float*)d_in[4];
    const float* W2  = (const float*)d_in[5];
    const float* b2  = (const float*)d_in[6];
    const float* W3  = (const float*)d_in[7];
    const float* b3  = (const float*)d_in[8];
    float* out = (float*)d_out;

    const int N = in_sizes[0] / N_FEAT;      // 100000
    const int E = in_sizes[2];               // 1600000
    const int NB = (N + (1 << NBW) - 1) >> NBW;   // 196

    size_t off = 0;
    auto alloc = [&](size_t bytes) {
        void* p = (char*)d_ws + off;
        off += (bytes + 255) & ~(size_t)255;
        return p;
    };
    float* dis     = (float*)alloc((size_t)N * 4);
    int*   cnt     = (int*)alloc((size_t)N * 4);
    int*   rowp    = (int*)alloc((size_t)N * 4);
    int*   bcur    = (int*)alloc(256 * 4);
    int2*  csr     = (int2*)alloc((size_t)NB * CAP * 8);
    int2*  ebuf    = (int2*)alloc((size_t)NB * CAP * 8);
    u16*   bufA16  = (u16*)alloc((size_t)N * 64 * 2);    // bf16 agg output (gemm input)
    u16*   hwB     = (u16*)alloc((size_t)N * 64 * 2);    // bf16 gemm output (gather side)
    u16*   hw16    = (u16*)alloc((size_t)N * 16 * 2);    // bf16 layer-3 gemm output
    uint4* Wp1     = (uint4*)alloc(512 * 16);            // B-fragment-packed weights
    uint4* Wp2     = (uint4*)alloc(512 * 16);
    uint4* Wp3     = (uint4*)alloc(128 * 16);

    const int TB = 256;

    int gblk = ((N + 15) / 16 + 3) / 4;      // gemm: one 16-row tile per wave
    int PB   = (E + 2047) / 2048;            // partition blocks

    // pack weights + zero cursors, then partition + fused gemm1, then CSR
    pack_init<<<4, TB, 0, stream>>>(W1, W2, W3, Wp1, Wp2, Wp3, bcur);
    part_gemm<<<PB + gblk, TB, 0, stream>>>(ei, ew, bcur, ebuf, E, NB, PB, x, Wp1, hwB, N);
    bucket_csr<<<NB, TB, 0, stream>>>(ebuf, bcur, csr, rowp, cnt, dis, N);

    int ablk64 = (N * 8 + TB - 1) / TB;      // 8 lanes/node
    int ablk16 = (N * 2 + TB - 1) / TB;      // 2 lanes/node

    float* logits = out + (size_t)N * 16;
    float* logits2 = out + (size_t)2 * N * 16;

    // layer 1 (hw unscaled; aggregate loads dis[src] per edge)
    aggregate<64, true, false, true><<<ablk64, TB, 0, stream>>>(hwB, rowp, cnt, csr, dis, b1, bufA16, nullptr, nullptr, N);
    // layer 2
    gemm_mf<64, true, true><<<gblk, TB, 0, stream>>>(bufA16, Wp2, dis, hwB, N);
    aggregate<64, true, false, false><<<ablk64, TB, 0, stream>>>(hwB, rowp, cnt, csr, dis, b2, bufA16, nullptr, nullptr, N);
    // layer 3 + fused log-softmax
    gemm_mf<16, true, true><<<gblk, TB, 0, stream>>>(bufA16, Wp3, dis, hw16, N);
    aggregate<16, false, true, false><<<ablk16, TB, 0, stream>>>(hw16, rowp, cnt, csr, dis, b3, out, logits, logits2, N);
}

// Round 18
// 168.338 us; speedup vs baseline: 2.6105x; 1.0420x over previous
//
#include <hip/hip_runtime.h>
#include <hip/hip_bf16.h>

#define N_FEAT 64
#define NBW 9                      // log2(nodes per bucket) = 512
#define SRC_BITS 23                // key = (dstLocal << 23) | src ; src < 2^23
#define CAP 9216                   // static bucket capacity (mean 8192 + >10 sigma)

typedef unsigned short u16;
typedef __attribute__((ext_vector_type(8))) short short8;   // 8 bf16 (4 VGPRs)
typedef __attribute__((ext_vector_type(4))) float f32x4;    // MFMA C/D

__device__ inline u16 f2bf(float f) {           // RNE f32 -> bf16
    unsigned u = __float_as_uint(f);
    u += 0x7fffu + ((u >> 16) & 1u);
    return (u16)(u >> 16);
}

// ---------------- pack W into MFMA B-fragment order + init cursors ----------

__device__ inline void packW(const float* __restrict__ W, uint4* __restrict__ Wpk,
                             int ncb, int wcols, int tid) {
    int nf = ncb * 2 * 64;
    for (int f = tid; f < nf; f += 256) {
        int cb = f >> 7;
        int s  = (f >> 6) & 1;
        int lane = f & 63;
        int kb = lane >> 4, c16 = lane & 15;
        union { uint4 q; u16 u[8]; } pk;
        #pragma unroll
        for (int i = 0; i < 8; ++i) {
            int k = s * 32 + kb * 8 + i;
            pk.u[i] = f2bf(W[k * wcols + cb * 16 + c16]);
        }
        Wpk[f] = pk.q;
    }
}

__global__ __launch_bounds__(256) void pack_init(const float* __restrict__ W1, const float* __restrict__ W2,
                                                 const float* __restrict__ W3,
                                                 uint4* Wp1, uint4* Wp2, uint4* Wp3, int* bcur) {
    if (blockIdx.x == 0)      packW(W1, Wp1, 4, 64, threadIdx.x);
    else if (blockIdx.x == 1) packW(W2, Wp2, 4, 64, threadIdx.x);
    else if (blockIdx.x == 2) packW(W3, Wp3, 1, 16, threadIdx.x);
    else                      bcur[threadIdx.x] = 0;
}

// ---------------- GEMM body via MFMA 16x16x32 bf16 (global A) ----------------

template<int OUTW, bool INBF, bool SCALE>
__device__ inline void gemm_body(const void* __restrict__ Av, const uint4* __restrict__ Wpk,
                                 const float* __restrict__ dis, u16* __restrict__ C, int N,
                                 int wid, int lane) {
    constexpr int NCB = OUTW / 16;
    int r0 = wid * 16;
    if (r0 >= N) return;
    int row16 = lane & 15, kb = lane >> 4;
    int r = min(r0 + row16, N - 1);

    short8 a0, a1;
    if (INBF) {
        const u16* arow = (const u16*)Av + (size_t)r * 64 + kb * 8;
        a0 = __builtin_bit_cast(short8, *(const uint4*)arow);
        a1 = __builtin_bit_cast(short8, *(const uint4*)(arow + 32));
    } else {
        const float* arow = (const float*)Av + (size_t)r * 64 + kb * 8;
        float4 f0 = *(const float4*)arow;
        float4 f1 = *(const float4*)(arow + 4);
        float4 f2 = *(const float4*)(arow + 32);
        float4 f3 = *(const float4*)(arow + 36);
        union { short8 v; u16 u[8]; } pa, pb;
        pa.u[0] = f2bf(f0.x); pa.u[1] = f2bf(f0.y); pa.u[2] = f2bf(f0.z); pa.u[3] = f2bf(f0.w);
        pa.u[4] = f2bf(f1.x); pa.u[5] = f2bf(f1.y); pa.u[6] = f2bf(f1.z); pa.u[7] = f2bf(f1.w);
        pb.u[0] = f2bf(f2.x); pb.u[1] = f2bf(f2.y); pb.u[2] = f2bf(f2.z); pb.u[3] = f2bf(f2.w);
        pb.u[4] = f2bf(f3.x); pb.u[5] = f2bf(f3.y); pb.u[6] = f2bf(f3.z); pb.u[7] = f2bf(f3.w);
        a0 = pa.v; a1 = pb.v;
    }

    f32x4 acc[NCB];
    #pragma unroll
    for (int cb = 0; cb < NCB; ++cb) {
        short8 b0 = __builtin_bit_cast(short8, Wpk[(cb * 2 + 0) * 64 + lane]);
        short8 b1 = __builtin_bit_cast(short8, Wpk[(cb * 2 + 1) * 64 + lane]);
        f32x4 z = {0.f, 0.f, 0.f, 0.f};
        z = __builtin_amdgcn_mfma_f32_16x16x32_bf16(a0, b0, z, 0, 0, 0);
        z = __builtin_amdgcn_mfma_f32_16x16x32_bf16(a1, b1, z, 0, 0, 0);
        acc[cb] = z;
    }

    int rbase = r0 + kb * 4;
    float dsc[4];
    #pragma unroll
    for (int j = 0; j < 4; ++j) dsc[j] = SCALE ? dis[min(rbase + j, N - 1)] : 1.0f;

    #pragma unroll
    for (int cb = 0; cb < NCB; ++cb) {
        int col = cb * 16 + row16;
        #pragma unroll
        for (int j = 0; j < 4; ++j) {
            int rr = rbase + j;
            if (rr < N) C[(size_t)rr * OUTW + col] = f2bf(SCALE ? acc[cb][j] * dsc[j] : acc[cb][j]);
        }
    }
}

// ---------------- partition (static buckets) + fused layer-1 GEMM ------------

__global__ __launch_bounds__(256) void part_gemm(const int* __restrict__ ei, const float* __restrict__ ew,
                                                 int* bcur, int2* __restrict__ ebuf, int E, int NB, int PB,
                                                 const float* __restrict__ x, const uint4* __restrict__ Wp1,
                                                 u16* __restrict__ hwB, int N) {
    constexpr int EPT = 8;
    __shared__ int cnt[256];
    __shared__ int base[256];
    int tid = threadIdx.x;

    if ((int)blockIdx.x >= PB) {                 // ---- gemm1 path ----
        int wid = (int)(((blockIdx.x - PB) * blockDim.x + tid) >> 6);
        gemm_body<64, false, false>(x, Wp1, nullptr, hwB, N, wid, tid & 63);
        return;
    }

    cnt[tid] = 0;
    __syncthreads();
    int start = blockIdx.x * (256 * EPT);

    int d[EPT], r[EPT], s[EPT]; float w[EPT];
    #pragma unroll
    for (int i = 0; i < EPT; ++i) {
        int e = start + i * 256 + tid;
        if (e < E) {
            d[i] = ei[E + e];
            s[i] = ei[e];
            w[i] = ew[e];
            r[i] = atomicAdd(&cnt[d[i] >> NBW], 1);
        } else d[i] = -1;
    }
    __syncthreads();
    if (tid < NB && cnt[tid]) base[tid] = atomicAdd(&bcur[tid], cnt[tid]);
    __syncthreads();
    #pragma unroll
    for (int i = 0; i < EPT; ++i) {
        if (d[i] >= 0) {
            int b = d[i] >> NBW;
            int dl = d[i] & ((1 << NBW) - 1);
            int gpos = base[b] + r[i];
            if (gpos < CAP) {
                int key = (dl << SRC_BITS) | s[i];
                ebuf[(size_t)b * CAP + gpos] = make_int2(key, __float_as_int(w[i]));
            }
        }
    }
}

__global__ __launch_bounds__(256) void bucket_csr(const int2* __restrict__ ebuf, const int* __restrict__ bcur,
                                                  int2* __restrict__ csr, int* __restrict__ rowp,
                                                  int* __restrict__ cnt, float* __restrict__ dis, int N) {
    __shared__ int   h[512];
    __shared__ float ws[512];
    __shared__ int   off[512];
    __shared__ int   wsum[4];
    int b = blockIdx.x, tid = threadIdx.x;
    int nbase = b << NBW;
    int nn = min(512, N - nbase);
    int beg = b * CAP;
    int m = min(bcur[b], CAP);

    h[tid] = 0; h[tid + 256] = 0;
    ws[tid] = 0.f; ws[tid + 256] = 0.f;
    __syncthreads();

    for (int i = tid; i < m; i += 256) {
        int2 en = ebuf[beg + i];
        int dl = ((unsigned)en.x) >> SRC_BITS;
        atomicAdd(&h[dl], 1);
        atomicAdd(&ws[dl], __int_as_float(en.y));
    }
    __syncthreads();

    int v0 = h[2 * tid], v1 = h[2 * tid + 1];
    int v = v0 + v1;
    int lane = tid & 63, wv = tid >> 6;
    int incl = v;
    #pragma unroll
    for (int o = 1; o < 64; o <<= 1) { int t = __shfl_up(incl, o); if (lane >= o) incl += t; }
    if (lane == 63) wsum[wv] = incl;
    __syncthreads();
    int add = 0;
    #pragma unroll
    for (int i = 0; i < 4; ++i) if (i < wv) add += wsum[i];
    int excl = add + incl - v;
    off[2 * tid] = excl;
    off[2 * tid + 1] = excl + v0;
    __syncthreads();

    for (int l = tid; l < nn; l += 256) {
        rowp[nbase + l] = beg + off[l];
        cnt[nbase + l]  = h[l];
        dis[nbase + l]  = rsqrtf(1.0f + ws[l]);
    }
    __syncthreads();
    h[tid] = 0; h[tid + 256] = 0;
    __syncthreads();

    for (int i = tid; i < m; i += 256) {
        int2 en = ebuf[beg + i];
        unsigned k = (unsigned)en.x;
        int dl  = k >> SRC_BITS;
        int src = k & ((1 << SRC_BITS) - 1);
        int pos = atomicAdd(&h[dl], 1);
        csr[beg + off[dl] + pos] = make_int2(src, en.y);   // raw ew
    }
}

// ---------------- Fused aggregate + next-layer GEMM ----------------
// Block = 4 waves = 32 nodes. Each wave aggregates 8 nodes (8 lanes/node,
// masked 8-deep gather pipeline), bias+relu, stages bf16 rows in LDS;
// sync; waves 0-1 run the 2x 16-row MFMA tiles of the NEXT layer's GEMM
// (epilogue scaled by dis[row]) and store to C. Deletes the bufA16
// round-trip and the standalone gemm dispatch.
// LOADDIS: hw unscaled (layer 1) -> w_e = ew*dis[src], self = dd*hw_n.

template<int OUTW, bool LOADDIS>
__global__ __launch_bounds__(256) void agg_gemm(const u16* __restrict__ hw, const int* __restrict__ rowp,
                                                const int* __restrict__ cnt, const int2* __restrict__ csr,
                                                const float* __restrict__ dis, const float* __restrict__ bias,
                                                const uint4* __restrict__ Wpk, u16* __restrict__ C, int N) {
    constexpr int UN = 8;
    __shared__ u16 As[32 * 64];          // 4KB staged agg output (gemm input tile)

    int tid  = threadIdx.x;
    int w    = tid >> 6;
    int lane = tid & 63;
    int g = lane >> 3;                   // node slot in wave (8 lanes/node)
    int t = lane & 7;                    // 16B chunk in row
    int l = w * 8 + g;                   // local row 0..31
    int n = blockIdx.x * 32 + l;
    bool alive = (n < N);
    n = min(n, N - 1);

    float dd = dis[n];
    int beg = rowp[n];
    int c   = cnt[n];
    const char* hwb = (const char*)hw;
    unsigned toff = (unsigned)t * 16u;

    float acc[8];
    {   // self term
        uint4 raw = *(const uint4*)(hwb + (unsigned)n * 128u + toff);
        float sw = LOADDIS ? dd : 1.0f;
        unsigned uw[4] = {raw.x, raw.y, raw.z, raw.w};
        #pragma unroll
        for (int k = 0; k < 4; ++k) {
            acc[2 * k]     = sw * __uint_as_float(uw[k] << 16);
            acc[2 * k + 1] = sw * __uint_as_float(uw[k] & 0xffff0000u);
        }
    }

    for (int j0 = 0; j0 < c; j0 += UN) {
        int2 e[UN];
        #pragma unroll
        for (int i = 0; i < UN; ++i) e[i] = csr[beg + min(j0 + i, c - 1)];
        uint4 r[UN]; float wgt[UN];
        #pragma unroll
        for (int i = 0; i < UN; ++i) {
            r[i] = *(const uint4*)(hwb + (unsigned)e[i].x * 128u + toff);
            float wr = __int_as_float(e[i].y);
            if (LOADDIS) wr *= dis[e[i].x];
            wgt[i] = (j0 + i < c) ? wr : 0.0f;
        }
        #pragma unroll
        for (int i = 0; i < UN; ++i) {
            unsigned u[4] = {r[i].x, r[i].y, r[i].z, r[i].w};
            #pragma unroll
            for (int k = 0; k < 4; ++k) {
                acc[2 * k]     = fmaf(wgt[i], __uint_as_float(u[k] << 16), acc[2 * k]);
                acc[2 * k + 1] = fmaf(wgt[i], __uint_as_float(u[k] & 0xffff0000u), acc[2 * k + 1]);
            }
        }
    }

    {   // bias + relu + stage to LDS (unconditional: dead rows masked at store)
        float4 b0 = *(const float4*)&bias[t * 8];
        float4 b1 = *(const float4*)&bias[t * 8 + 4];
        float bb[8] = {b0.x, b0.y, b0.z, b0.w, b1.x, b1.y, b1.z, b1.w};
        #pragma unroll
        for (int k = 0; k < 8; ++k) acc[k] = fmaxf(fmaf(dd, acc[k], bb[k]), 0.0f);
        uint4 pk;
        pk.x = (unsigned)f2bf(acc[0]) | ((unsigned)f2bf(acc[1]) << 16);
        pk.y = (unsigned)f2bf(acc[2]) | ((unsigned)f2bf(acc[3]) << 16);
        pk.z = (unsigned)f2bf(acc[4]) | ((unsigned)f2bf(acc[5]) << 16);
        pk.w = (unsigned)f2bf(acc[6]) | ((unsigned)f2bf(acc[7]) << 16);
        *(uint4*)&As[l * 64 + t * 8] = pk;
    }
    __syncthreads();

    // ---- next-layer GEMM on the 32 staged rows (waves 0,1) ----
    if (w < 2) {
        constexpr int NCB = OUTW / 16;
        int r0 = blockIdx.x * 32 + w * 16;
        if (r0 < N) {
            int row16 = lane & 15, kb = lane >> 4;
            const u16* arow = &As[(w * 16 + row16) * 64 + kb * 8];
            short8 a0 = __builtin_bit_cast(short8, *(const uint4*)arow);
            short8 a1 = __builtin_bit_cast(short8, *(const uint4*)(arow + 32));

            f32x4 za[NCB];
            #pragma unroll
            for (int cb = 0; cb < NCB; ++cb) {
                short8 b0 = __builtin_bit_cast(short8, Wpk[(cb * 2 + 0) * 64 + lane]);
                short8 b1 = __builtin_bit_cast(short8, Wpk[(cb * 2 + 1) * 64 + lane]);
                f32x4 z = {0.f, 0.f, 0.f, 0.f};
                z = __builtin_amdgcn_mfma_f32_16x16x32_bf16(a0, b0, z, 0, 0, 0);
                z = __builtin_amdgcn_mfma_f32_16x16x32_bf16(a1, b1, z, 0, 0, 0);
                za[cb] = z;
            }

            int rbase = r0 + kb * 4;
            float dsc[4];
            #pragma unroll
            for (int j = 0; j < 4; ++j) dsc[j] = dis[min(rbase + j, N - 1)];
            #pragma unroll
            for (int cb = 0; cb < NCB; ++cb) {
                int col = cb * 16 + row16;
                #pragma unroll
                for (int j = 0; j < 4; ++j) {
                    int rr = rbase + j;
                    if (rr < N) C[(size_t)rr * OUTW + col] = f2bf(za[cb][j] * dsc[j]);
                }
            }
        }
    }
}

// ---------------- Final aggregation (F=16) + fused log-softmax ----------------

__global__ __launch_bounds__(256) void agg_final(const u16* __restrict__ hw, const int* __restrict__ rowp,
                                                 const int* __restrict__ cnt, const int2* __restrict__ csr,
                                                 const float* __restrict__ dis, const float* __restrict__ bias,
                                                 float* __restrict__ out0, float* __restrict__ out2,
                                                 float* __restrict__ out3, int N) {
    constexpr int UN = 8;
    int wv   = (int)((blockIdx.x * blockDim.x + threadIdx.x) >> 6);
    int lane = threadIdx.x & 63;
    int g = lane >> 1;                   // 32 nodes per wave, 2 lanes/node
    int t = lane & 1;
    int n = wv * 32 + g;
    bool alive = (n < N);
    n = min(n, N - 1);

    float dd = dis[n];
    int beg = rowp[n];
    int c   = cnt[n];
    const char* hwb = (const char*)hw;
    unsigned toff = (unsigned)t * 16u;

    float acc[8];
    {
        uint4 raw = *(const uint4*)(hwb + (unsigned)n * 32u + toff);
        unsigned uw[4] = {raw.x, raw.y, raw.z, raw.w};
        #pragma unroll
        for (int k = 0; k < 4; ++k) {
            acc[2 * k]     = __uint_as_float(uw[k] << 16);
            acc[2 * k + 1] = __uint_as_float(uw[k] & 0xffff0000u);
        }
    }

    for (int j0 = 0; j0 < c; j0 += UN) {
        int2 e[UN];
        #pragma unroll
        for (int i = 0; i < UN; ++i) e[i] = csr[beg + min(j0 + i, c - 1)];
        uint4 r[UN]; float wgt[UN];
        #pragma unroll
        for (int i = 0; i < UN; ++i) {
            r[i] = *(const uint4*)(hwb + (unsigned)e[i].x * 32u + toff);
            wgt[i] = (j0 + i < c) ? __int_as_float(e[i].y) : 0.0f;
        }
        #pragma unroll
        for (int i = 0; i < UN; ++i) {
            unsigned u[4] = {r[i].x, r[i].y, r[i].z, r[i].w};
            #pragma unroll
            for (int k = 0; k < 4; ++k) {
                acc[2 * k]     = fmaf(wgt[i], __uint_as_float(u[k] << 16), acc[2 * k]);
                acc[2 * k + 1] = fmaf(wgt[i], __uint_as_float(u[k] & 0xffff0000u), acc[2 * k + 1]);
            }
        }
    }

    if (alive) {
        float4 b0 = *(const float4*)&bias[t * 8];
        float4 b1 = *(const float4*)&bias[t * 8 + 4];
        float bb[8] = {b0.x, b0.y, b0.z, b0.w, b1.x, b1.y, b1.z, b1.w};
        #pragma unroll
        for (int k = 0; k < 8; ++k) acc[k] = fmaf(dd, acc[k], bb[k]);

        float4 r0 = make_float4(acc[0], acc[1], acc[2], acc[3]);
        float4 r1 = make_float4(acc[4], acc[5], acc[6], acc[7]);
        *(float4*)&out2[(size_t)n * 16 + t * 8] = r0;
        *(float4*)&out2[(size_t)n * 16 + t * 8 + 4] = r1;
        *(float4*)&out3[(size_t)n * 16 + t * 8] = r0;
        *(float4*)&out3[(size_t)n * 16 + t * 8 + 4] = r1;
        float mloc = acc[0];
        #pragma unroll
        for (int k = 1; k < 8; ++k) mloc = fmaxf(mloc, acc[k]);
        float m = fmaxf(mloc, __shfl_xor(mloc, 1));
        float sloc = 0.f;
        #pragma unroll
        for (int k = 0; k < 8; ++k) sloc += __expf(acc[k] - m);
        float ssum = sloc + __shfl_xor(sloc, 1);
        float ls = m + __logf(ssum);
        float4 w0 = make_float4(acc[0] - ls, acc[1] - ls, acc[2] - ls, acc[3] - ls);
        float4 w1 = make_float4(acc[4] - ls, acc[5] - ls, acc[6] - ls, acc[7] - ls);
        *(float4*)&out0[(size_t)n * 16 + t * 8] = w0;
        *(float4*)&out0[(size_t)n * 16 + t * 8 + 4] = w1;
    }
}

// ---------------- launch ----------------

extern "C" void kernel_launch(void* const* d_in, const int* in_sizes, int n_in,
                              void* d_out, int out_size, void* d_ws, size_t ws_size,
                              hipStream_t stream) {
    const float* x   = (const float*)d_in[0];
    const int*   ei  = (const int*)d_in[1];
    const float* ew  = (const float*)d_in[2];
    const float* W1  = (const float*)d_in[3];
    const float* b1  = (const float*)d_in[4];
    const float* W2  = (const float*)d_in[5];
    const float* b2  = (const float*)d_in[6];
    const float* W3  = (const float*)d_in[7];
    const float* b3  = (const float*)d_in[8];
    float* out = (float*)d_out;

    const int N = in_sizes[0] / N_FEAT;      // 100000
    const int E = in_sizes[2];               // 1600000
    const int NB = (N + (1 << NBW) - 1) >> NBW;   // 196

    size_t off = 0;
    auto alloc = [&](size_t bytes) {
        void* p = (char*)d_ws + off;
        off += (bytes + 255) & ~(size_t)255;
        return p;
    };
    float* dis     = (float*)alloc((size_t)N * 4);
    int*   cnt     = (int*)alloc((size_t)N * 4);
    int*   rowp    = (int*)alloc((size_t)N * 4);
    int*   bcur    = (int*)alloc(256 * 4);
    int2*  csr     = (int2*)alloc((size_t)NB * CAP * 8);
    int2*  ebuf    = (int2*)alloc((size_t)NB * CAP * 8);
    u16*   hwB     = (u16*)alloc((size_t)N * 64 * 2);    // gemm1 out (layer-1 gather table)
    u16*   hwB2    = (u16*)alloc((size_t)N * 64 * 2);    // gemm2 out (layer-2 gather table)
    u16*   hw16    = (u16*)alloc((size_t)N * 16 * 2);    // gemm3 out (layer-3 gather table)
    uint4* Wp1     = (uint4*)alloc(512 * 16);            // B-fragment-packed weights
    uint4* Wp2     = (uint4*)alloc(512 * 16);
    uint4* Wp3     = (uint4*)alloc(128 * 16);

    const int TB = 256;

    int gblk = ((N + 15) / 16 + 3) / 4;      // gemm1: one 16-row tile per wave
    int PB   = (E + 2047) / 2048;            // partition blocks
    int fblk = (N + 31) / 32;                // fused agg+gemm blocks (32 nodes each)
    int ablk16 = (N * 2 + TB - 1) / TB;      // final agg: 2 lanes/node

    float* logits = out + (size_t)N * 16;
    float* logits2 = out + (size_t)2 * N * 16;

    // pack weights + zero cursors; partition + fused gemm1; bucket CSR
    pack_init<<<4, TB, 0, stream>>>(W1, W2, W3, Wp1, Wp2, Wp3, bcur);
    part_gemm<<<PB + gblk, TB, 0, stream>>>(ei, ew, bcur, ebuf, E, NB, PB, x, Wp1, hwB, N);
    bucket_csr<<<NB, TB, 0, stream>>>(ebuf, bcur, csr, rowp, cnt, dis, N);

    // layer 1 aggregate (LOADDIS) + layer-2 GEMM fused
    agg_gemm<64, true><<<fblk, TB, 0, stream>>>(hwB, rowp, cnt, csr, dis, b1, Wp2, hwB2, N);
    // layer 2 aggregate + layer-3 GEMM fused
    agg_gemm<16, false><<<fblk, TB, 0, stream>>>(hwB2, rowp, cnt, csr, dis, b2, Wp3, hw16, N);
    // layer 3 aggregate + log-softmax
    agg_final<<<ablk16, TB, 0, stream>>>(hw16, rowp, cnt, csr, dis, b3, out, logits, logits2, N);
}

// Round 20
// 163.776 us; speedup vs baseline: 2.6832x; 1.0279x over previous
//
#include <hip/hip_runtime.h>
#include <hip/hip_bf16.h>

#define N_FEAT 64
#define NBW 9                      // log2(nodes per bucket) = 512
#define SRC_BITS 23                // key = (dstLocal << 23) | src ; src < 2^23
#define CAP 9216                   // static bucket capacity (mean 8192 + >10 sigma)

typedef unsigned short u16;
typedef __attribute__((ext_vector_type(8))) short short8;   // 8 bf16 (4 VGPRs)
typedef __attribute__((ext_vector_type(4))) float f32x4;    // MFMA C/D

__device__ inline u16 f2bf(float f) {           // RNE f32 -> bf16
    unsigned u = __float_as_uint(f);
    u += 0x7fffu + ((u >> 16) & 1u);
    return (u16)(u >> 16);
}

// ---------------- pack W into MFMA B-fragment order + init cursors ----------

__device__ inline void packW(const float* __restrict__ W, uint4* __restrict__ Wpk,
                             int ncb, int wcols, int tid) {
    int nf = ncb * 2 * 64;
    for (int f = tid; f < nf; f += 256) {
        int cb = f >> 7;
        int s  = (f >> 6) & 1;
        int lane = f & 63;
        int kb = lane >> 4, c16 = lane & 15;
        union { uint4 q; u16 u[8]; } pk;
        #pragma unroll
        for (int i = 0; i < 8; ++i) {
            int k = s * 32 + kb * 8 + i;
            pk.u[i] = f2bf(W[k * wcols + cb * 16 + c16]);
        }
        Wpk[f] = pk.q;
    }
}

__global__ __launch_bounds__(256) void pack_init(const float* __restrict__ W1, const float* __restrict__ W2,
                                                 const float* __restrict__ W3,
                                                 uint4* Wp1, uint4* Wp2, uint4* Wp3, int* bcur) {
    if (blockIdx.x == 0)      packW(W1, Wp1, 4, 64, threadIdx.x);
    else if (blockIdx.x == 1) packW(W2, Wp2, 4, 64, threadIdx.x);
    else if (blockIdx.x == 2) packW(W3, Wp3, 1, 16, threadIdx.x);
    else                      bcur[threadIdx.x] = 0;
}

// ---------------- GEMM body via MFMA 16x16x32 bf16 (global A) ----------------

template<int OUTW, bool INBF, bool SCALE>
__device__ inline void gemm_body(const void* __restrict__ Av, const uint4* __restrict__ Wpk,
                                 const float* __restrict__ dis, u16* __restrict__ C, int N,
                                 int wid, int lane) {
    constexpr int NCB = OUTW / 16;
    int r0 = wid * 16;
    if (r0 >= N) return;
    int row16 = lane & 15, kb = lane >> 4;
    int r = min(r0 + row16, N - 1);

    short8 a0, a1;
    if (INBF) {
        const u16* arow = (const u16*)Av + (size_t)r * 64 + kb * 8;
        a0 = __builtin_bit_cast(short8, *(const uint4*)arow);
        a1 = __builtin_bit_cast(short8, *(const uint4*)(arow + 32));
    } else {
        const float* arow = (const float*)Av + (size_t)r * 64 + kb * 8;
        float4 f0 = *(const float4*)arow;
        float4 f1 = *(const float4*)(arow + 4);
        float4 f2 = *(const float4*)(arow + 32);
        float4 f3 = *(const float4*)(arow + 36);
        union { short8 v; u16 u[8]; } pa, pb;
        pa.u[0] = f2bf(f0.x); pa.u[1] = f2bf(f0.y); pa.u[2] = f2bf(f0.z); pa.u[3] = f2bf(f0.w);
        pa.u[4] = f2bf(f1.x); pa.u[5] = f2bf(f1.y); pa.u[6] = f2bf(f1.z); pa.u[7] = f2bf(f1.w);
        pb.u[0] = f2bf(f2.x); pb.u[1] = f2bf(f2.y); pb.u[2] = f2bf(f2.z); pb.u[3] = f2bf(f2.w);
        pb.u[4] = f2bf(f3.x); pb.u[5] = f2bf(f3.y); pb.u[6] = f2bf(f3.z); pb.u[7] = f2bf(f3.w);
        a0 = pa.v; a1 = pb.v;
    }

    f32x4 acc[NCB];
    #pragma unroll
    for (int cb = 0; cb < NCB; ++cb) {
        short8 b0 = __builtin_bit_cast(short8, Wpk[(cb * 2 + 0) * 64 + lane]);
        short8 b1 = __builtin_bit_cast(short8, Wpk[(cb * 2 + 1) * 64 + lane]);
        f32x4 z = {0.f, 0.f, 0.f, 0.f};
        z = __builtin_amdgcn_mfma_f32_16x16x32_bf16(a0, b0, z, 0, 0, 0);
        z = __builtin_amdgcn_mfma_f32_16x16x32_bf16(a1, b1, z, 0, 0, 0);
        acc[cb] = z;
    }

    int rbase = r0 + kb * 4;
    float dsc[4];
    #pragma unroll
    for (int j = 0; j < 4; ++j) dsc[j] = SCALE ? dis[min(rbase + j, N - 1)] : 1.0f;

    #pragma unroll
    for (int cb = 0; cb < NCB; ++cb) {
        int col = cb * 16 + row16;
        #pragma unroll
        for (int j = 0; j < 4; ++j) {
            int rr = rbase + j;
            if (rr < N) C[(size_t)rr * OUTW + col] = f2bf(SCALE ? acc[cb][j] * dsc[j] : acc[cb][j]);
        }
    }
}

// ---------------- partition (static buckets) + fused layer-1 GEMM ------------

__global__ __launch_bounds__(256) void part_gemm(const int* __restrict__ ei, const float* __restrict__ ew,
                                                 int* bcur, int2* __restrict__ ebuf, int E, int NB, int PB,
                                                 const float* __restrict__ x, const uint4* __restrict__ Wp1,
                                                 u16* __restrict__ hwB, int N) {
    constexpr int EPT = 8;
    __shared__ int cnt[256];
    __shared__ int base[256];
    int tid = threadIdx.x;

    if ((int)blockIdx.x >= PB) {                 // ---- gemm1 path ----
        int wid = (int)(((blockIdx.x - PB) * blockDim.x + tid) >> 6);
        gemm_body<64, false, false>(x, Wp1, nullptr, hwB, N, wid, tid & 63);
        return;
    }

    cnt[tid] = 0;
    __syncthreads();
    int start = blockIdx.x * (256 * EPT);

    int d[EPT], r[EPT], s[EPT]; float w[EPT];
    #pragma unroll
    for (int i = 0; i < EPT; ++i) {
        int e = start + i * 256 + tid;
        if (e < E) {
            d[i] = ei[E + e];
            s[i] = ei[e];
            w[i] = ew[e];
            r[i] = atomicAdd(&cnt[d[i] >> NBW], 1);
        } else d[i] = -1;
    }
    __syncthreads();
    if (tid < NB && cnt[tid]) base[tid] = atomicAdd(&bcur[tid], cnt[tid]);
    __syncthreads();
    #pragma unroll
    for (int i = 0; i < EPT; ++i) {
        if (d[i] >= 0) {
            int b = d[i] >> NBW;
            int dl = d[i] & ((1 << NBW) - 1);
            int gpos = base[b] + r[i];
            if (gpos < CAP) {
                int key = (dl << SRC_BITS) | s[i];
                ebuf[(size_t)b * CAP + gpos] = make_int2(key, __float_as_int(w[i]));
            }
        }
    }
}

__global__ __launch_bounds__(256) void bucket_csr(const int2* __restrict__ ebuf, const int* __restrict__ bcur,
                                                  int2* __restrict__ csr, int* __restrict__ rowp,
                                                  int* __restrict__ cnt, float* __restrict__ dis, int N) {
    __shared__ int   h[512];
    __shared__ float ws[512];
    __shared__ int   off[512];
    __shared__ int   wsum[4];
    int b = blockIdx.x, tid = threadIdx.x;
    int nbase = b << NBW;
    int nn = min(512, N - nbase);
    int beg = b * CAP;
    int m = min(bcur[b], CAP);

    h[tid] = 0; h[tid + 256] = 0;
    ws[tid] = 0.f; ws[tid + 256] = 0.f;
    __syncthreads();

    for (int i = tid; i < m; i += 256) {
        int2 en = ebuf[beg + i];
        int dl = ((unsigned)en.x) >> SRC_BITS;
        atomicAdd(&h[dl], 1);
        atomicAdd(&ws[dl], __int_as_float(en.y));
    }
    __syncthreads();

    int v0 = h[2 * tid], v1 = h[2 * tid + 1];
    int v = v0 + v1;
    int lane = tid & 63, wv = tid >> 6;
    int incl = v;
    #pragma unroll
    for (int o = 1; o < 64; o <<= 1) { int t = __shfl_up(incl, o); if (lane >= o) incl += t; }
    if (lane == 63) wsum[wv] = incl;
    __syncthreads();
    int add = 0;
    #pragma unroll
    for (int i = 0; i < 4; ++i) if (i < wv) add += wsum[i];
    int excl = add + incl - v;
    off[2 * tid] = excl;
    off[2 * tid + 1] = excl + v0;
    __syncthreads();

    for (int l = tid; l < nn; l += 256) {
        rowp[nbase + l] = beg + off[l];
        cnt[nbase + l]  = h[l];
        dis[nbase + l]  = rsqrtf(1.0f + ws[l]);
    }
    __syncthreads();
    h[tid] = 0; h[tid + 256] = 0;
    __syncthreads();

    for (int i = tid; i < m; i += 256) {
        int2 en = ebuf[beg + i];
        unsigned k = (unsigned)en.x;
        int dl  = k >> SRC_BITS;
        int src = k & ((1 << SRC_BITS) - 1);
        int pos = atomicAdd(&h[dl], 1);
        csr[beg + off[dl] + pos] = make_int2(src, en.y);   // raw ew
    }

    // SENTINEL PAD: the aggregation loop's double-buffered batch reads can
    // overrun the last row of this bucket by up to 15 entries into [m, CAP)
    // (uninitialized workspace). Zero-fill {src=0, w=0} so prefetched loads
    // always see a valid node index; weights are masked to zero anyway.
    if (tid < 16) csr[beg + m + tid] = make_int2(0, 0);
}

// ---------------- Fused aggregate + next-layer GEMM ----------------
// Block = 4 waves = 32 nodes, 8 lanes/node. Gather inner loop: csr batch
// double-buffered (next batch's loads issue under current gathers); reads
// may overrun a row into following rows / sentinel pad (always valid).
// After staging to LDS, ALL 4 waves run the next-layer GEMM: wave =
// (row-tile, col-half) for OUTW=64; waves 0-1 for OUTW=16 (NCB=1).
// LOADDIS: hw unscaled (layer 1) -> w_e = ew*dis[src], self = dd*hw_n.

template<int OUTW, bool LOADDIS>
__global__ __launch_bounds__(256) void agg_gemm(const u16* __restrict__ hw, const int* __restrict__ rowp,
                                                const int* __restrict__ cnt, const int2* __restrict__ csr,
                                                const float* __restrict__ dis, const float* __restrict__ bias,
                                                const uint4* __restrict__ Wpk, u16* __restrict__ C, int N) {
    constexpr int UN = 8;
    __shared__ u16 As[32 * 64];          // 4KB staged agg output (gemm input tile)

    int tid  = threadIdx.x;
    int w    = tid >> 6;
    int lane = tid & 63;
    int g = lane >> 3;                   // node slot in wave (8 lanes/node)
    int t = lane & 7;                    // 16B chunk in row
    int l = w * 8 + g;                   // local row 0..31
    int n = blockIdx.x * 32 + l;
    n = min(n, N - 1);

    float dd = dis[n];
    int beg = rowp[n];
    int c   = cnt[n];
    const char* hwb = (const char*)hw;
    unsigned toff = (unsigned)t * 16u;

    float acc[8];
    {   // self term
        uint4 raw = *(const uint4*)(hwb + (unsigned)n * 128u + toff);
        float sw = LOADDIS ? dd : 1.0f;
        unsigned uw[4] = {raw.x, raw.y, raw.z, raw.w};
        #pragma unroll
        for (int k = 0; k < 4; ++k) {
            acc[2 * k]     = sw * __uint_as_float(uw[k] << 16);
            acc[2 * k + 1] = sw * __uint_as_float(uw[k] & 0xffff0000u);
        }
    }

    // gather loop: csr batch double-buffered (overruns land on valid entries)
    int2 e[UN];
    #pragma unroll
    for (int i = 0; i < UN; ++i) e[i] = csr[beg + i];
    for (int j0 = 0; j0 < c; j0 += UN) {
        uint4 r[UN];
        #pragma unroll
        for (int i = 0; i < UN; ++i)
            r[i] = *(const uint4*)(hwb + (unsigned)e[i].x * 128u + toff);
        int2 en[UN];
        #pragma unroll
        for (int i = 0; i < UN; ++i) en[i] = csr[beg + j0 + UN + i];   // prefetch next
        float wgt[UN];
        #pragma unroll
        for (int i = 0; i < UN; ++i) {
            float wr = __int_as_float(e[i].y);
            if (LOADDIS) wr *= dis[e[i].x];
            wgt[i] = (j0 + i < c) ? wr : 0.0f;
        }
        #pragma unroll
        for (int i = 0; i < UN; ++i) {
            unsigned u[4] = {r[i].x, r[i].y, r[i].z, r[i].w};
            #pragma unroll
            for (int k = 0; k < 4; ++k) {
                acc[2 * k]     = fmaf(wgt[i], __uint_as_float(u[k] << 16), acc[2 * k]);
                acc[2 * k + 1] = fmaf(wgt[i], __uint_as_float(u[k] & 0xffff0000u), acc[2 * k + 1]);
            }
        }
        #pragma unroll
        for (int i = 0; i < UN; ++i) e[i] = en[i];
    }

    {   // bias + relu + stage to LDS (dead rows stage garbage; masked at C store)
        float4 b0 = *(const float4*)&bias[t * 8];
        float4 b1 = *(const float4*)&bias[t * 8 + 4];
        float bb[8] = {b0.x, b0.y, b0.z, b0.w, b1.x, b1.y, b1.z, b1.w};
        #pragma unroll
        for (int k = 0; k < 8; ++k) acc[k] = fmaxf(fmaf(dd, acc[k], bb[k]), 0.0f);
        uint4 pk;
        pk.x = (unsigned)f2bf(acc[0]) | ((unsigned)f2bf(acc[1]) << 16);
        pk.y = (unsigned)f2bf(acc[2]) | ((unsigned)f2bf(acc[3]) << 16);
        pk.z = (unsigned)f2bf(acc[4]) | ((unsigned)f2bf(acc[5]) << 16);
        pk.w = (unsigned)f2bf(acc[6]) | ((unsigned)f2bf(acc[7]) << 16);
        *(uint4*)&As[l * 64 + t * 8] = pk;
    }
    __syncthreads();

    // ---- next-layer GEMM on the 32 staged rows ----
    if (OUTW == 64) {
        // 4 waves: wave = (row-tile = w>>1, col-half = w&1), 2 col-blocks each
        int tile = w >> 1, half = w & 1;
        int r0 = blockIdx.x * 32 + tile * 16;
        if (r0 < N) {
            int row16 = lane & 15, kb = lane >> 4;
            const u16* arow = &As[(tile * 16 + row16) * 64 + kb * 8];
            short8 a0 = __builtin_bit_cast(short8, *(const uint4*)arow);
            short8 a1 = __builtin_bit_cast(short8, *(const uint4*)(arow + 32));

            f32x4 za[2];
            #pragma unroll
            for (int c2 = 0; c2 < 2; ++c2) {
                int cb = half * 2 + c2;
                short8 b0 = __builtin_bit_cast(short8, Wpk[(cb * 2 + 0) * 64 + lane]);
                short8 b1 = __builtin_bit_cast(short8, Wpk[(cb * 2 + 1) * 64 + lane]);
                f32x4 z = {0.f, 0.f, 0.f, 0.f};
                z = __builtin_amdgcn_mfma_f32_16x16x32_bf16(a0, b0, z, 0, 0, 0);
                z = __builtin_amdgcn_mfma_f32_16x16x32_bf16(a1, b1, z, 0, 0, 0);
                za[c2] = z;
            }

            int rbase = r0 + kb * 4;
            float dsc[4];
            #pragma unroll
            for (int j = 0; j < 4; ++j) dsc[j] = dis[min(rbase + j, N - 1)];
            #pragma unroll
            for (int c2 = 0; c2 < 2; ++c2) {
                int col = (half * 2 + c2) * 16 + row16;
                #pragma unroll
                for (int j = 0; j < 4; ++j) {
                    int rr = rbase + j;
                    if (rr < N) C[(size_t)rr * 64 + col] = f2bf(za[c2][j] * dsc[j]);
                }
            }
        }
    } else {
        // OUTW=16 (NCB=1): waves 0,1 each do one 16-row tile
        if (w < 2) {
            int r0 = blockIdx.x * 32 + w * 16;
            if (r0 < N) {
                int row16 = lane & 15, kb = lane >> 4;
                const u16* arow = &As[(w * 16 + row16) * 64 + kb * 8];
                short8 a0 = __builtin_bit_cast(short8, *(const uint4*)arow);
                short8 a1 = __builtin_bit_cast(short8, *(const uint4*)(arow + 32));
                short8 b0 = __builtin_bit_cast(short8, Wpk[0 * 64 + lane]);
                short8 b1 = __builtin_bit_cast(short8, Wpk[1 * 64 + lane]);
                f32x4 z = {0.f, 0.f, 0.f, 0.f};
                z = __builtin_amdgcn_mfma_f32_16x16x32_bf16(a0, b0, z, 0, 0, 0);
                z = __builtin_amdgcn_mfma_f32_16x16x32_bf16(a1, b1, z, 0, 0, 0);

                int rbase = r0 + kb * 4;
                float dsc[4];
                #pragma unroll
                for (int j = 0; j < 4; ++j) dsc[j] = dis[min(rbase + j, N - 1)];
                int col = row16;
                #pragma unroll
                for (int j = 0; j < 4; ++j) {
                    int rr = rbase + j;
                    if (rr < N) C[(size_t)rr * 16 + col] = f2bf(z[j] * dsc[j]);
                }
            }
        }
    }
}

// ---------------- Final aggregation (F=16) + fused log-softmax ----------------

__global__ __launch_bounds__(256) void agg_final(const u16* __restrict__ hw, const int* __restrict__ rowp,
                                                 const int* __restrict__ cnt, const int2* __restrict__ csr,
                                                 const float* __restrict__ dis, const float* __restrict__ bias,
                                                 float* __restrict__ out0, float* __restrict__ out2,
                                                 float* __restrict__ out3, int N) {
    constexpr int UN = 8;
    int wv   = (int)((blockIdx.x * blockDim.x + threadIdx.x) >> 6);
    int lane = threadIdx.x & 63;
    int g = lane >> 1;                   // 32 nodes per wave, 2 lanes/node
    int t = lane & 1;
    int n = wv * 32 + g;
    bool alive = (n < N);
    n = min(n, N - 1);

    float dd = dis[n];
    int beg = rowp[n];
    int c   = cnt[n];
    const char* hwb = (const char*)hw;
    unsigned toff = (unsigned)t * 16u;

    float acc[8];
    {
        uint4 raw = *(const uint4*)(hwb + (unsigned)n * 32u + toff);
        unsigned uw[4] = {raw.x, raw.y, raw.z, raw.w};
        #pragma unroll
        for (int k = 0; k < 4; ++k) {
            acc[2 * k]     = __uint_as_float(uw[k] << 16);
            acc[2 * k + 1] = __uint_as_float(uw[k] & 0xffff0000u);
        }
    }

    int2 e[UN];
    #pragma unroll
    for (int i = 0; i < UN; ++i) e[i] = csr[beg + i];
    for (int j0 = 0; j0 < c; j0 += UN) {
        uint4 r[UN];
        #pragma unroll
        for (int i = 0; i < UN; ++i)
            r[i] = *(const uint4*)(hwb + (unsigned)e[i].x * 32u + toff);
        int2 en[UN];
        #pragma unroll
        for (int i = 0; i < UN; ++i) en[i] = csr[beg + j0 + UN + i];
        float wgt[UN];
        #pragma unroll
        for (int i = 0; i < UN; ++i) wgt[i] = (j0 + i < c) ? __int_as_float(e[i].y) : 0.0f;
        #pragma unroll
        for (int i = 0; i < UN; ++i) {
            unsigned u[4] = {r[i].x, r[i].y, r[i].z, r[i].w};
            #pragma unroll
            for (int k = 0; k < 4; ++k) {
                acc[2 * k]     = fmaf(wgt[i], __uint_as_float(u[k] << 16), acc[2 * k]);
                acc[2 * k + 1] = fmaf(wgt[i], __uint_as_float(u[k] & 0xffff0000u), acc[2 * k + 1]);
            }
        }
        #pragma unroll
        for (int i = 0; i < UN; ++i) e[i] = en[i];
    }

    if (alive) {
        float4 b0 = *(const float4*)&bias[t * 8];
        float4 b1 = *(const float4*)&bias[t * 8 + 4];
        float bb[8] = {b0.x, b0.y, b0.z, b0.w, b1.x, b1.y, b1.z, b1.w};
        #pragma unroll
        for (int k = 0; k < 8; ++k) acc[k] = fmaf(dd, acc[k], bb[k]);

        float4 r0 = make_float4(acc[0], acc[1], acc[2], acc[3]);
        float4 r1 = make_float4(acc[4], acc[5], acc[6], acc[7]);
        *(float4*)&out2[(size_t)n * 16 + t * 8] = r0;
        *(float4*)&out2[(size_t)n * 16 + t * 8 + 4] = r1;
        *(float4*)&out3[(size_t)n * 16 + t * 8] = r0;
        *(float4*)&out3[(size_t)n * 16 + t * 8 + 4] = r1;
        float mloc = acc[0];
        #pragma unroll
        for (int k = 1; k < 8; ++k) mloc = fmaxf(mloc, acc[k]);
        float m = fmaxf(mloc, __shfl_xor(mloc, 1));
        float sloc = 0.f;
        #pragma unroll
        for (int k = 0; k < 8; ++k) sloc += __expf(acc[k] - m);
        float ssum = sloc + __shfl_xor(sloc, 1);
        float ls = m + __logf(ssum);
        float4 w0 = make_float4(acc[0] - ls, acc[1] - ls, acc[2] - ls, acc[3] - ls);
        float4 w1 = make_float4(acc[4] - ls, acc[5] - ls, acc[6] - ls, acc[7] - ls);
        *(float4*)&out0[(size_t)n * 16 + t * 8] = w0;
        *(float4*)&out0[(size_t)n * 16 + t * 8 + 4] = w1;
    }
}

// ---------------- launch ----------------

extern "C" void kernel_launch(void* const* d_in, const int* in_sizes, int n_in,
                              void* d_out, int out_size, void* d_ws, size_t ws_size,
                              hipStream_t stream) {
    const float* x   = (const float*)d_in[0];
    const int*   ei  = (const int*)d_in[1];
    const float* ew  = (const float*)d_in[2];
    const float* W1  = (const float*)d_in[3];
    const float* b1  = (const float*)d_in[4];
    const float* W2  = (const float*)d_in[5];
    const float* b2  = (const float*)d_in[6];
    const float* W3  = (const float*)d_in[7];
    const float* b3  = (const float*)d_in[8];
    float* out = (float*)d_out;

    const int N = in_sizes[0] / N_FEAT;      // 100000
    const int E = in_sizes[2];               // 1600000
    const int NB = (N + (1 << NBW) - 1) >> NBW;   // 196

    size_t off = 0;
    auto alloc = [&](size_t bytes) {
        void* p = (char*)d_ws + off;
        off += (bytes + 255) & ~(size_t)255;
        return p;
    };
    float* dis     = (float*)alloc((size_t)N * 4);
    int*   cnt     = (int*)alloc((size_t)N * 4);
    int*   rowp    = (int*)alloc((size_t)N * 4);
    int*   bcur    = (int*)alloc(256 * 4);
    int2*  csr     = (int2*)alloc(((size_t)NB * CAP + 32) * 8);  // +32-entry pad (sentinel-filled)
    int2*  ebuf    = (int2*)alloc((size_t)NB * CAP * 8);
    u16*   hwB     = (u16*)alloc((size_t)N * 64 * 2);    // gemm1 out (layer-1 gather table)
    u16*   hwB2    = (u16*)alloc((size_t)N * 64 * 2);    // gemm2 out (layer-2 gather table)
    u16*   hw16    = (u16*)alloc((size_t)N * 16 * 2);    // gemm3 out (layer-3 gather table)
    uint4* Wp1     = (uint4*)alloc(512 * 16);            // B-fragment-packed weights
    uint4* Wp2     = (uint4*)alloc(512 * 16);
    uint4* Wp3     = (uint4*)alloc(128 * 16);

    const int TB = 256;

    int gblk = ((N + 15) / 16 + 3) / 4;      // gemm1: one 16-row tile per wave
    int PB   = (E + 2047) / 2048;            // partition blocks
    int fblk = (N + 31) / 32;                // fused agg+gemm blocks (32 nodes each)
    int ablk16 = (N * 2 + TB - 1) / TB;      // final agg: 2 lanes/node

    float* logits = out + (size_t)N * 16;
    float* logits2 = out + (size_t)2 * N * 16;

    // pack weights + zero cursors; partition + fused gemm1; bucket CSR
    pack_init<<<4, TB, 0, stream>>>(W1, W2, W3, Wp1, Wp2, Wp3, bcur);
    part_gemm<<<PB + gblk, TB, 0, stream>>>(ei, ew, bcur, ebuf, E, NB, PB, x, Wp1, hwB, N);
    bucket_csr<<<NB, TB, 0, stream>>>(ebuf, bcur, csr, rowp, cnt, dis, N);

    // layer 1 aggregate (LOADDIS) + layer-2 GEMM fused
    agg_gemm<64, true><<<fblk, TB, 0, stream>>>(hwB, rowp, cnt, csr, dis, b1, Wp2, hwB2, N);
    // layer 2 aggregate + layer-3 GEMM fused
    agg_gemm<16, false><<<fblk, TB, 0, stream>>>(hwB2, rowp, cnt, csr, dis, b2, Wp3, hw16, N);
    // layer 3 aggregate + log-softmax
    agg_final<<<ablk16, TB, 0, stream>>>(hw16, rowp, cnt, csr, dis, b3, out, logits, logits2, N);
}

// Round 21
// 161.930 us; speedup vs baseline: 2.7138x; 1.0114x over previous
//
#include <hip/hip_runtime.h>
#include <hip/hip_bf16.h>

#define N_FEAT 64
#define NBW 9                      // log2(nodes per bucket) = 512
#define SRC_BITS 23                // key = (dstLocal << 23) | src ; src < 2^23
#define CAP 9216                   // static bucket capacity (mean 8192 + >10 sigma)

typedef unsigned short u16;
typedef __attribute__((ext_vector_type(8))) short short8;   // 8 bf16 (4 VGPRs)
typedef __attribute__((ext_vector_type(4))) float f32x4;    // MFMA C/D

__device__ inline u16 f2bf(float f) {           // RNE f32 -> bf16
    unsigned u = __float_as_uint(f);
    u += 0x7fffu + ((u >> 16) & 1u);
    return (u16)(u >> 16);
}

// ---------------- pack W into MFMA B-fragment order + init cursors ----------

__device__ inline void packW(const float* __restrict__ W, uint4* __restrict__ Wpk,
                             int ncb, int wcols, int tid) {
    int nf = ncb * 2 * 64;
    for (int f = tid; f < nf; f += 256) {
        int cb = f >> 7;
        int s  = (f >> 6) & 1;
        int lane = f & 63;
        int kb = lane >> 4, c16 = lane & 15;
        union { uint4 q; u16 u[8]; } pk;
        #pragma unroll
        for (int i = 0; i < 8; ++i) {
            int k = s * 32 + kb * 8 + i;
            pk.u[i] = f2bf(W[k * wcols + cb * 16 + c16]);
        }
        Wpk[f] = pk.q;
    }
}

__global__ __launch_bounds__(256) void pack_init(const float* __restrict__ W1, const float* __restrict__ W2,
                                                 const float* __restrict__ W3,
                                                 uint4* Wp1, uint4* Wp2, uint4* Wp3, int* bcur) {
    if (blockIdx.x == 0)      packW(W1, Wp1, 4, 64, threadIdx.x);
    else if (blockIdx.x == 1) packW(W2, Wp2, 4, 64, threadIdx.x);
    else if (blockIdx.x == 2) packW(W3, Wp3, 1, 16, threadIdx.x);
    else                      bcur[threadIdx.x] = 0;
}

// ---------------- GEMM body via MFMA 16x16x32 bf16 (global A) ----------------

template<int OUTW, bool INBF, bool SCALE>
__device__ inline void gemm_body(const void* __restrict__ Av, const uint4* __restrict__ Wpk,
                                 const float* __restrict__ dis, u16* __restrict__ C, int N,
                                 int wid, int lane) {
    constexpr int NCB = OUTW / 16;
    int r0 = wid * 16;
    if (r0 >= N) return;
    int row16 = lane & 15, kb = lane >> 4;
    int r = min(r0 + row16, N - 1);

    short8 a0, a1;
    if (INBF) {
        const u16* arow = (const u16*)Av + (size_t)r * 64 + kb * 8;
        a0 = __builtin_bit_cast(short8, *(const uint4*)arow);
        a1 = __builtin_bit_cast(short8, *(const uint4*)(arow + 32));
    } else {
        const float* arow = (const float*)Av + (size_t)r * 64 + kb * 8;
        float4 f0 = *(const float4*)arow;
        float4 f1 = *(const float4*)(arow + 4);
        float4 f2 = *(const float4*)(arow + 32);
        float4 f3 = *(const float4*)(arow + 36);
        union { short8 v; u16 u[8]; } pa, pb;
        pa.u[0] = f2bf(f0.x); pa.u[1] = f2bf(f0.y); pa.u[2] = f2bf(f0.z); pa.u[3] = f2bf(f0.w);
        pa.u[4] = f2bf(f1.x); pa.u[5] = f2bf(f1.y); pa.u[6] = f2bf(f1.z); pa.u[7] = f2bf(f1.w);
        pb.u[0] = f2bf(f2.x); pb.u[1] = f2bf(f2.y); pb.u[2] = f2bf(f2.z); pb.u[3] = f2bf(f2.w);
        pb.u[4] = f2bf(f3.x); pb.u[5] = f2bf(f3.y); pb.u[6] = f2bf(f3.z); pb.u[7] = f2bf(f3.w);
        a0 = pa.v; a1 = pb.v;
    }

    f32x4 acc[NCB];
    #pragma unroll
    for (int cb = 0; cb < NCB; ++cb) {
        short8 b0 = __builtin_bit_cast(short8, Wpk[(cb * 2 + 0) * 64 + lane]);
        short8 b1 = __builtin_bit_cast(short8, Wpk[(cb * 2 + 1) * 64 + lane]);
        f32x4 z = {0.f, 0.f, 0.f, 0.f};
        z = __builtin_amdgcn_mfma_f32_16x16x32_bf16(a0, b0, z, 0, 0, 0);
        z = __builtin_amdgcn_mfma_f32_16x16x32_bf16(a1, b1, z, 0, 0, 0);
        acc[cb] = z;
    }

    int rbase = r0 + kb * 4;
    float dsc[4];
    #pragma unroll
    for (int j = 0; j < 4; ++j) dsc[j] = SCALE ? dis[min(rbase + j, N - 1)] : 1.0f;

    #pragma unroll
    for (int cb = 0; cb < NCB; ++cb) {
        int col = cb * 16 + row16;
        #pragma unroll
        for (int j = 0; j < 4; ++j) {
            int rr = rbase + j;
            if (rr < N) C[(size_t)rr * OUTW + col] = f2bf(SCALE ? acc[cb][j] * dsc[j] : acc[cb][j]);
        }
    }
}

// ---------------- partition (static buckets, EPT=32) + fused layer-1 GEMM ----
// Phase 1 reads only dst + ranks into LDS histogram (d[32]+r[32] regs).
// Phase 2 claims contiguous bucket runs (~42 entries = ~336B -> low write
// amplification) and reads src/ew (coalesced, exactly once) while scattering.
// blocks [PB,..): gemm1 = bf16(x @ W1), unscaled.

__global__ __launch_bounds__(256) void part_gemm(const int* __restrict__ ei, const float* __restrict__ ew,
                                                 int* bcur, int2* __restrict__ ebuf, int E, int NB, int PB,
                                                 const float* __restrict__ x, const uint4* __restrict__ Wp1,
                                                 u16* __restrict__ hwB, int N) {
    constexpr int EPT = 32;
    __shared__ int cnt[256];
    __shared__ int base[256];
    int tid = threadIdx.x;

    if ((int)blockIdx.x >= PB) {                 // ---- gemm1 path ----
        int wid = (int)(((blockIdx.x - PB) * blockDim.x + tid) >> 6);
        gemm_body<64, false, false>(x, Wp1, nullptr, hwB, N, wid, tid & 63);
        return;
    }

    cnt[tid] = 0;
    __syncthreads();
    int start = blockIdx.x * (256 * EPT);

    int d[EPT], r[EPT];
    #pragma unroll
    for (int i = 0; i < EPT; ++i) {
        int e = start + i * 256 + tid;
        if (e < E) {
            d[i] = ei[E + e];
            r[i] = atomicAdd(&cnt[d[i] >> NBW], 1);
        } else d[i] = -1;
    }
    __syncthreads();
    if (tid < NB && cnt[tid]) base[tid] = atomicAdd(&bcur[tid], cnt[tid]);
    __syncthreads();
    #pragma unroll
    for (int i = 0; i < EPT; ++i) {
        if (d[i] >= 0) {
            int e = start + i * 256 + tid;
            int s = ei[e];                       // src read once (coalesced)
            float w = ew[e];                     // ew read once (coalesced)
            int b = d[i] >> NBW;
            int dl = d[i] & ((1 << NBW) - 1);
            int gpos = base[b] + r[i];
            if (gpos < CAP) {
                int key = (dl << SRC_BITS) | s;
                ebuf[(size_t)b * CAP + gpos] = make_int2(key, __float_as_int(w));
            }
        }
    }
}

__global__ __launch_bounds__(256) void bucket_csr(const int2* __restrict__ ebuf, const int* __restrict__ bcur,
                                                  int2* __restrict__ csr, int* __restrict__ rowp,
                                                  int* __restrict__ cnt, float* __restrict__ dis, int N) {
    __shared__ int   h[512];
    __shared__ float ws[512];
    __shared__ int   off[512];
    __shared__ int   wsum[4];
    int b = blockIdx.x, tid = threadIdx.x;
    int nbase = b << NBW;
    int nn = min(512, N - nbase);
    int beg = b * CAP;
    int m = min(bcur[b], CAP);

    h[tid] = 0; h[tid + 256] = 0;
    ws[tid] = 0.f; ws[tid + 256] = 0.f;
    __syncthreads();

    for (int i = tid; i < m; i += 256) {
        int2 en = ebuf[beg + i];
        int dl = ((unsigned)en.x) >> SRC_BITS;
        atomicAdd(&h[dl], 1);
        atomicAdd(&ws[dl], __int_as_float(en.y));
    }
    __syncthreads();

    int v0 = h[2 * tid], v1 = h[2 * tid + 1];
    int v = v0 + v1;
    int lane = tid & 63, wv = tid >> 6;
    int incl = v;
    #pragma unroll
    for (int o = 1; o < 64; o <<= 1) { int t = __shfl_up(incl, o); if (lane >= o) incl += t; }
    if (lane == 63) wsum[wv] = incl;
    __syncthreads();
    int add = 0;
    #pragma unroll
    for (int i = 0; i < 4; ++i) if (i < wv) add += wsum[i];
    int excl = add + incl - v;
    off[2 * tid] = excl;
    off[2 * tid + 1] = excl + v0;
    __syncthreads();

    for (int l = tid; l < nn; l += 256) {
        rowp[nbase + l] = beg + off[l];
        cnt[nbase + l]  = h[l];
        dis[nbase + l]  = rsqrtf(1.0f + ws[l]);
    }
    __syncthreads();
    h[tid] = 0; h[tid + 256] = 0;
    __syncthreads();

    for (int i = tid; i < m; i += 256) {
        int2 en = ebuf[beg + i];
        unsigned k = (unsigned)en.x;
        int dl  = k >> SRC_BITS;
        int src = k & ((1 << SRC_BITS) - 1);
        int pos = atomicAdd(&h[dl], 1);
        csr[beg + off[dl] + pos] = make_int2(src, en.y);   // raw ew
    }

    // SENTINEL PAD: aggregation's double-buffered batch reads can overrun the
    // bucket's filled region by <16 entries. Zero-fill so prefetched loads see
    // a valid node index (0); weights are masked to zero anyway.
    if (tid < 16) csr[beg + m + tid] = make_int2(0, 0);
}

// ---------------- Fused aggregate + next-layer GEMM ----------------
// Block = 4 waves = 32 nodes, 8 lanes/node; csr batches double-buffered;
// after LDS staging all 4 waves run the next-layer GEMM (col-split for
// OUTW=64). LOADDIS: hw unscaled -> w_e = ew*dis[src], self = dd*hw_n.

template<int OUTW, bool LOADDIS>
__global__ __launch_bounds__(256) void agg_gemm(const u16* __restrict__ hw, const int* __restrict__ rowp,
                                                const int* __restrict__ cnt, const int2* __restrict__ csr,
                                                const float* __restrict__ dis, const float* __restrict__ bias,
                                                const uint4* __restrict__ Wpk, u16* __restrict__ C, int N) {
    constexpr int UN = 8;
    __shared__ u16 As[32 * 64];          // 4KB staged agg output (gemm input tile)

    int tid  = threadIdx.x;
    int w    = tid >> 6;
    int lane = tid & 63;
    int g = lane >> 3;                   // node slot in wave (8 lanes/node)
    int t = lane & 7;                    // 16B chunk in row
    int l = w * 8 + g;                   // local row 0..31
    int n = blockIdx.x * 32 + l;
    n = min(n, N - 1);

    float dd = dis[n];
    int beg = rowp[n];
    int c   = cnt[n];
    const char* hwb = (const char*)hw;
    unsigned toff = (unsigned)t * 16u;

    float acc[8];
    {   // self term
        uint4 raw = *(const uint4*)(hwb + (unsigned)n * 128u + toff);
        float sw = LOADDIS ? dd : 1.0f;
        unsigned uw[4] = {raw.x, raw.y, raw.z, raw.w};
        #pragma unroll
        for (int k = 0; k < 4; ++k) {
            acc[2 * k]     = sw * __uint_as_float(uw[k] << 16);
            acc[2 * k + 1] = sw * __uint_as_float(uw[k] & 0xffff0000u);
        }
    }

    // gather loop: csr batch double-buffered (overruns land on valid entries)
    int2 e[UN];
    #pragma unroll
    for (int i = 0; i < UN; ++i) e[i] = csr[beg + i];
    for (int j0 = 0; j0 < c; j0 += UN) {
        uint4 r[UN];
        #pragma unroll
        for (int i = 0; i < UN; ++i)
            r[i] = *(const uint4*)(hwb + (unsigned)e[i].x * 128u + toff);
        int2 en[UN];
        #pragma unroll
        for (int i = 0; i < UN; ++i) en[i] = csr[beg + j0 + UN + i];   // prefetch next
        float wgt[UN];
        #pragma unroll
        for (int i = 0; i < UN; ++i) {
            float wr = __int_as_float(e[i].y);
            if (LOADDIS) wr *= dis[e[i].x];
            wgt[i] = (j0 + i < c) ? wr : 0.0f;
        }
        #pragma unroll
        for (int i = 0; i < UN; ++i) {
            unsigned u[4] = {r[i].x, r[i].y, r[i].z, r[i].w};
            #pragma unroll
            for (int k = 0; k < 4; ++k) {
                acc[2 * k]     = fmaf(wgt[i], __uint_as_float(u[k] << 16), acc[2 * k]);
                acc[2 * k + 1] = fmaf(wgt[i], __uint_as_float(u[k] & 0xffff0000u), acc[2 * k + 1]);
            }
        }
        #pragma unroll
        for (int i = 0; i < UN; ++i) e[i] = en[i];
    }

    {   // bias + relu + stage to LDS (dead rows stage garbage; masked at C store)
        float4 b0 = *(const float4*)&bias[t * 8];
        float4 b1 = *(const float4*)&bias[t * 8 + 4];
        float bb[8] = {b0.x, b0.y, b0.z, b0.w, b1.x, b1.y, b1.z, b1.w};
        #pragma unroll
        for (int k = 0; k < 8; ++k) acc[k] = fmaxf(fmaf(dd, acc[k], bb[k]), 0.0f);
        uint4 pk;
        pk.x = (unsigned)f2bf(acc[0]) | ((unsigned)f2bf(acc[1]) << 16);
        pk.y = (unsigned)f2bf(acc[2]) | ((unsigned)f2bf(acc[3]) << 16);
        pk.z = (unsigned)f2bf(acc[4]) | ((unsigned)f2bf(acc[5]) << 16);
        pk.w = (unsigned)f2bf(acc[6]) | ((unsigned)f2bf(acc[7]) << 16);
        *(uint4*)&As[l * 64 + t * 8] = pk;
    }
    __syncthreads();

    // ---- next-layer GEMM on the 32 staged rows ----
    if (OUTW == 64) {
        int tile = w >> 1, half = w & 1;
        int r0 = blockIdx.x * 32 + tile * 16;
        if (r0 < N) {
            int row16 = lane & 15, kb = lane >> 4;
            const u16* arow = &As[(tile * 16 + row16) * 64 + kb * 8];
            short8 a0 = __builtin_bit_cast(short8, *(const uint4*)arow);
            short8 a1 = __builtin_bit_cast(short8, *(const uint4*)(arow + 32));

            f32x4 za[2];
            #pragma unroll
            for (int c2 = 0; c2 < 2; ++c2) {
                int cb = half * 2 + c2;
                short8 b0 = __builtin_bit_cast(short8, Wpk[(cb * 2 + 0) * 64 + lane]);
                short8 b1 = __builtin_bit_cast(short8, Wpk[(cb * 2 + 1) * 64 + lane]);
                f32x4 z = {0.f, 0.f, 0.f, 0.f};
                z = __builtin_amdgcn_mfma_f32_16x16x32_bf16(a0, b0, z, 0, 0, 0);
                z = __builtin_amdgcn_mfma_f32_16x16x32_bf16(a1, b1, z, 0, 0, 0);
                za[c2] = z;
            }

            int rbase = r0 + kb * 4;
            float dsc[4];
            #pragma unroll
            for (int j = 0; j < 4; ++j) dsc[j] = dis[min(rbase + j, N - 1)];
            #pragma unroll
            for (int c2 = 0; c2 < 2; ++c2) {
                int col = (half * 2 + c2) * 16 + row16;
                #pragma unroll
                for (int j = 0; j < 4; ++j) {
                    int rr = rbase + j;
                    if (rr < N) C[(size_t)rr * 64 + col] = f2bf(za[c2][j] * dsc[j]);
                }
            }
        }
    } else {
        if (w < 2) {
            int r0 = blockIdx.x * 32 + w * 16;
            if (r0 < N) {
                int row16 = lane & 15, kb = lane >> 4;
                const u16* arow = &As[(w * 16 + row16) * 64 + kb * 8];
                short8 a0 = __builtin_bit_cast(short8, *(const uint4*)arow);
                short8 a1 = __builtin_bit_cast(short8, *(const uint4*)(arow + 32));
                short8 b0 = __builtin_bit_cast(short8, Wpk[0 * 64 + lane]);
                short8 b1 = __builtin_bit_cast(short8, Wpk[1 * 64 + lane]);
                f32x4 z = {0.f, 0.f, 0.f, 0.f};
                z = __builtin_amdgcn_mfma_f32_16x16x32_bf16(a0, b0, z, 0, 0, 0);
                z = __builtin_amdgcn_mfma_f32_16x16x32_bf16(a1, b1, z, 0, 0, 0);

                int rbase = r0 + kb * 4;
                float dsc[4];
                #pragma unroll
                for (int j = 0; j < 4; ++j) dsc[j] = dis[min(rbase + j, N - 1)];
                int col = row16;
                #pragma unroll
                for (int j = 0; j < 4; ++j) {
                    int rr = rbase + j;
                    if (rr < N) C[(size_t)rr * 16 + col] = f2bf(z[j] * dsc[j]);
                }
            }
        }
    }
}

// ---------------- Final aggregation (F=16) + fused log-softmax ----------------

__global__ __launch_bounds__(256) void agg_final(const u16* __restrict__ hw, const int* __restrict__ rowp,
                                                 const int* __restrict__ cnt, const int2* __restrict__ csr,
                                                 const float* __restrict__ dis, const float* __restrict__ bias,
                                                 float* __restrict__ out0, float* __restrict__ out2,
                                                 float* __restrict__ out3, int N) {
    constexpr int UN = 8;
    int wv   = (int)((blockIdx.x * blockDim.x + threadIdx.x) >> 6);
    int lane = threadIdx.x & 63;
    int g = lane >> 1;                   // 32 nodes per wave, 2 lanes/node
    int t = lane & 1;
    int n = wv * 32 + g;
    bool alive = (n < N);
    n = min(n, N - 1);

    float dd = dis[n];
    int beg = rowp[n];
    int c   = cnt[n];
    const char* hwb = (const char*)hw;
    unsigned toff = (unsigned)t * 16u;

    float acc[8];
    {
        uint4 raw = *(const uint4*)(hwb + (unsigned)n * 32u + toff);
        unsigned uw[4] = {raw.x, raw.y, raw.z, raw.w};
        #pragma unroll
        for (int k = 0; k < 4; ++k) {
            acc[2 * k]     = __uint_as_float(uw[k] << 16);
            acc[2 * k + 1] = __uint_as_float(uw[k] & 0xffff0000u);
        }
    }

    int2 e[UN];
    #pragma unroll
    for (int i = 0; i < UN; ++i) e[i] = csr[beg + i];
    for (int j0 = 0; j0 < c; j0 += UN) {
        uint4 r[UN];
        #pragma unroll
        for (int i = 0; i < UN; ++i)
            r[i] = *(const uint4*)(hwb + (unsigned)e[i].x * 32u + toff);
        int2 en[UN];
        #pragma unroll
        for (int i = 0; i < UN; ++i) en[i] = csr[beg + j0 + UN + i];
        float wgt[UN];
        #pragma unroll
        for (int i = 0; i < UN; ++i) wgt[i] = (j0 + i < c) ? __int_as_float(e[i].y) : 0.0f;
        #pragma unroll
        for (int i = 0; i < UN; ++i) {
            unsigned u[4] = {r[i].x, r[i].y, r[i].z, r[i].w};
            #pragma unroll
            for (int k = 0; k < 4; ++k) {
                acc[2 * k]     = fmaf(wgt[i], __uint_as_float(u[k] << 16), acc[2 * k]);
                acc[2 * k + 1] = fmaf(wgt[i], __uint_as_float(u[k] & 0xffff0000u), acc[2 * k + 1]);
            }
        }
        #pragma unroll
        for (int i = 0; i < UN; ++i) e[i] = en[i];
    }

    if (alive) {
        float4 b0 = *(const float4*)&bias[t * 8];
        float4 b1 = *(const float4*)&bias[t * 8 + 4];
        float bb[8] = {b0.x, b0.y, b0.z, b0.w, b1.x, b1.y, b1.z, b1.w};
        #pragma unroll
        for (int k = 0; k < 8; ++k) acc[k] = fmaf(dd, acc[k], bb[k]);

        float4 r0 = make_float4(acc[0], acc[1], acc[2], acc[3]);
        float4 r1 = make_float4(acc[4], acc[5], acc[6], acc[7]);
        *(float4*)&out2[(size_t)n * 16 + t * 8] = r0;
        *(float4*)&out2[(size_t)n * 16 + t * 8 + 4] = r1;
        *(float4*)&out3[(size_t)n * 16 + t * 8] = r0;
        *(float4*)&out3[(size_t)n * 16 + t * 8 + 4] = r1;
        float mloc = acc[0];
        #pragma unroll
        for (int k = 1; k < 8; ++k) mloc = fmaxf(mloc, acc[k]);
        float m = fmaxf(mloc, __shfl_xor(mloc, 1));
        float sloc = 0.f;
        #pragma unroll
        for (int k = 0; k < 8; ++k) sloc += __expf(acc[k] - m);
        float ssum = sloc + __shfl_xor(sloc, 1);
        float ls = m + __logf(ssum);
        float4 w0 = make_float4(acc[0] - ls, acc[1] - ls, acc[2] - ls, acc[3] - ls);
        float4 w1 = make_float4(acc[4] - ls, acc[5] - ls, acc[6] - ls, acc[7] - ls);
        *(float4*)&out0[(size_t)n * 16 + t * 8] = w0;
        *(float4*)&out0[(size_t)n * 16 + t * 8 + 4] = w1;
    }
}

// ---------------- launch ----------------

extern "C" void kernel_launch(void* const* d_in, const int* in_sizes, int n_in,
                              void* d_out, int out_size, void* d_ws, size_t ws_size,
                              hipStream_t stream) {
    const float* x   = (const float*)d_in[0];
    const int*   ei  = (const int*)d_in[1];
    const float* ew  = (const float*)d_in[2];
    const float* W1  = (const float*)d_in[3];
    const float* b1  = (const float*)d_in[4];
    const float* W2  = (const float*)d_in[5];
    const float* b2  = (const float*)d_in[6];
    const float* W3  = (const float*)d_in[7];
    const float* b3  = (const float*)d_in[8];
    float* out = (float*)d_out;

    const int N = in_sizes[0] / N_FEAT;      // 100000
    const int E = in_sizes[2];               // 1600000
    const int NB = (N + (1 << NBW) - 1) >> NBW;   // 196

    size_t off = 0;
    auto alloc = [&](size_t bytes) {
        void* p = (char*)d_ws + off;
        off += (bytes + 255) & ~(size_t)255;
        return p;
    };
    float* dis     = (float*)alloc((size_t)N * 4);
    int*   cnt     = (int*)alloc((size_t)N * 4);
    int*   rowp    = (int*)alloc((size_t)N * 4);
    int*   bcur    = (int*)alloc(256 * 4);
    int2*  csr     = (int2*)alloc(((size_t)NB * CAP + 32) * 8);  // +32-entry pad (sentinel-filled)
    int2*  ebuf    = (int2*)alloc((size_t)NB * CAP * 8);
    u16*   hwB     = (u16*)alloc((size_t)N * 64 * 2);    // gemm1 out (layer-1 gather table)
    u16*   hwB2    = (u16*)alloc((size_t)N * 64 * 2);    // gemm2 out (layer-2 gather table)
    u16*   hw16    = (u16*)alloc((size_t)N * 16 * 2);    // gemm3 out (layer-3 gather table)
    uint4* Wp1     = (uint4*)alloc(512 * 16);            // B-fragment-packed weights
    uint4* Wp2     = (uint4*)alloc(512 * 16);
    uint4* Wp3     = (uint4*)alloc(128 * 16);

    const int TB = 256;

    int gblk = ((N + 15) / 16 + 3) / 4;      // gemm1: one 16-row tile per wave
    int PB   = (E + 256 * 32 - 1) / (256 * 32);   // partition blocks (EPT=32)
    int fblk = (N + 31) / 32;                // fused agg+gemm blocks (32 nodes each)
    int ablk16 = (N * 2 + TB - 1) / TB;      // final agg: 2 lanes/node

    float* logits = out + (size_t)N * 16;
    float* logits2 = out + (size_t)2 * N * 16;

    // pack weights + zero cursors; partition + fused gemm1; bucket CSR
    pack_init<<<4, TB, 0, stream>>>(W1, W2, W3, Wp1, Wp2, Wp3, bcur);
    part_gemm<<<PB + gblk, TB, 0, stream>>>(ei, ew, bcur, ebuf, E, NB, PB, x, Wp1, hwB, N);
    bucket_csr<<<NB, TB, 0, stream>>>(ebuf, bcur, csr, rowp, cnt, dis, N);

    // layer 1 aggregate (LOADDIS) + layer-2 GEMM fused
    agg_gemm<64, true><<<fblk, TB, 0, stream>>>(hwB, rowp, cnt, csr, dis, b1, Wp2, hwB2, N);
    // layer 2 aggregate + layer-3 GEMM fused
    agg_gemm<16, false><<<fblk, TB, 0, stream>>>(hwB2, rowp, cnt, csr, dis, b2, Wp3, hw16, N);
    // layer 3 aggregate + log-softmax
    agg_final<<<ablk16, TB, 0, stream>>>(hw16, rowp, cnt, csr, dis, b3, out, logits, logits2, N);
}

// Round 22
// 158.576 us; speedup vs baseline: 2.7712x; 1.0212x over previous
//
#include <hip/hip_runtime.h>
#include <hip/hip_bf16.h>

#define N_FEAT 64
#define NBW 9                      // log2(nodes per bucket) = 512
#define SRC_BITS 23                // key = (dstLocal << 23) | src ; src < 2^23
#define CAP 9216                   // static bucket capacity (mean 8192 + >10 sigma)

typedef unsigned short u16;
typedef __attribute__((ext_vector_type(8))) short short8;   // 8 bf16 (4 VGPRs)
typedef __attribute__((ext_vector_type(4))) float f32x4;    // MFMA C/D

__device__ inline u16 f2bf(float f) {           // RNE f32 -> bf16
    unsigned u = __float_as_uint(f);
    u += 0x7fffu + ((u >> 16) & 1u);
    return (u16)(u >> 16);
}

// ---------------- pack W into MFMA B-fragment order + init cursors ----------

__device__ inline void packW(const float* __restrict__ W, uint4* __restrict__ Wpk,
                             int ncb, int wcols, int tid) {
    int nf = ncb * 2 * 64;
    for (int f = tid; f < nf; f += 256) {
        int cb = f >> 7;
        int s  = (f >> 6) & 1;
        int lane = f & 63;
        int kb = lane >> 4, c16 = lane & 15;
        union { uint4 q; u16 u[8]; } pk;
        #pragma unroll
        for (int i = 0; i < 8; ++i) {
            int k = s * 32 + kb * 8 + i;
            pk.u[i] = f2bf(W[k * wcols + cb * 16 + c16]);
        }
        Wpk[f] = pk.q;
    }
}

__global__ __launch_bounds__(256) void pack_init(const float* __restrict__ W1, const float* __restrict__ W2,
                                                 const float* __restrict__ W3,
                                                 uint4* Wp1, uint4* Wp2, uint4* Wp3, int* bcur) {
    if (blockIdx.x == 0)      packW(W1, Wp1, 4, 64, threadIdx.x);
    else if (blockIdx.x == 1) packW(W2, Wp2, 4, 64, threadIdx.x);
    else if (blockIdx.x == 2) packW(W3, Wp3, 1, 16, threadIdx.x);
    else {                                   // zero strided cursors (256 x 16 ints)
        for (int i = threadIdx.x; i < 256 * 16; i += 256) bcur[i] = 0;
    }
}

// ---------------- GEMM body via MFMA 16x16x32 bf16 (global A) ----------------

template<int OUTW, bool INBF, bool SCALE>
__device__ inline void gemm_body(const void* __restrict__ Av, const uint4* __restrict__ Wpk,
                                 const float* __restrict__ dis, u16* __restrict__ C, int N,
                                 int wid, int lane) {
    constexpr int NCB = OUTW / 16;
    int r0 = wid * 16;
    if (r0 >= N) return;
    int row16 = lane & 15, kb = lane >> 4;
    int r = min(r0 + row16, N - 1);

    short8 a0, a1;
    if (INBF) {
        const u16* arow = (const u16*)Av + (size_t)r * 64 + kb * 8;
        a0 = __builtin_bit_cast(short8, *(const uint4*)arow);
        a1 = __builtin_bit_cast(short8, *(const uint4*)(arow + 32));
    } else {
        const float* arow = (const float*)Av + (size_t)r * 64 + kb * 8;
        float4 f0 = *(const float4*)arow;
        float4 f1 = *(const float4*)(arow + 4);
        float4 f2 = *(const float4*)(arow + 32);
        float4 f3 = *(const float4*)(arow + 36);
        union { short8 v; u16 u[8]; } pa, pb;
        pa.u[0] = f2bf(f0.x); pa.u[1] = f2bf(f0.y); pa.u[2] = f2bf(f0.z); pa.u[3] = f2bf(f0.w);
        pa.u[4] = f2bf(f1.x); pa.u[5] = f2bf(f1.y); pa.u[6] = f2bf(f1.z); pa.u[7] = f2bf(f1.w);
        pb.u[0] = f2bf(f2.x); pb.u[1] = f2bf(f2.y); pb.u[2] = f2bf(f2.z); pb.u[3] = f2bf(f2.w);
        pb.u[4] = f2bf(f3.x); pb.u[5] = f2bf(f3.y); pb.u[6] = f2bf(f3.z); pb.u[7] = f2bf(f3.w);
        a0 = pa.v; a1 = pb.v;
    }

    f32x4 acc[NCB];
    #pragma unroll
    for (int cb = 0; cb < NCB; ++cb) {
        short8 b0 = __builtin_bit_cast(short8, Wpk[(cb * 2 + 0) * 64 + lane]);
        short8 b1 = __builtin_bit_cast(short8, Wpk[(cb * 2 + 1) * 64 + lane]);
        f32x4 z = {0.f, 0.f, 0.f, 0.f};
        z = __builtin_amdgcn_mfma_f32_16x16x32_bf16(a0, b0, z, 0, 0, 0);
        z = __builtin_amdgcn_mfma_f32_16x16x32_bf16(a1, b1, z, 0, 0, 0);
        acc[cb] = z;
    }

    int rbase = r0 + kb * 4;
    float dsc[4];
    #pragma unroll
    for (int j = 0; j < 4; ++j) dsc[j] = SCALE ? dis[min(rbase + j, N - 1)] : 1.0f;

    #pragma unroll
    for (int cb = 0; cb < NCB; ++cb) {
        int col = cb * 16 + row16;
        #pragma unroll
        for (int j = 0; j < 4; ++j) {
            int rr = rbase + j;
            if (rr < N) C[(size_t)rr * OUTW + col] = f2bf(SCALE ? acc[cb][j] * dsc[j] : acc[cb][j]);
        }
    }
}

// ---------------- partition (static buckets, EPT=16) + fused layer-1 GEMM ----
// Phase 1: dst + LDS-histogram rank (d[16]+r[16] regs). Claim contiguous
// bucket runs via STRIDED global cursors (one per 64B line -> parallel
// memory-side atomic service). Phase 2: re-read src/ew coalesced, scatter.
// blocks [PB,..): gemm1 = bf16(x @ W1), unscaled.

__global__ __launch_bounds__(256) void part_gemm(const int* __restrict__ ei, const float* __restrict__ ew,
                                                 int* bcur, int2* __restrict__ ebuf, int E, int NB, int PB,
                                                 const float* __restrict__ x, const uint4* __restrict__ Wp1,
                                                 u16* __restrict__ hwB, int N) {
    constexpr int EPT = 16;
    __shared__ int cnt[256];
    __shared__ int base[256];
    int tid = threadIdx.x;

    if ((int)blockIdx.x >= PB) {                 // ---- gemm1 path ----
        int wid = (int)(((blockIdx.x - PB) * blockDim.x + tid) >> 6);
        gemm_body<64, false, false>(x, Wp1, nullptr, hwB, N, wid, tid & 63);
        return;
    }

    cnt[tid] = 0;
    __syncthreads();
    int start = blockIdx.x * (256 * EPT);

    int d[EPT], r[EPT];
    #pragma unroll
    for (int i = 0; i < EPT; ++i) {
        int e = start + i * 256 + tid;
        if (e < E) {
            d[i] = ei[E + e];
            r[i] = atomicAdd(&cnt[d[i] >> NBW], 1);
        } else d[i] = -1;
    }
    __syncthreads();
    if (tid < NB && cnt[tid]) base[tid] = atomicAdd(&bcur[tid << 4], cnt[tid]);  // strided cursor
    __syncthreads();
    #pragma unroll
    for (int i = 0; i < EPT; ++i) {
        if (d[i] >= 0) {
            int e = start + i * 256 + tid;
            int s = ei[e];                       // src read once (coalesced)
            float w = ew[e];                     // ew read once (coalesced)
            int b = d[i] >> NBW;
            int dl = d[i] & ((1 << NBW) - 1);
            int gpos = base[b] + r[i];
            if (gpos < CAP) {
                int key = (dl << SRC_BITS) | s;
                ebuf[(size_t)b * CAP + gpos] = make_int2(key, __float_as_int(w));
            }
        }
    }
}

__global__ __launch_bounds__(256) void bucket_csr(const int2* __restrict__ ebuf, const int* __restrict__ bcur,
                                                  int2* __restrict__ csr, int* __restrict__ rowp,
                                                  int* __restrict__ cnt, float* __restrict__ dis, int N) {
    __shared__ int   h[512];
    __shared__ float ws[512];
    __shared__ int   off[512];
    __shared__ int   wsum[4];
    int b = blockIdx.x, tid = threadIdx.x;
    int nbase = b << NBW;
    int nn = min(512, N - nbase);
    int beg = b * CAP;
    int m = min(bcur[b << 4], CAP);              // strided cursor

    h[tid] = 0; h[tid + 256] = 0;
    ws[tid] = 0.f; ws[tid + 256] = 0.f;
    __syncthreads();

    for (int i = tid; i < m; i += 256) {
        int2 en = ebuf[beg + i];
        int dl = ((unsigned)en.x) >> SRC_BITS;
        atomicAdd(&h[dl], 1);
        atomicAdd(&ws[dl], __int_as_float(en.y));
    }
    __syncthreads();

    int v0 = h[2 * tid], v1 = h[2 * tid + 1];
    int v = v0 + v1;
    int lane = tid & 63, wv = tid >> 6;
    int incl = v;
    #pragma unroll
    for (int o = 1; o < 64; o <<= 1) { int t = __shfl_up(incl, o); if (lane >= o) incl += t; }
    if (lane == 63) wsum[wv] = incl;
    __syncthreads();
    int add = 0;
    #pragma unroll
    for (int i = 0; i < 4; ++i) if (i < wv) add += wsum[i];
    int excl = add + incl - v;
    off[2 * tid] = excl;
    off[2 * tid + 1] = excl + v0;
    __syncthreads();

    for (int l = tid; l < nn; l += 256) {
        rowp[nbase + l] = beg + off[l];
        cnt[nbase + l]  = h[l];
        dis[nbase + l]  = rsqrtf(1.0f + ws[l]);
    }
    __syncthreads();
    h[tid] = 0; h[tid + 256] = 0;
    __syncthreads();

    for (int i = tid; i < m; i += 256) {
        int2 en = ebuf[beg + i];
        unsigned k = (unsigned)en.x;
        int dl  = k >> SRC_BITS;
        int src = k & ((1 << SRC_BITS) - 1);
        int pos = atomicAdd(&h[dl], 1);
        csr[beg + off[dl] + pos] = make_int2(src, en.y);   // raw ew
    }

    // SENTINEL PAD: aggregation's double-buffered batch reads can overrun the
    // bucket's filled region by <16 entries. Zero-fill so prefetched loads see
    // a valid node index (0); weights are masked to zero anyway.
    if (tid < 16) csr[beg + m + tid] = make_int2(0, 0);
}

// ---------------- Fused aggregate + next-layer GEMM ----------------
// Block = 4 waves = 32 nodes, 8 lanes/node; csr batches double-buffered;
// after LDS staging all 4 waves run the next-layer GEMM (col-split for
// OUTW=64). LOADDIS: hw unscaled -> w_e = ew*dis[src], self = dd*hw_n.

template<int OUTW, bool LOADDIS>
__global__ __launch_bounds__(256) void agg_gemm(const u16* __restrict__ hw, const int* __restrict__ rowp,
                                                const int* __restrict__ cnt, const int2* __restrict__ csr,
                                                const float* __restrict__ dis, const float* __restrict__ bias,
                                                const uint4* __restrict__ Wpk, u16* __restrict__ C, int N) {
    constexpr int UN = 8;
    __shared__ u16 As[32 * 64];          // 4KB staged agg output (gemm input tile)

    int tid  = threadIdx.x;
    int w    = tid >> 6;
    int lane = tid & 63;
    int g = lane >> 3;                   // node slot in wave (8 lanes/node)
    int t = lane & 7;                    // 16B chunk in row
    int l = w * 8 + g;                   // local row 0..31
    int n = blockIdx.x * 32 + l;
    n = min(n, N - 1);

    float dd = dis[n];
    int beg = rowp[n];
    int c   = cnt[n];
    const char* hwb = (const char*)hw;
    unsigned toff = (unsigned)t * 16u;

    float acc[8];
    {   // self term
        uint4 raw = *(const uint4*)(hwb + (unsigned)n * 128u + toff);
        float sw = LOADDIS ? dd : 1.0f;
        unsigned uw[4] = {raw.x, raw.y, raw.z, raw.w};
        #pragma unroll
        for (int k = 0; k < 4; ++k) {
            acc[2 * k]     = sw * __uint_as_float(uw[k] << 16);
            acc[2 * k + 1] = sw * __uint_as_float(uw[k] & 0xffff0000u);
        }
    }

    // gather loop: csr batch double-buffered (overruns land on valid entries)
    int2 e[UN];
    #pragma unroll
    for (int i = 0; i < UN; ++i) e[i] = csr[beg + i];
    for (int j0 = 0; j0 < c; j0 += UN) {
        uint4 r[UN];
        #pragma unroll
        for (int i = 0; i < UN; ++i)
            r[i] = *(const uint4*)(hwb + (unsigned)e[i].x * 128u + toff);
        int2 en[UN];
        #pragma unroll
        for (int i = 0; i < UN; ++i) en[i] = csr[beg + j0 + UN + i];   // prefetch next
        float wgt[UN];
        #pragma unroll
        for (int i = 0; i < UN; ++i) {
            float wr = __int_as_float(e[i].y);
            if (LOADDIS) wr *= dis[e[i].x];
            wgt[i] = (j0 + i < c) ? wr : 0.0f;
        }
        #pragma unroll
        for (int i = 0; i < UN; ++i) {
            unsigned u[4] = {r[i].x, r[i].y, r[i].z, r[i].w};
            #pragma unroll
            for (int k = 0; k < 4; ++k) {
                acc[2 * k]     = fmaf(wgt[i], __uint_as_float(u[k] << 16), acc[2 * k]);
                acc[2 * k + 1] = fmaf(wgt[i], __uint_as_float(u[k] & 0xffff0000u), acc[2 * k + 1]);
            }
        }
        #pragma unroll
        for (int i = 0; i < UN; ++i) e[i] = en[i];
    }

    {   // bias + relu + stage to LDS (dead rows stage garbage; masked at C store)
        float4 b0 = *(const float4*)&bias[t * 8];
        float4 b1 = *(const float4*)&bias[t * 8 + 4];
        float bb[8] = {b0.x, b0.y, b0.z, b0.w, b1.x, b1.y, b1.z, b1.w};
        #pragma unroll
        for (int k = 0; k < 8; ++k) acc[k] = fmaxf(fmaf(dd, acc[k], bb[k]), 0.0f);
        uint4 pk;
        pk.x = (unsigned)f2bf(acc[0]) | ((unsigned)f2bf(acc[1]) << 16);
        pk.y = (unsigned)f2bf(acc[2]) | ((unsigned)f2bf(acc[3]) << 16);
        pk.z = (unsigned)f2bf(acc[4]) | ((unsigned)f2bf(acc[5]) << 16);
        pk.w = (unsigned)f2bf(acc[6]) | ((unsigned)f2bf(acc[7]) << 16);
        *(uint4*)&As[l * 64 + t * 8] = pk;
    }
    __syncthreads();

    // ---- next-layer GEMM on the 32 staged rows ----
    if (OUTW == 64) {
        int tile = w >> 1, half = w & 1;
        int r0 = blockIdx.x * 32 + tile * 16;
        if (r0 < N) {
            int row16 = lane & 15, kb = lane >> 4;
            const u16* arow = &As[(tile * 16 + row16) * 64 + kb * 8];
            short8 a0 = __builtin_bit_cast(short8, *(const uint4*)arow);
            short8 a1 = __builtin_bit_cast(short8, *(const uint4*)(arow + 32));

            f32x4 za[2];
            #pragma unroll
            for (int c2 = 0; c2 < 2; ++c2) {
                int cb = half * 2 + c2;
                short8 b0 = __builtin_bit_cast(short8, Wpk[(cb * 2 + 0) * 64 + lane]);
                short8 b1 = __builtin_bit_cast(short8, Wpk[(cb * 2 + 1) * 64 + lane]);
                f32x4 z = {0.f, 0.f, 0.f, 0.f};
                z = __builtin_amdgcn_mfma_f32_16x16x32_bf16(a0, b0, z, 0, 0, 0);
                z = __builtin_amdgcn_mfma_f32_16x16x32_bf16(a1, b1, z, 0, 0, 0);
                za[c2] = z;
            }

            int rbase = r0 + kb * 4;
            float dsc[4];
            #pragma unroll
            for (int j = 0; j < 4; ++j) dsc[j] = dis[min(rbase + j, N - 1)];
            #pragma unroll
            for (int c2 = 0; c2 < 2; ++c2) {
                int col = (half * 2 + c2) * 16 + row16;
                #pragma unroll
                for (int j = 0; j < 4; ++j) {
                    int rr = rbase + j;
                    if (rr < N) C[(size_t)rr * 64 + col] = f2bf(za[c2][j] * dsc[j]);
                }
            }
        }
    } else {
        if (w < 2) {
            int r0 = blockIdx.x * 32 + w * 16;
            if (r0 < N) {
                int row16 = lane & 15, kb = lane >> 4;
                const u16* arow = &As[(w * 16 + row16) * 64 + kb * 8];
                short8 a0 = __builtin_bit_cast(short8, *(const uint4*)arow);
                short8 a1 = __builtin_bit_cast(short8, *(const uint4*)(arow + 32));
                short8 b0 = __builtin_bit_cast(short8, Wpk[0 * 64 + lane]);
                short8 b1 = __builtin_bit_cast(short8, Wpk[1 * 64 + lane]);
                f32x4 z = {0.f, 0.f, 0.f, 0.f};
                z = __builtin_amdgcn_mfma_f32_16x16x32_bf16(a0, b0, z, 0, 0, 0);
                z = __builtin_amdgcn_mfma_f32_16x16x32_bf16(a1, b1, z, 0, 0, 0);

                int rbase = r0 + kb * 4;
                float dsc[4];
                #pragma unroll
                for (int j = 0; j < 4; ++j) dsc[j] = dis[min(rbase + j, N - 1)];
                int col = row16;
                #pragma unroll
                for (int j = 0; j < 4; ++j) {
                    int rr = rbase + j;
                    if (rr < N) C[(size_t)rr * 16 + col] = f2bf(z[j] * dsc[j]);
                }
            }
        }
    }
}

// ---------------- Final aggregation (F=16) + fused log-softmax ----------------

__global__ __launch_bounds__(256) void agg_final(const u16* __restrict__ hw, const int* __restrict__ rowp,
                                                 const int* __restrict__ cnt, const int2* __restrict__ csr,
                                                 const float* __restrict__ dis, const float* __restrict__ bias,
                                                 float* __restrict__ out0, float* __restrict__ out2,
                                                 float* __restrict__ out3, int N) {
    constexpr int UN = 8;
    int wv   = (int)((blockIdx.x * blockDim.x + threadIdx.x) >> 6);
    int lane = threadIdx.x & 63;
    int g = lane >> 1;                   // 32 nodes per wave, 2 lanes/node
    int t = lane & 1;
    int n = wv * 32 + g;
    bool alive = (n < N);
    n = min(n, N - 1);

    float dd = dis[n];
    int beg = rowp[n];
    int c   = cnt[n];
    const char* hwb = (const char*)hw;
    unsigned toff = (unsigned)t * 16u;

    float acc[8];
    {
        uint4 raw = *(const uint4*)(hwb + (unsigned)n * 32u + toff);
        unsigned uw[4] = {raw.x, raw.y, raw.z, raw.w};
        #pragma unroll
        for (int k = 0; k < 4; ++k) {
            acc[2 * k]     = __uint_as_float(uw[k] << 16);
            acc[2 * k + 1] = __uint_as_float(uw[k] & 0xffff0000u);
        }
    }

    int2 e[UN];
    #pragma unroll
    for (int i = 0; i < UN; ++i) e[i] = csr[beg + i];
    for (int j0 = 0; j0 < c; j0 += UN) {
        uint4 r[UN];
        #pragma unroll
        for (int i = 0; i < UN; ++i)
            r[i] = *(const uint4*)(hwb + (unsigned)e[i].x * 32u + toff);
        int2 en[UN];
        #pragma unroll
        for (int i = 0; i < UN; ++i) en[i] = csr[beg + j0 + UN + i];
        float wgt[UN];
        #pragma unroll
        for (int i = 0; i < UN; ++i) wgt[i] = (j0 + i < c) ? __int_as_float(e[i].y) : 0.0f;
        #pragma unroll
        for (int i = 0; i < UN; ++i) {
            unsigned u[4] = {r[i].x, r[i].y, r[i].z, r[i].w};
            #pragma unroll
            for (int k = 0; k < 4; ++k) {
                acc[2 * k]     = fmaf(wgt[i], __uint_as_float(u[k] << 16), acc[2 * k]);
                acc[2 * k + 1] = fmaf(wgt[i], __uint_as_float(u[k] & 0xffff0000u), acc[2 * k + 1]);
            }
        }
        #pragma unroll
        for (int i = 0; i < UN; ++i) e[i] = en[i];
    }

    if (alive) {
        float4 b0 = *(const float4*)&bias[t * 8];
        float4 b1 = *(const float4*)&bias[t * 8 + 4];
        float bb[8] = {b0.x, b0.y, b0.z, b0.w, b1.x, b1.y, b1.z, b1.w};
        #pragma unroll
        for (int k = 0; k < 8; ++k) acc[k] = fmaf(dd, acc[k], bb[k]);

        float4 r0 = make_float4(acc[0], acc[1], acc[2], acc[3]);
        float4 r1 = make_float4(acc[4], acc[5], acc[6], acc[7]);
        *(float4*)&out2[(size_t)n * 16 + t * 8] = r0;
        *(float4*)&out2[(size_t)n * 16 + t * 8 + 4] = r1;
        *(float4*)&out3[(size_t)n * 16 + t * 8] = r0;
        *(float4*)&out3[(size_t)n * 16 + t * 8 + 4] = r1;
        float mloc = acc[0];
        #pragma unroll
        for (int k = 1; k < 8; ++k) mloc = fmaxf(mloc, acc[k]);
        float m = fmaxf(mloc, __shfl_xor(mloc, 1));
        float sloc = 0.f;
        #pragma unroll
        for (int k = 0; k < 8; ++k) sloc += __expf(acc[k] - m);
        float ssum = sloc + __shfl_xor(sloc, 1);
        float ls = m + __logf(ssum);
        float4 w0 = make_float4(acc[0] - ls, acc[1] - ls, acc[2] - ls, acc[3] - ls);
        float4 w1 = make_float4(acc[4] - ls, acc[5] - ls, acc[6] - ls, acc[7] - ls);
        *(float4*)&out0[(size_t)n * 16 + t * 8] = w0;
        *(float4*)&out0[(size_t)n * 16 + t * 8 + 4] = w1;
    }
}

// ---------------- launch ----------------

extern "C" void kernel_launch(void* const* d_in, const int* in_sizes, int n_in,
                              void* d_out, int out_size, void* d_ws, size_t ws_size,
                              hipStream_t stream) {
    const float* x   = (const float*)d_in[0];
    const int*   ei  = (const int*)d_in[1];
    const float* ew  = (const float*)d_in[2];
    const float* W1  = (const float*)d_in[3];
    const float* b1  = (const float*)d_in[4];
    const float* W2  = (const float*)d_in[5];
    const float* b2  = (const float*)d_in[6];
    const float* W3  = (const float*)d_in[7];
    const float* b3  = (const float*)d_in[8];
    float* out = (float*)d_out;

    const int N = in_sizes[0] / N_FEAT;      // 100000
    const int E = in_sizes[2];               // 1600000
    const int NB = (N + (1 << NBW) - 1) >> NBW;   // 196

    size_t off = 0;
    auto alloc = [&](size_t bytes) {
        void* p = (char*)d_ws + off;
        off += (bytes + 255) & ~(size_t)255;
        return p;
    };
    float* dis     = (float*)alloc((size_t)N * 4);
    int*   cnt     = (int*)alloc((size_t)N * 4);
    int*   rowp    = (int*)alloc((size_t)N * 4);
    int*   bcur    = (int*)alloc(256 * 16 * 4);          // strided cursors (64B/bucket)
    int2*  csr     = (int2*)alloc(((size_t)NB * CAP + 32) * 8);  // +32-entry pad (sentinel-filled)
    int2*  ebuf    = (int2*)alloc((size_t)NB * CAP * 8);
    u16*   hwB     = (u16*)alloc((size_t)N * 64 * 2);    // gemm1 out (layer-1 gather table)
    u16*   hwB2    = (u16*)alloc((size_t)N * 64 * 2);    // gemm2 out (layer-2 gather table)
    u16*   hw16    = (u16*)alloc((size_t)N * 16 * 2);    // gemm3 out (layer-3 gather table)
    uint4* Wp1     = (uint4*)alloc(512 * 16);            // B-fragment-packed weights
    uint4* Wp2     = (uint4*)alloc(512 * 16);
    uint4* Wp3     = (uint4*)alloc(128 * 16);

    const int TB = 256;

    int gblk = ((N + 15) / 16 + 3) / 4;      // gemm1: one 16-row tile per wave
    int PB   = (E + 256 * 16 - 1) / (256 * 16);   // partition blocks (EPT=16) = 391
    int fblk = (N + 31) / 32;                // fused agg+gemm blocks (32 nodes each)
    int ablk16 = (N * 2 + TB - 1) / TB;      // final agg: 2 lanes/node

    float* logits = out + (size_t)N * 16;
    float* logits2 = out + (size_t)2 * N * 16;

    // pack weights + zero cursors; partition + fused gemm1; bucket CSR
    pack_init<<<4, TB, 0, stream>>>(W1, W2, W3, Wp1, Wp2, Wp3, bcur);
    part_gemm<<<PB + gblk, TB, 0, stream>>>(ei, ew, bcur, ebuf, E, NB, PB, x, Wp1, hwB, N);
    bucket_csr<<<NB, TB, 0, stream>>>(ebuf, bcur, csr, rowp, cnt, dis, N);

    // layer 1 aggregate (LOADDIS) + layer-2 GEMM fused
    agg_gemm<64, true><<<fblk, TB, 0, stream>>>(hwB, rowp, cnt, csr, dis, b1, Wp2, hwB2, N);
    // layer 2 aggregate + layer-3 GEMM fused
    agg_gemm<16, false><<<fblk, TB, 0, stream>>>(hwB2, rowp, cnt, csr, dis, b2, Wp3, hw16, N);
    // layer 3 aggregate + log-softmax
    agg_final<<<ablk16, TB, 0, stream>>>(hw16, rowp, cnt, csr, dis, b3, out, logits, logits2, N);
}